// Round 8
// baseline (481.754 us; speedup 1.0000x reference)
//
#include <hip/hip_runtime.h>
#include <hip/hip_bf16.h>
#include <cstddef>
#include <cstdint>

typedef __hip_bfloat16 hbf;
typedef __attribute__((ext_vector_type(8))) __bf16 bf16x8;
typedef __attribute__((ext_vector_type(4))) float f32x4;

#define B_ 2
#define T_ 2048
#define D_ 1024
#define H_ 16
#define FF_ 4096
#define EPS_ 1e-5f
// Q pre-scale = log2(e)/sqrt(dk): attention exponentials become native exp2
#define SCALE_ 0.18033688011112f

__device__ __forceinline__ float bf2f(hbf v) { return __bfloat162float(v); }
__device__ __forceinline__ float fexp2(float x) {
  return __builtin_amdgcn_exp2f(x);  // v_exp_f32 (2^x native)
}
__device__ __forceinline__ float flog2(float x) {
  return __builtin_amdgcn_logf(x);  // v_log_f32 (log2 native)
}
__device__ __forceinline__ float ldin(const void* p, size_t i, int isbf) {
  return isbf ? __bfloat162float(((const hbf*)p)[i]) : ((const float*)p)[i];
}
__device__ __forceinline__ void ston(void* p, size_t i, float v, int isbf) {
  if (isbf) ((hbf*)p)[i] = __float2bfloat16(v);
  else ((float*)p)[i] = v;
}
__device__ __forceinline__ f32x4 mfma16(bf16x8 a, bf16x8 b, f32x4 c) {
  return __builtin_amdgcn_mfma_f32_16x16x32_bf16(a, b, c, 0, 0, 0);
}
__device__ __forceinline__ bf16x8 ldfrag(const hbf* p) {
  return *(const bf16x8*)p;
}
// async global->LDS, 16B/lane; LDS base wave-uniform (HW: lane i -> base+i*16)
__device__ __forceinline__ void glds16(const hbf* g, hbf* l) {
  __builtin_amdgcn_global_load_lds(
      (const __attribute__((address_space(1))) void*)g,
      (__attribute__((address_space(3))) void*)l, 16, 0, 0);
}

// ---------------------------------------------------------------------------
// Runtime input-dtype detection (bf16 vs fp32), from bit patterns of x.
// ---------------------------------------------------------------------------
__global__ __launch_bounds__(256) void detect_dtype(const unsigned* x,
                                                    int* flag) {
  __shared__ int cnt[256];
  int c = 0;
  for (int i = threadIdx.x; i < 4096; i += 256) {
    unsigned low = x[i] & 0xFFFFu;
    unsigned e = (low >> 7) & 0xFFu;
    if (e >= 100u && e <= 142u) c++;
  }
  cnt[threadIdx.x] = c;
  __syncthreads();
  for (int off = 128; off > 0; off >>= 1) {
    if ((int)threadIdx.x < off) cnt[threadIdx.x] += cnt[threadIdx.x + off];
    __syncthreads();
  }
  if (threadIdx.x == 0) *flag = (cnt[0] > 2458) ? 1 : 0;
}

// ---------------------------------------------------------------------------
// Mega-preconversion: one launch does all weight transposes + x/bias converts.
// Flat block-id job table:
//  [0,3072)      Wq/Wk/Wv -> wqkvt (head-sliced transpose, R=1024,C=64,z=16)
//  [3072,4096)   Wo -> wot          (1024x1024)
//  [4096,8192)   W1 -> w1t          (1024x4096)
//  [8192,12288)  W2 -> w2t          (4096x1024)
//  [12288,13312) x -> xb            (4M elements, 4096/block, vectorized)
//  13312: b1 -> b1b ; 13313: b2 -> b2b
// ---------------------------------------------------------------------------
__device__ __forceinline__ void tr_tile(const void* __restrict__ src,
                                        hbf* __restrict__ dst, int R, int C,
                                        size_t zoff, int cx, int ry, int f,
                                        float (*tile)[33]) {
  const int tx = threadIdx.x & 31, ty = threadIdx.x >> 5;
  const int c0 = cx * 32, r0 = ry * 32;
#pragma unroll
  for (int p = 0; p < 4; p++) {
    int rr = p * 8 + ty;
    tile[rr][tx] = ldin(src, zoff + (size_t)(r0 + rr) * C + c0 + tx, f);
  }
  __syncthreads();
#pragma unroll
  for (int p = 0; p < 4; p++) {
    int cc = p * 8 + ty;
    dst[zoff + (size_t)(c0 + cc) * R + r0 + tx] = __float2bfloat16(tile[tx][cc]);
  }
}

__global__ __launch_bounds__(256) void preconv(
    const void* __restrict__ x, const void* __restrict__ Wq,
    const void* __restrict__ Wk, const void* __restrict__ Wv,
    const void* __restrict__ Wo, const void* __restrict__ W1,
    const void* __restrict__ W2, const void* __restrict__ b1,
    const void* __restrict__ b2, hbf* __restrict__ xb,
    hbf* __restrict__ wqkvt, hbf* __restrict__ wot, hbf* __restrict__ w1t,
    hbf* __restrict__ w2t, hbf* __restrict__ b1b, hbf* __restrict__ b2b,
    const int* __restrict__ flag) {
  __shared__ float tile[32][33];
  const int f = *flag;
  const int bid = blockIdx.x;
  if (bid < 3072) {
    int which = bid >> 10;  // 0=Wq 1=Wk 2=Wv
    int r = bid & 1023;
    int z = r >> 6, rem = r & 63;
    int ry = rem >> 1, cx = rem & 1;
    const void* src = (which == 0) ? Wq : (which == 1) ? Wk : Wv;
    hbf* dst = wqkvt + (size_t)which * (D_ * D_);
    tr_tile(src, dst, 1024, 64, (size_t)z * 65536, cx, ry, f, tile);
  } else if (bid < 4096) {
    int t = bid - 3072;
    tr_tile(Wo, wot, 1024, 1024, 0, t & 31, t >> 5, f, tile);
  } else if (bid < 8192) {
    int t = bid - 4096;
    tr_tile(W1, w1t, 1024, 4096, 0, t & 127, t >> 7, f, tile);
  } else if (bid < 12288) {
    int t = bid - 8192;
    tr_tile(W2, w2t, 4096, 1024, 0, t & 31, t >> 5, f, tile);
  } else if (bid < 13312) {
    size_t base = (size_t)(bid - 12288) * 4096;
    if (f) {
      // bf16 input: straight 16B copies
      const uint4* src = (const uint4*)((const hbf*)x + base);
      uint4* dst = (uint4*)(xb + base);
      for (int i = threadIdx.x; i < 512; i += 256) dst[i] = src[i];
    } else {
      // fp32 input: float4 x2 -> 8 bf16 packed (uint2x2)
      const float4* src = (const float4*)((const float*)x + base);
      for (int i = threadIdx.x; i < 512; i += 256) {
        float4 a = src[i * 2], b = src[i * 2 + 1];
        union {
          hbf h[8];
          uint4 u;
        } o;
        o.h[0] = __float2bfloat16(a.x);
        o.h[1] = __float2bfloat16(a.y);
        o.h[2] = __float2bfloat16(a.z);
        o.h[3] = __float2bfloat16(a.w);
        o.h[4] = __float2bfloat16(b.x);
        o.h[5] = __float2bfloat16(b.y);
        o.h[6] = __float2bfloat16(b.z);
        o.h[7] = __float2bfloat16(b.w);
        *(uint4*)(xb + base + (size_t)i * 8) = o.u;
      }
    }
  } else if (bid == 13312) {
    for (int i = threadIdx.x; i < FF_; i += 256)
      b1b[i] = __float2bfloat16(ldin(b1, i, f));
  } else {
    for (int i = threadIdx.x; i < D_; i += 256)
      b2b[i] = __float2bfloat16(ldin(b2, i, f));
  }
}

// ---------------------------------------------------------------------------
// MFMA GEMM (m97 structure): C(MxN) = A(MxK) @ Bt(NxK)^T, bf16, fp32 accum.
// BMxBN tile, BK=64 or 128, global_load_lds width-16 staging, 4 waves 2x2.
// BK=128 for BN=64 tiles (out-proj, FFN2): doubles MFMA per barrier pair
// (16->32) and halves the K-step/drain count -- those kernels were
// stall-bound (FFN2: 89us, MfmaUtil 15%, BW 1.7 of 6.3 TB/s). LDS stays
// <=48KB so the 2-blocks/CU grid cap is unaffected.
// MODE 0: QKV fused (N=3072): scatter to (which,B,H,T,64); Q scaled.
// MODE 1: C = acc + e1[m*N+n]; fused LN stats -> atomicAdd red[batch]
// MODE 2: C = relu(acc + e1[n])            (FFN1 + bias)
// MODE 5: C = acc + bias[n] + e1[m*N+n]; fused LN stats (FFN2+b2+residual;
//         bias passed via Cf0). No split-K, no fp32 partial round-trip.
// ---------------------------------------------------------------------------
template <int MODE, int BM, int BN, int BK>
__global__ __launch_bounds__(256) void gemm_bt(
    const hbf* __restrict__ A, const hbf* __restrict__ Bt, hbf* __restrict__ C,
    float* __restrict__ Cf0, float* __restrict__ Cf1,
    const hbf* __restrict__ e1, float* __restrict__ red, int M, int N, int K,
    int LDK) {
  constexpr int WM = BM / 2, WN = BN / 2;
  constexpr int IF = WM / 16, JF = WN / 16;
  constexpr int HK = BK / 32;       // 32-wide k-chunks per K-step
  constexpr int LPT = BK / 8;       // lanes covering one row (8 hbf/lane)
  constexpr int CPR = 2048 / BK;    // rows staged per glds chunk (4KB)
  __shared__ alignas(16) hbf As[BM * BK];
  __shared__ alignas(16) hbf Bs[BN * BK];
  const int tid = threadIdx.x;
  const int wave = tid >> 6, lane = tid & 63;
  const int quad = lane >> 4, l16 = lane & 15;
  const int m0 = blockIdx.y * BM, n0 = blockIdx.x * BN;
  const int mw = (wave >> 1) * WM, nw = (wave & 1) * WN;
  const int srow = tid / LPT;
  const int scol = (tid % LPT) * 8;
  const f32x4 zero = {0.f, 0.f, 0.f, 0.f};
  f32x4 acc[IF][JF];
#pragma unroll
  for (int i = 0; i < IF; i++)
#pragma unroll
    for (int j = 0; j < JF; j++) acc[i][j] = zero;

  const hbf* ga = &A[(size_t)(m0 + srow) * LDK + scol];
  const hbf* gb = &Bt[(size_t)(n0 + srow) * LDK + scol];
  hbf* lA = &As[wave * 512];
  hbf* lB = &Bs[wave * 512];

  for (int k0 = 0; k0 < K; k0 += BK) {
#pragma unroll
    for (int c = 0; c < BM / CPR; c++)
      glds16(ga + (size_t)(c * CPR) * LDK + k0, lA + c * 2048);
#pragma unroll
    for (int c = 0; c < BN / CPR; c++)
      glds16(gb + (size_t)(c * CPR) * LDK + k0, lB + c * 2048);
    __syncthreads();
    bf16x8 af[HK][IF], bfr[HK][JF];
#pragma unroll
    for (int h = 0; h < HK; h++) {
#pragma unroll
      for (int i = 0; i < IF; i++)
        af[h][i] = ldfrag(&As[(mw + i * 16 + l16) * BK + h * 32 + quad * 8]);
#pragma unroll
      for (int j = 0; j < JF; j++)
        bfr[h][j] = ldfrag(&Bs[(nw + j * 16 + l16) * BK + h * 32 + quad * 8]);
    }
#pragma unroll
    for (int h = 0; h < HK; h++)
#pragma unroll
      for (int i = 0; i < IF; i++)
#pragma unroll
        for (int j = 0; j < JF; j++)
          acc[i][j] = mfma16(af[h][i], bfr[h][j], acc[i][j]);
    __syncthreads();
  }
  float ssum = 0.f, ssq = 0.f;
#pragma unroll
  for (int i = 0; i < IF; i++)
#pragma unroll
    for (int j = 0; j < JF; j++)
#pragma unroll
      for (int r = 0; r < 4; r++) {
        int m = m0 + mw + i * 16 + quad * 4 + r;
        int n = n0 + nw + j * 16 + l16;
        float v = acc[i][j][r];
        if (MODE == 0) {
          int which = n >> 10, n1 = n & 1023;
          int h = n1 >> 6, cc = n1 & 63;
          int b = m >> 11, t = m & (T_ - 1);
          if (which == 0) v *= SCALE_;  // pre-scale Q by log2e/sqrt(dk)
          C[(size_t)which * ((size_t)B_ * H_ * T_ * 64) +
            (((size_t)(b * H_ + h)) * T_ + t) * 64 + cc] = __float2bfloat16(v);
        } else if (MODE == 1) {
          hbf hv = __float2bfloat16(v + bf2f(e1[(size_t)m * N + n]));
          C[(size_t)m * N + n] = hv;
          float fv = bf2f(hv);
          ssum += fv;
          ssq += fv * fv;
        } else if (MODE == 2) {
          C[(size_t)m * N + n] = __float2bfloat16(fmaxf(v + bf2f(e1[n]), 0.f));
        } else if (MODE == 5) {
          const hbf* bias = (const hbf*)Cf0;
          hbf hv = __float2bfloat16(v + bf2f(bias[n]) +
                                    bf2f(e1[(size_t)m * N + n]));
          C[(size_t)m * N + n] = hv;
          float fv = bf2f(hv);
          ssum += fv;
          ssq += fv * fv;
        }
      }
  if (MODE == 1 || MODE == 5) {
    // fused LN stats: block tile lies within one batch (BM=128 | 2048)
    float* sc = (float*)As;  // dead LDS reuse (post final barrier)
    sc[tid] = ssum;
    sc[256 + tid] = ssq;
    __syncthreads();
    for (int off = 128; off > 0; off >>= 1) {
      if (tid < off) {
        sc[tid] += sc[tid + off];
        sc[256 + tid] += sc[256 + tid + off];
      }
      __syncthreads();
    }
    if (tid == 0) {
      int b = m0 >> 11;
      atomicAdd(&red[b * 2 + 0], sc[0]);
      atomicAdd(&red[b * 2 + 1], sc[256]);
    }
  }
}

// ---------------------------------------------------------------------------
// Attention stats + V-transform (MFMA): S = Q K^T (Q pre-scaled by log2e/8,
// so all exponentials are base-2 -> native v_exp_f32).
//   adj[s] = max_q S[q,s] + log2(sum_q 2^(S[q,s]-max))
// Tail (fused, block owns its 64 s-rows): Vt'[v,s] = V[s,v]*2^(-adj[s]).
// Block: 64 s (4 waves x 16), loops q-tiles of 64. Padded LDS stride 72.
// ---------------------------------------------------------------------------
__global__ __launch_bounds__(256) void attn_stats(const hbf* __restrict__ Q,
                                                  const hbf* __restrict__ K,
                                                  const hbf* __restrict__ V,
                                                  hbf* __restrict__ Vt) {
  __shared__ alignas(16) hbf Ks[64 * 72];
  __shared__ alignas(16) hbf Qs[64 * 72];
  __shared__ float sAdj[64];
  const int bh = blockIdx.y;
  const int s0 = blockIdx.x * 64;
  const int tid = threadIdx.x;
  const int wave = tid >> 6, lane = tid & 63;
  const int quad = lane >> 4, l16 = lane & 15;
  const int sw = wave * 16;
  const hbf* Kb = K + (size_t)bh * T_ * 64;
  const hbf* Qb = Q + (size_t)bh * T_ * 64;
  const hbf* Vb = V + (size_t)bh * T_ * 64;
  hbf* Vtb = Vt + (size_t)bh * 64 * T_;
  const int r_ = tid >> 3, c_ = (tid & 7) * 8;
#pragma unroll
  for (int c = 0; c < 2; c++) {
    int row = c * 32 + r_;
    *(float4*)(&Ks[row * 72 + c_]) =
        *(const float4*)(&Kb[(size_t)(s0 + row) * 64 + c_]);
  }
  __syncthreads();
  bf16x8 kf0 = ldfrag(&Ks[(sw + l16) * 72 + quad * 8]);
  bf16x8 kf1 = ldfrag(&Ks[(sw + l16) * 72 + 32 + quad * 8]);
  float m_thr[4], l_thr[4];
#pragma unroll
  for (int r = 0; r < 4; r++) {
    m_thr[r] = -1e30f;
    l_thr[r] = 0.f;
  }
  const f32x4 zero = {0.f, 0.f, 0.f, 0.f};
  for (int qt = 0; qt < T_ / 64; qt++) {
    if (qt) __syncthreads();
#pragma unroll
    for (int c = 0; c < 2; c++) {
      int row = c * 32 + r_;
      *(float4*)(&Qs[row * 72 + c_]) =
          *(const float4*)(&Qb[(size_t)(qt * 64 + row) * 64 + c_]);
    }
    __syncthreads();
    f32x4 acc[4];
#pragma unroll
    for (int j = 0; j < 4; j++) {
      bf16x8 qf0 = ldfrag(&Qs[(j * 16 + l16) * 72 + quad * 8]);
      bf16x8 qf1 = ldfrag(&Qs[(j * 16 + l16) * 72 + 32 + quad * 8]);
      f32x4 a = zero;
      a = mfma16(kf0, qf0, a);
      a = mfma16(kf1, qf1, a);
      acc[j] = a;
    }
#pragma unroll
    for (int r = 0; r < 4; r++) {
      float mt = fmaxf(fmaxf(acc[0][r], acc[1][r]),
                       fmaxf(acc[2][r], acc[3][r]));
      float nm = fmaxf(m_thr[r], mt);
      float s = l_thr[r] * fexp2(m_thr[r] - nm);
#pragma unroll
      for (int j = 0; j < 4; j++) s += fexp2(acc[j][r] - nm);
      l_thr[r] = s;
      m_thr[r] = nm;
    }
  }
#pragma unroll
  for (int d = 1; d < 16; d <<= 1) {
#pragma unroll
    for (int r = 0; r < 4; r++) {
      float om = __shfl_xor(m_thr[r], d);
      float ol = __shfl_xor(l_thr[r], d);
      float nm = fmaxf(m_thr[r], om);
      l_thr[r] = l_thr[r] * fexp2(m_thr[r] - nm) + ol * fexp2(om - nm);
      m_thr[r] = nm;
    }
  }
  if (l16 == 0) {
#pragma unroll
    for (int r = 0; r < 4; r++)
      sAdj[sw + quad * 4 + r] = m_thr[r] + flog2(l_thr[r]);
  }
  __syncthreads();
  // fused V scale+transpose for this block's s-range (reuse Ks as tile)
#pragma unroll
  for (int c = 0; c < 2; c++) {
    int e = (c * 256 + tid) * 8;
    int r = e >> 6, col = e & 63;
    union alignas(16) {
      hbf h[8];
      float4 f4;
    } u;
    u.f4 = *(const float4*)(&Vb[(size_t)(s0 + r) * 64 + col]);
    float sc = fexp2(-sAdj[r]);
#pragma unroll
    for (int k2 = 0; k2 < 8; k2++)
      u.h[k2] = __float2bfloat16(bf2f(u.h[k2]) * sc);
    *(float4*)(&Ks[r * 72 + col]) = u.f4;
  }
  __syncthreads();
#pragma unroll
  for (int c = 0; c < 2; c++) {
    int e = (c * 256 + tid) * 8;
    int v = e >> 6, tt = e & 63;
    union alignas(16) {
      hbf h[8];
      float4 f4;
    } u;
#pragma unroll
    for (int k2 = 0; k2 < 8; k2++) u.h[k2] = Ks[(tt + k2) * 72 + v];
    *(float4*)(&Vtb[(size_t)v * T_ + s0 + tt]) = u.f4;
  }
}

// ---------------------------------------------------------------------------
// Attention apply (MFMA): O[q,v] = sum_s 2^(S[q,s]) * V'[s,v]
// (normalizer folded into V'). Cross-iteration pipeline: iteration st
// computes QK^T(st) AND PV(st-1) so PV's MFMAs overlap QK's load/exp chain.
//  * K double-buffered (16KB), V triple-buffered (24KB), P per-wave
//    double-buffered (37KB). 77KB total -> 2 blocks/CU (grid cap).
//  * staging via global_load_lds + XOR swizzle, one barrier per iteration,
//    s_setprio(1) around MFMA clusters.
// Block: 128 q (4 waves x 32), s-tiles of 64, grid (16,32).
// ---------------------------------------------------------------------------
__global__ __launch_bounds__(256) void attn_apply(const hbf* __restrict__ Q,
                                                  const hbf* __restrict__ K,
                                                  const hbf* __restrict__ Vt,
                                                  hbf* __restrict__ heads) {
  __shared__ alignas(16) hbf Ksb[2 * 64 * 64];
  __shared__ alignas(16) hbf Vsb[3 * 64 * 64];
  __shared__ alignas(16) hbf Ps[4 * 2 * 32 * 72];
  const int bh = blockIdx.y;
  const int b = bh >> 4, h = bh & 15;
  const int q0 = blockIdx.x * 128;
  const int tid = threadIdx.x;
  const int wave = tid >> 6, lane = tid & 63;
  const int quad = lane >> 4, l16 = lane & 15;
  const int qw = wave * 32;
  const hbf* Qb = Q + (size_t)bh * T_ * 64;
  const hbf* Kb = K + (size_t)bh * T_ * 64;
  const hbf* Vtb = Vt + (size_t)bh * 64 * T_;
  hbf* Pw = &Ps[wave * (2 * 32 * 72)];
  // staging: lane -> LDS slot (row=tid>>3, chunk=tid&7); source chunk is
  // inverse-swizzled so LDS slot (r,c) holds global chunk c^(r&7).
  const int srow = tid >> 3, sc8 = tid & 7;
  const int swz = sc8 ^ (srow & 7);
  const hbf* gk = Kb + (size_t)srow * 64 + swz * 8;
  const hbf* gv = Vtb + (size_t)srow * T_ + swz * 8;
  hbf* lK = &Ksb[wave * 512];
  hbf* lV = &Vsb[wave * 512];
  const int sx = (l16 & 7) * 8;  // read-side elem swizzle for this lane's rows
  // Q fragments (B-operand): lane supplies Q[col=q(l16)][k=quad*8 in hh*32]
  bf16x8 qf[2][2];
#pragma unroll
  for (int i = 0; i < 2; i++)
#pragma unroll
    for (int hh = 0; hh < 2; hh++)
      qf[i][hh] = ldfrag(&Qb[(size_t)(q0 + qw + i * 16 + l16) * 64 + hh * 32 +
                             quad * 8]);
  const f32x4 zero = {0.f, 0.f, 0.f, 0.f};
  f32x4 accO[2][4];
#pragma unroll
  for (int i = 0; i < 2; i++)
#pragma unroll
    for (int j = 0; j < 4; j++) accO[i][j] = zero;

  // prologue: stage tiles 0 and 1 (K slots 0/1, V slots 0/1)
  glds16(gk, lK);
  glds16(gk + 2048, lK + 2048);
  glds16(gv, lV);
  glds16(gv + (size_t)32 * T_, lV + 2048);
  glds16(gk + 4096, lK + 4096);
  glds16(gk + 4096 + 2048, lK + 4096 + 2048);
  glds16(gv + 64, lV + 4096);
  glds16(gv + (size_t)32 * T_ + 64, lV + 4096 + 2048);
  __syncthreads();

  // prologue compute: QK^T(0) -> P[0] (no PV yet)
  {
    const hbf* Kc = &Ksb[0];
    bf16x8 kf[4][2];
#pragma unroll
    for (int j = 0; j < 4; j++)
#pragma unroll
      for (int hh = 0; hh < 2; hh++)
        kf[j][hh] =
            ldfrag(&Kc[(j * 16 + l16) * 64 + ((hh * 32 + quad * 8) ^ sx)]);
    __builtin_amdgcn_s_setprio(1);
    f32x4 accS[2][4];
#pragma unroll
    for (int i = 0; i < 2; i++)
#pragma unroll
      for (int j = 0; j < 4; j++) {
        f32x4 a = mfma16(kf[j][0], qf[i][0], zero);
        accS[i][j] = mfma16(kf[j][1], qf[i][1], a);
      }
    __builtin_amdgcn_s_setprio(0);
#pragma unroll
    for (int i = 0; i < 2; i++)
#pragma unroll
      for (int j = 0; j < 4; j++) {
        union {
          hbf h4[4];
          uint2 u;
        } pk;
#pragma unroll
        for (int r = 0; r < 4; r++)
          pk.h4[r] = __float2bfloat16(fexp2(accS[i][j][r]));
        *(uint2*)&Pw[(i * 16 + l16) * 72 + j * 16 + quad * 4] = pk.u;
      }
  }
  __syncthreads();  // protect K slot 0 from the st=1 prefetch (tile 2)

  for (int st = 1; st < T_ / 64; st++) {
    const int kcur = st & 1;
    const int pcur = st & 1, pprev = pcur ^ 1;
    const int vprev = (st - 1) % 3;
    if (st < T_ / 64 - 1) {  // async prefetch tile st+1 (drains at barrier)
      const int knxt = (st + 1) & 1, vnxt = (st + 1) % 3;
      size_t ko = (size_t)(st + 1) * 4096;
      glds16(gk + ko, lK + knxt * 4096);
      glds16(gk + ko + 2048, lK + knxt * 4096 + 2048);
      glds16(gv + (st + 1) * 64, lV + vnxt * 4096);
      glds16(gv + (size_t)32 * T_ + (st + 1) * 64, lV + vnxt * 4096 + 2048);
    }
    const hbf* Kc = &Ksb[kcur * 4096];
    const hbf* Vp = &Vsb[vprev * 4096];
    // issue kf loads for QK(st) early (in-order lgkm: complete before pf use)
    bf16x8 kf[4][2];
#pragma unroll
    for (int j = 0; j < 4; j++)
#pragma unroll
      for (int hh = 0; hh < 2; hh++)
        kf[j][hh] =
            ldfrag(&Kc[(j * 16 + l16) * 64 + ((hh * 32 + quad * 8) ^ sx)]);
    // PV(st-1): A = P[prev] rows q, B = V'[prev] rows v
    bf16x8 pf[2][2];
#pragma unroll
    for (int i = 0; i < 2; i++)
#pragma unroll
      for (int hh = 0; hh < 2; hh++)
        pf[i][hh] = ldfrag(
            &Pw[pprev * (32 * 72) + (i * 16 + l16) * 72 + hh * 32 + quad * 8]);
    __builtin_amdgcn_s_setprio(1);
#pragma unroll
    for (int j2 = 0; j2 < 4; j2++) {
      bf16x8 vf0 = ldfrag(&Vp[(j2 * 16 + l16) * 64 + ((quad * 8) ^ sx)]);
      bf16x8 vf1 = ldfrag(&Vp[(j2 * 16 + l16) * 64 + ((32 + quad * 8) ^ sx)]);
#pragma unroll
      for (int i = 0; i < 2; i++) {
        accO[i][j2] = mfma16(pf[i][0], vf0, accO[i][j2]);
        accO[i][j2] = mfma16(pf[i][1], vf1, accO[i][j2]);
      }
    }
    // QK^T(st) swapped: accS[i][j] = D[s][q]
    f32x4 accS[2][4];
#pragma unroll
    for (int i = 0; i < 2; i++)
#pragma unroll
      for (int j = 0; j < 4; j++) {
        f32x4 a = mfma16(kf[j][0], qf[i][0], zero);
        accS[i][j] = mfma16(kf[j][1], qf[i][1], a);
      }
    __builtin_amdgcn_s_setprio(0);
    // exp2 -> bf16 pack -> P[cur] (8 b64 writes, s-consecutive)
#pragma unroll
    for (int i = 0; i < 2; i++)
#pragma unroll
      for (int j = 0; j < 4; j++) {
        union {
          hbf h4[4];
          uint2 u;
        } pk;
#pragma unroll
        for (int r = 0; r < 4; r++)
          pk.h4[r] = __float2bfloat16(fexp2(accS[i][j][r]));
        *(uint2*)&Pw[pcur * (32 * 72) + (i * 16 + l16) * 72 + j * 16 +
                     quad * 4] = pk.u;
      }
    __syncthreads();
  }
  // epilogue: PV(last tile): P[(T/64-1)&1], V[(T/64-1)%3]
  {
    const int pl = (T_ / 64 - 1) & 1;
    const hbf* Vp = &Vsb[((T_ / 64 - 1) % 3) * 4096];
    bf16x8 pf[2][2];
#pragma unroll
    for (int i = 0; i < 2; i++)
#pragma unroll
      for (int hh = 0; hh < 2; hh++)
        pf[i][hh] = ldfrag(
            &Pw[pl * (32 * 72) + (i * 16 + l16) * 72 + hh * 32 + quad * 8]);
    __builtin_amdgcn_s_setprio(1);
#pragma unroll
    for (int j2 = 0; j2 < 4; j2++) {
      bf16x8 vf0 = ldfrag(&Vp[(j2 * 16 + l16) * 64 + ((quad * 8) ^ sx)]);
      bf16x8 vf1 = ldfrag(&Vp[(j2 * 16 + l16) * 64 + ((32 + quad * 8) ^ sx)]);
#pragma unroll
      for (int i = 0; i < 2; i++) {
        accO[i][j2] = mfma16(pf[i][0], vf0, accO[i][j2]);
        accO[i][j2] = mfma16(pf[i][1], vf1, accO[i][j2]);
      }
    }
    __builtin_amdgcn_s_setprio(0);
  }
#pragma unroll
  for (int i = 0; i < 2; i++)
#pragma unroll
    for (int j2 = 0; j2 < 4; j2++)
#pragma unroll
      for (int r = 0; r < 4; r++) {
        int q = q0 + qw + i * 16 + quad * 4 + r;
        int v = j2 * 16 + l16;
        heads[((size_t)(b * T_ + q)) * D_ + h * 64 + v] =
            __float2bfloat16(accO[i][j2][r]);
      }
}

// ---------------------------------------------------------------------------
// LN1 normalize (stats came fused from the out-proj GEMM).
// ---------------------------------------------------------------------------
__global__ __launch_bounds__(256) void ln_norm(const hbf* __restrict__ src,
                                               const float* __restrict__ red,
                                               void* dst,
                                               const int* __restrict__ flag,
                                               int force_bf) {
  const int isbf = force_bf ? 1 : *flag;
  const float invN = 1.f / (float)(T_ * D_);
  for (size_t i = (size_t)blockIdx.x * 256 + threadIdx.x;
       i < (size_t)B_ * T_ * D_; i += (size_t)gridDim.x * 256) {
    int b = (int)(i >> 21);
    float mu = red[b * 2 + 0] * invN;
    float var = red[b * 2 + 1] * invN - mu * mu;
    ston(dst, i, (bf2f(src[i]) - mu) * rsqrtf(var + EPS_), isbf);
  }
}

// ---------------------------------------------------------------------------
// LN2 normalize: r2 (bf16, stats fused in MODE-5 FFN2) -> d_out. Vectorized
// 4x bf16 loads; bf16 or fp32 output per runtime flag.
// ---------------------------------------------------------------------------
__global__ __launch_bounds__(256) void ln2_norm(const hbf* __restrict__ r2,
                                                const float* __restrict__ red,
                                                void* dst,
                                                const int* __restrict__ flag) {
  const int isbf = *flag;
  const float invN = 1.f / (float)(T_ * D_);
  const uint2* r2v = (const uint2*)r2;
  for (size_t i = (size_t)blockIdx.x * 256 + threadIdx.x;
       i < (size_t)B_ * T_ * D_ / 4; i += (size_t)gridDim.x * 256) {
    int b = (int)(i >> 19);  // per-batch 4-elem count = T*D/4 = 2^19
    float mu = red[b * 2 + 0] * invN;
    float var = red[b * 2 + 1] * invN - mu * mu;
    float rstd = rsqrtf(var + EPS_);
    union {
      uint2 u;
      hbf h[4];
    } s;
    s.u = r2v[i];
    float out[4];
#pragma unroll
    for (int r = 0; r < 4; r++) out[r] = (bf2f(s.h[r]) - mu) * rstd;
    if (isbf) {
      union {
        hbf h[4];
        uint2 u;
      } pk;
#pragma unroll
      for (int r = 0; r < 4; r++) pk.h[r] = __float2bfloat16(out[r]);
      ((uint2*)dst)[i] = pk.u;
    } else {
      float4 f{out[0], out[1], out[2], out[3]};
      ((float4*)dst)[i] = f;
    }
  }
}

// ---------------------------------------------------------------------------
// Workspace (MiB offsets), ~88.1 MB total:
//  [0,8) xb (later r2) | [8,14) Wqkvt | [14,16) Wot | [16,24) W1t | [24,32) W2t
//  [32,40) Q | [40,48) K | [48,56) V | [56,64) Vt | [64,72) heads
//  [72,80) r1 | [80,88) o1 | ff1 aliases [32,64)
//  [88,..) b1b 8K | b2b 2K | red 32B | flag 4B
// ---------------------------------------------------------------------------
extern "C" void kernel_launch(void* const* d_in, const int* in_sizes, int n_in,
                              void* d_out, int out_size, void* d_ws,
                              size_t ws_size, hipStream_t stream) {
  const void* x = d_in[0];
  const void* Wq = d_in[1];
  const void* Wk = d_in[2];
  const void* Wv = d_in[3];
  const void* Wo = d_in[4];
  const void* W1 = d_in[5];
  const void* W2 = d_in[7];
  const void* b1 = d_in[6];
  const void* b2 = d_in[8];

  const size_t MB = 1024 * 1024;
  if (ws_size < 89 * MB) return;

  char* w = (char*)d_ws;
  hbf* xb = (hbf*)(w + 0 * MB);
  hbf* wqkvt = (hbf*)(w + 8 * MB);
  hbf* wot = (hbf*)(w + 14 * MB);
  hbf* w1t = (hbf*)(w + 16 * MB);
  hbf* w2t = (hbf*)(w + 24 * MB);
  hbf* Qb = (hbf*)(w + 32 * MB);
  hbf* Kb = (hbf*)(w + 40 * MB);
  hbf* Vb = (hbf*)(w + 48 * MB);
  hbf* Vtb = (hbf*)(w + 56 * MB);
  hbf* heads = (hbf*)(w + 64 * MB);
  hbf* r1 = (hbf*)(w + 72 * MB);
  hbf* o1 = (hbf*)(w + 80 * MB);
  hbf* ff1 = (hbf*)(w + 32 * MB);  // over dead Q/K/V/Vt
  hbf* r2 = (hbf*)(w + 0 * MB);    // over dead xb (dead after out-proj)
  hbf* b1b = (hbf*)(w + 88 * MB);
  hbf* b2b = b1b + FF_;
  float* red = (float*)(b2b + D_);
  int* flag = (int*)(red + 8);

  hipMemsetAsync(red, 0, 8 * sizeof(float) + sizeof(int), stream);
  detect_dtype<<<1, 256, 0, stream>>>((const unsigned*)x, flag);

  const int M = B_ * T_;  // 4096
  // --- one-launch preconversion ---
  preconv<<<13314, 256, 0, stream>>>(x, Wq, Wk, Wv, Wo, W1, W2, b1, b2, xb,
                                     wqkvt, wot, w1t, w2t, b1b, b2b, flag);
  // --- QKV fused projection (Q pre-scaled by log2e/8) ---
  gemm_bt<0, 128, 128, 64><<<dim3(24, 32), 256, 0, stream>>>(
      xb, wqkvt, Qb, nullptr, nullptr, nullptr, nullptr, M, 3 * D_, D_, D_);
  // --- attention: col-softmax stats + fused V scale/transpose, then apply ---
  attn_stats<<<dim3(32, 32), 256, 0, stream>>>(Qb, Kb, Vb, Vtb);
  attn_apply<<<dim3(16, 32), 256, 0, stream>>>(Qb, Kb, Vtb, heads);
  // --- out-proj + residual + fused LN1 stats (BK=128: 32 MFMA/barrier) ---
  gemm_bt<1, 128, 64, 128><<<dim3(16, 32), 256, 0, stream>>>(
      heads, wot, r1, nullptr, nullptr, xb, red, M, D_, D_, D_);
  ln_norm<<<4096, 256, 0, stream>>>(r1, red, o1, flag, 1);
  // --- FFN1 ---
  gemm_bt<2, 128, 128, 64><<<dim3(32, 32), 256, 0, stream>>>(
      o1, w1t, ff1, nullptr, nullptr, b1b, nullptr, M, FF_, D_, D_);
  // --- FFN2 single-K + fused b2 + residual(o1) + LN2 stats (BK=128) ---
  gemm_bt<5, 128, 64, 128><<<dim3(16, 32), 256, 0, stream>>>(
      ff1, w2t, r2, (float*)b2b, nullptr, o1, red + 4, M, D_, FF_, FF_);
  // --- LN2 normalize ---
  ln2_norm<<<2048, 256, 0, stream>>>(r2, red + 4, d_out, flag);
}

// Round 9
// 450.853 us; speedup vs baseline: 1.0685x; 1.0685x over previous
//
#include <hip/hip_runtime.h>
#include <hip/hip_bf16.h>
#include <cstddef>
#include <cstdint>

typedef __hip_bfloat16 hbf;
typedef __attribute__((ext_vector_type(8))) __bf16 bf16x8;
typedef __attribute__((ext_vector_type(4))) float f32x4;

#define B_ 2
#define T_ 2048
#define D_ 1024
#define H_ 16
#define FF_ 4096
#define EPS_ 1e-5f
// Q pre-scale = log2(e)/sqrt(dk): attention exponentials become native exp2
#define SCALE_ 0.18033688011112f

__device__ __forceinline__ float bf2f(hbf v) { return __bfloat162float(v); }
__device__ __forceinline__ float fexp2(float x) {
  return __builtin_amdgcn_exp2f(x);  // v_exp_f32 (2^x native)
}
__device__ __forceinline__ float flog2(float x) {
  return __builtin_amdgcn_logf(x);  // v_log_f32 (log2 native)
}
__device__ __forceinline__ float ldin(const void* p, size_t i, int isbf) {
  return isbf ? __bfloat162float(((const hbf*)p)[i]) : ((const float*)p)[i];
}
__device__ __forceinline__ void ston(void* p, size_t i, float v, int isbf) {
  if (isbf) ((hbf*)p)[i] = __float2bfloat16(v);
  else ((float*)p)[i] = v;
}
__device__ __forceinline__ f32x4 mfma16(bf16x8 a, bf16x8 b, f32x4 c) {
  return __builtin_amdgcn_mfma_f32_16x16x32_bf16(a, b, c, 0, 0, 0);
}
__device__ __forceinline__ bf16x8 ldfrag(const hbf* p) {
  return *(const bf16x8*)p;
}
// async global->LDS, 16B/lane; LDS base wave-uniform (HW: lane i -> base+i*16)
__device__ __forceinline__ void glds16(const hbf* g, hbf* l) {
  __builtin_amdgcn_global_load_lds(
      (const __attribute__((address_space(1))) void*)g,
      (__attribute__((address_space(3))) void*)l, 16, 0, 0);
}

// ---------------------------------------------------------------------------
// Runtime input-dtype detection (bf16 vs fp32), from bit patterns of x.
// ---------------------------------------------------------------------------
__global__ __launch_bounds__(256) void detect_dtype(const unsigned* x,
                                                    int* flag) {
  __shared__ int cnt[256];
  int c = 0;
  for (int i = threadIdx.x; i < 4096; i += 256) {
    unsigned low = x[i] & 0xFFFFu;
    unsigned e = (low >> 7) & 0xFFu;
    if (e >= 100u && e <= 142u) c++;
  }
  cnt[threadIdx.x] = c;
  __syncthreads();
  for (int off = 128; off > 0; off >>= 1) {
    if ((int)threadIdx.x < off) cnt[threadIdx.x] += cnt[threadIdx.x + off];
    __syncthreads();
  }
  if (threadIdx.x == 0) *flag = (cnt[0] > 2458) ? 1 : 0;
}

// ---------------------------------------------------------------------------
// Mega-preconversion: one launch does all weight transposes + x/bias converts.
// Flat block-id job table:
//  [0,3072)      Wq/Wk/Wv -> wqkvt (head-sliced transpose, R=1024,C=64,z=16)
//  [3072,4096)   Wo -> wot          (1024x1024)
//  [4096,8192)   W1 -> w1t          (1024x4096)
//  [8192,12288)  W2 -> w2t          (4096x1024)
//  [12288,13312) x -> xb            (4M elements, 4096/block, vectorized)
//  13312: b1 -> b1b ; 13313: b2 -> b2b
// ---------------------------------------------------------------------------
__device__ __forceinline__ void tr_tile(const void* __restrict__ src,
                                        hbf* __restrict__ dst, int R, int C,
                                        size_t zoff, int cx, int ry, int f,
                                        float (*tile)[33]) {
  const int tx = threadIdx.x & 31, ty = threadIdx.x >> 5;
  const int c0 = cx * 32, r0 = ry * 32;
#pragma unroll
  for (int p = 0; p < 4; p++) {
    int rr = p * 8 + ty;
    tile[rr][tx] = ldin(src, zoff + (size_t)(r0 + rr) * C + c0 + tx, f);
  }
  __syncthreads();
#pragma unroll
  for (int p = 0; p < 4; p++) {
    int cc = p * 8 + ty;
    dst[zoff + (size_t)(c0 + cc) * R + r0 + tx] = __float2bfloat16(tile[tx][cc]);
  }
}

__global__ __launch_bounds__(256) void preconv(
    const void* __restrict__ x, const void* __restrict__ Wq,
    const void* __restrict__ Wk, const void* __restrict__ Wv,
    const void* __restrict__ Wo, const void* __restrict__ W1,
    const void* __restrict__ W2, const void* __restrict__ b1,
    const void* __restrict__ b2, hbf* __restrict__ xb,
    hbf* __restrict__ wqkvt, hbf* __restrict__ wot, hbf* __restrict__ w1t,
    hbf* __restrict__ w2t, hbf* __restrict__ b1b, hbf* __restrict__ b2b,
    const int* __restrict__ flag) {
  __shared__ float tile[32][33];
  const int f = *flag;
  const int bid = blockIdx.x;
  if (bid < 3072) {
    int which = bid >> 10;  // 0=Wq 1=Wk 2=Wv
    int r = bid & 1023;
    int z = r >> 6, rem = r & 63;
    int ry = rem >> 1, cx = rem & 1;
    const void* src = (which == 0) ? Wq : (which == 1) ? Wk : Wv;
    hbf* dst = wqkvt + (size_t)which * (D_ * D_);
    tr_tile(src, dst, 1024, 64, (size_t)z * 65536, cx, ry, f, tile);
  } else if (bid < 4096) {
    int t = bid - 3072;
    tr_tile(Wo, wot, 1024, 1024, 0, t & 31, t >> 5, f, tile);
  } else if (bid < 8192) {
    int t = bid - 4096;
    tr_tile(W1, w1t, 1024, 4096, 0, t & 127, t >> 7, f, tile);
  } else if (bid < 12288) {
    int t = bid - 8192;
    tr_tile(W2, w2t, 4096, 1024, 0, t & 31, t >> 5, f, tile);
  } else if (bid < 13312) {
    size_t base = (size_t)(bid - 12288) * 4096;
    if (f) {
      // bf16 input: straight 16B copies
      const uint4* src = (const uint4*)((const hbf*)x + base);
      uint4* dst = (uint4*)(xb + base);
      for (int i = threadIdx.x; i < 512; i += 256) dst[i] = src[i];
    } else {
      // fp32 input: float4 x2 -> 8 bf16 packed (uint2x2)
      const float4* src = (const float4*)((const float*)x + base);
      for (int i = threadIdx.x; i < 512; i += 256) {
        float4 a = src[i * 2], b = src[i * 2 + 1];
        union {
          hbf h[8];
          uint4 u;
        } o;
        o.h[0] = __float2bfloat16(a.x);
        o.h[1] = __float2bfloat16(a.y);
        o.h[2] = __float2bfloat16(a.z);
        o.h[3] = __float2bfloat16(a.w);
        o.h[4] = __float2bfloat16(b.x);
        o.h[5] = __float2bfloat16(b.y);
        o.h[6] = __float2bfloat16(b.z);
        o.h[7] = __float2bfloat16(b.w);
        *(uint4*)(xb + base + (size_t)i * 8) = o.u;
      }
    }
  } else if (bid == 13312) {
    for (int i = threadIdx.x; i < FF_; i += 256)
      b1b[i] = __float2bfloat16(ldin(b1, i, f));
  } else {
    for (int i = threadIdx.x; i < D_; i += 256)
      b2b[i] = __float2bfloat16(ldin(b2, i, f));
  }
}

// ---------------------------------------------------------------------------
// MFMA GEMM (m97 structure): C(MxN) = A(MxK) @ Bt(NxK)^T, bf16, fp32 accum.
// BMxBN tile, BK=64, global_load_lds width-16 staging, 4 waves as 2x2.
// Config ledger (all A/B'd on this workload):
//  * scalar epilogue (4 consecutive m/thread) -- operand-swap vector stores
//    cost ~8% (same MFMA-busy, worse cache-line locality per store).
//  * BK=64 -- BK=128 regressed 25% (bank-conflict 19M->44M; LDS reads hit
//    critical path in this 2-barrier structure; T2-swizzle is regime-gated
//    off here).
//  * no XCD swizzle -- natural dispatch gives bx%8 per XCD (fits 4MB L2).
//  * FFN2 = split-K z=2 with BN=128 (32 MFMA/barrier AND 512 blocks); the
//    MODE-5 single-K BN=64 variant was 89.8us vs 60.3us (16 MFMA/barrier
//    stall-bound at K=4096).
// MODE 0: QKV fused (N=3072): scatter to (which,B,H,T,64); Q scaled.
// MODE 1: C = acc + e1[m*N+n]; fused LN stats -> atomicAdd red[batch]
// MODE 2: C = relu(acc + e1[n])            (FFN1 + bias)
// MODE 4: Cf_z[m*N+n] = acc  (fp32 split-K partial, z = blockIdx.z)
// ---------------------------------------------------------------------------
template <int MODE, int BM, int BN, int BK>
__global__ __launch_bounds__(256) void gemm_bt(
    const hbf* __restrict__ A, const hbf* __restrict__ Bt, hbf* __restrict__ C,
    float* __restrict__ Cf0, float* __restrict__ Cf1,
    const hbf* __restrict__ e1, float* __restrict__ red, int M, int N, int K,
    int LDK) {
  constexpr int WM = BM / 2, WN = BN / 2;
  constexpr int IF = WM / 16, JF = WN / 16;
  constexpr int HK = BK / 32;     // 32-wide k-chunks per K-step
  constexpr int LPT = BK / 8;     // lanes covering one row (8 hbf/lane)
  constexpr int CPR = 2048 / BK;  // rows staged per glds chunk (4KB)
  __shared__ alignas(16) hbf As[BM * BK];
  __shared__ alignas(16) hbf Bs[BN * BK];
  const int tid = threadIdx.x;
  const int wave = tid >> 6, lane = tid & 63;
  const int quad = lane >> 4, l16 = lane & 15;
  const int m0 = blockIdx.y * BM, n0 = blockIdx.x * BN;
  const int mw = (wave >> 1) * WM, nw = (wave & 1) * WN;
  const int srow = tid / LPT;
  const int scol = (tid % LPT) * 8;
  const int kbase = (MODE == 4) ? blockIdx.z * K : 0;
  const f32x4 zero = {0.f, 0.f, 0.f, 0.f};
  f32x4 acc[IF][JF];
#pragma unroll
  for (int i = 0; i < IF; i++)
#pragma unroll
    for (int j = 0; j < JF; j++) acc[i][j] = zero;

  const hbf* ga = &A[(size_t)(m0 + srow) * LDK + kbase + scol];
  const hbf* gb = &Bt[(size_t)(n0 + srow) * LDK + kbase + scol];
  hbf* lA = &As[wave * 512];
  hbf* lB = &Bs[wave * 512];

  for (int k0 = 0; k0 < K; k0 += BK) {
#pragma unroll
    for (int c = 0; c < BM / CPR; c++)
      glds16(ga + (size_t)(c * CPR) * LDK + k0, lA + c * 2048);
#pragma unroll
    for (int c = 0; c < BN / CPR; c++)
      glds16(gb + (size_t)(c * CPR) * LDK + k0, lB + c * 2048);
    __syncthreads();
    bf16x8 af[HK][IF], bfr[HK][JF];
#pragma unroll
    for (int h = 0; h < HK; h++) {
#pragma unroll
      for (int i = 0; i < IF; i++)
        af[h][i] = ldfrag(&As[(mw + i * 16 + l16) * BK + h * 32 + quad * 8]);
#pragma unroll
      for (int j = 0; j < JF; j++)
        bfr[h][j] = ldfrag(&Bs[(nw + j * 16 + l16) * BK + h * 32 + quad * 8]);
    }
#pragma unroll
    for (int h = 0; h < HK; h++)
#pragma unroll
      for (int i = 0; i < IF; i++)
#pragma unroll
        for (int j = 0; j < JF; j++)
          acc[i][j] = mfma16(af[h][i], bfr[h][j], acc[i][j]);
    __syncthreads();
  }
  float ssum = 0.f, ssq = 0.f;
#pragma unroll
  for (int i = 0; i < IF; i++)
#pragma unroll
    for (int j = 0; j < JF; j++)
#pragma unroll
      for (int r = 0; r < 4; r++) {
        int m = m0 + mw + i * 16 + quad * 4 + r;
        int n = n0 + nw + j * 16 + l16;
        float v = acc[i][j][r];
        if (MODE == 0) {
          int which = n >> 10, n1 = n & 1023;
          int h = n1 >> 6, cc = n1 & 63;
          int b = m >> 11, t = m & (T_ - 1);
          if (which == 0) v *= SCALE_;  // pre-scale Q by log2e/sqrt(dk)
          C[(size_t)which * ((size_t)B_ * H_ * T_ * 64) +
            (((size_t)(b * H_ + h)) * T_ + t) * 64 + cc] = __float2bfloat16(v);
        } else if (MODE == 1) {
          hbf hv = __float2bfloat16(v + bf2f(e1[(size_t)m * N + n]));
          C[(size_t)m * N + n] = hv;
          float fv = bf2f(hv);
          ssum += fv;
          ssq += fv * fv;
        } else if (MODE == 2) {
          C[(size_t)m * N + n] = __float2bfloat16(fmaxf(v + bf2f(e1[n]), 0.f));
        } else if (MODE == 4) {
          float* Cf = blockIdx.z ? Cf1 : Cf0;
          Cf[(size_t)m * N + n] = v;
        }
      }
  if (MODE == 1) {
    // fused LN stats: block tile lies within one batch (BM=128 | 2048)
    float* sc = (float*)As;  // dead LDS reuse (post final barrier)
    sc[tid] = ssum;
    sc[256 + tid] = ssq;
    __syncthreads();
    for (int off = 128; off > 0; off >>= 1) {
      if (tid < off) {
        sc[tid] += sc[tid + off];
        sc[256 + tid] += sc[256 + tid + off];
      }
      __syncthreads();
    }
    if (tid == 0) {
      int b = m0 >> 11;
      atomicAdd(&red[b * 2 + 0], sc[0]);
      atomicAdd(&red[b * 2 + 1], sc[256]);
    }
  }
}

// ---------------------------------------------------------------------------
// Attention stats + V-transform (MFMA): S = Q K^T (Q pre-scaled by log2e/8,
// so all exponentials are base-2 -> native v_exp_f32).
//   adj[s] = max_q S[q,s] + log2(sum_q 2^(S[q,s]-max))
// Tail (fused, block owns its 64 s-rows): Vt'[v,s] = V[s,v]*2^(-adj[s]).
// Block: 64 s (4 waves x 16), loops q-tiles of 64. Padded LDS stride 72.
// ---------------------------------------------------------------------------
__global__ __launch_bounds__(256) void attn_stats(const hbf* __restrict__ Q,
                                                  const hbf* __restrict__ K,
                                                  const hbf* __restrict__ V,
                                                  hbf* __restrict__ Vt) {
  __shared__ alignas(16) hbf Ks[64 * 72];
  __shared__ alignas(16) hbf Qs[64 * 72];
  __shared__ float sAdj[64];
  const int bh = blockIdx.y;
  const int s0 = blockIdx.x * 64;
  const int tid = threadIdx.x;
  const int wave = tid >> 6, lane = tid & 63;
  const int quad = lane >> 4, l16 = lane & 15;
  const int sw = wave * 16;
  const hbf* Kb = K + (size_t)bh * T_ * 64;
  const hbf* Qb = Q + (size_t)bh * T_ * 64;
  const hbf* Vb = V + (size_t)bh * T_ * 64;
  hbf* Vtb = Vt + (size_t)bh * 64 * T_;
  const int r_ = tid >> 3, c_ = (tid & 7) * 8;
#pragma unroll
  for (int c = 0; c < 2; c++) {
    int row = c * 32 + r_;
    *(float4*)(&Ks[row * 72 + c_]) =
        *(const float4*)(&Kb[(size_t)(s0 + row) * 64 + c_]);
  }
  __syncthreads();
  bf16x8 kf0 = ldfrag(&Ks[(sw + l16) * 72 + quad * 8]);
  bf16x8 kf1 = ldfrag(&Ks[(sw + l16) * 72 + 32 + quad * 8]);
  float m_thr[4], l_thr[4];
#pragma unroll
  for (int r = 0; r < 4; r++) {
    m_thr[r] = -1e30f;
    l_thr[r] = 0.f;
  }
  const f32x4 zero = {0.f, 0.f, 0.f, 0.f};
  for (int qt = 0; qt < T_ / 64; qt++) {
    if (qt) __syncthreads();
#pragma unroll
    for (int c = 0; c < 2; c++) {
      int row = c * 32 + r_;
      *(float4*)(&Qs[row * 72 + c_]) =
          *(const float4*)(&Qb[(size_t)(qt * 64 + row) * 64 + c_]);
    }
    __syncthreads();
    f32x4 acc[4];
#pragma unroll
    for (int j = 0; j < 4; j++) {
      bf16x8 qf0 = ldfrag(&Qs[(j * 16 + l16) * 72 + quad * 8]);
      bf16x8 qf1 = ldfrag(&Qs[(j * 16 + l16) * 72 + 32 + quad * 8]);
      f32x4 a = zero;
      a = mfma16(kf0, qf0, a);
      a = mfma16(kf1, qf1, a);
      acc[j] = a;
    }
#pragma unroll
    for (int r = 0; r < 4; r++) {
      float mt = fmaxf(fmaxf(acc[0][r], acc[1][r]),
                       fmaxf(acc[2][r], acc[3][r]));
      float nm = fmaxf(m_thr[r], mt);
      float s = l_thr[r] * fexp2(m_thr[r] - nm);
#pragma unroll
      for (int j = 0; j < 4; j++) s += fexp2(acc[j][r] - nm);
      l_thr[r] = s;
      m_thr[r] = nm;
    }
  }
#pragma unroll
  for (int d = 1; d < 16; d <<= 1) {
#pragma unroll
    for (int r = 0; r < 4; r++) {
      float om = __shfl_xor(m_thr[r], d);
      float ol = __shfl_xor(l_thr[r], d);
      float nm = fmaxf(m_thr[r], om);
      l_thr[r] = l_thr[r] * fexp2(m_thr[r] - nm) + ol * fexp2(om - nm);
      m_thr[r] = nm;
    }
  }
  if (l16 == 0) {
#pragma unroll
    for (int r = 0; r < 4; r++)
      sAdj[sw + quad * 4 + r] = m_thr[r] + flog2(l_thr[r]);
  }
  __syncthreads();
  // fused V scale+transpose for this block's s-range (reuse Ks as tile)
#pragma unroll
  for (int c = 0; c < 2; c++) {
    int e = (c * 256 + tid) * 8;
    int r = e >> 6, col = e & 63;
    union alignas(16) {
      hbf h[8];
      float4 f4;
    } u;
    u.f4 = *(const float4*)(&Vb[(size_t)(s0 + r) * 64 + col]);
    float sc = fexp2(-sAdj[r]);
#pragma unroll
    for (int k2 = 0; k2 < 8; k2++)
      u.h[k2] = __float2bfloat16(bf2f(u.h[k2]) * sc);
    *(float4*)(&Ks[r * 72 + col]) = u.f4;
  }
  __syncthreads();
#pragma unroll
  for (int c = 0; c < 2; c++) {
    int e = (c * 256 + tid) * 8;
    int v = e >> 6, tt = e & 63;
    union alignas(16) {
      hbf h[8];
      float4 f4;
    } u;
#pragma unroll
    for (int k2 = 0; k2 < 8; k2++) u.h[k2] = Ks[(tt + k2) * 72 + v];
    *(float4*)(&Vtb[(size_t)v * T_ + s0 + tt]) = u.f4;
  }
}

// ---------------------------------------------------------------------------
// Attention apply (MFMA): O[q,v] = sum_s 2^(S[q,s]) * V'[s,v]
// (normalizer folded into V'). Cross-iteration pipeline: iteration st
// computes QK^T(st) AND PV(st-1) so PV's MFMAs overlap QK's load/exp chain.
//  * K double-buffered (16KB), V triple-buffered (24KB), P per-wave
//    double-buffered (37KB). 77KB total -> 2 blocks/CU (grid cap).
//  * staging via global_load_lds + XOR swizzle, one barrier per iteration,
//    s_setprio(1) around MFMA clusters.
// Block: 128 q (4 waves x 32), s-tiles of 64, grid (16,32).
// ---------------------------------------------------------------------------
__global__ __launch_bounds__(256) void attn_apply(const hbf* __restrict__ Q,
                                                  const hbf* __restrict__ K,
                                                  const hbf* __restrict__ Vt,
                                                  hbf* __restrict__ heads) {
  __shared__ alignas(16) hbf Ksb[2 * 64 * 64];
  __shared__ alignas(16) hbf Vsb[3 * 64 * 64];
  __shared__ alignas(16) hbf Ps[4 * 2 * 32 * 72];
  const int bh = blockIdx.y;
  const int b = bh >> 4, h = bh & 15;
  const int q0 = blockIdx.x * 128;
  const int tid = threadIdx.x;
  const int wave = tid >> 6, lane = tid & 63;
  const int quad = lane >> 4, l16 = lane & 15;
  const int qw = wave * 32;
  const hbf* Qb = Q + (size_t)bh * T_ * 64;
  const hbf* Kb = K + (size_t)bh * T_ * 64;
  const hbf* Vtb = Vt + (size_t)bh * 64 * T_;
  hbf* Pw = &Ps[wave * (2 * 32 * 72)];
  // staging: lane -> LDS slot (row=tid>>3, chunk=tid&7); source chunk is
  // inverse-swizzled so LDS slot (r,c) holds global chunk c^(r&7).
  const int srow = tid >> 3, sc8 = tid & 7;
  const int swz = sc8 ^ (srow & 7);
  const hbf* gk = Kb + (size_t)srow * 64 + swz * 8;
  const hbf* gv = Vtb + (size_t)srow * T_ + swz * 8;
  hbf* lK = &Ksb[wave * 512];
  hbf* lV = &Vsb[wave * 512];
  const int sx = (l16 & 7) * 8;  // read-side elem swizzle for this lane's rows
  // Q fragments (B-operand): lane supplies Q[col=q(l16)][k=quad*8 in hh*32]
  bf16x8 qf[2][2];
#pragma unroll
  for (int i = 0; i < 2; i++)
#pragma unroll
    for (int hh = 0; hh < 2; hh++)
      qf[i][hh] = ldfrag(&Qb[(size_t)(q0 + qw + i * 16 + l16) * 64 + hh * 32 +
                             quad * 8]);
  const f32x4 zero = {0.f, 0.f, 0.f, 0.f};
  f32x4 accO[2][4];
#pragma unroll
  for (int i = 0; i < 2; i++)
#pragma unroll
    for (int j = 0; j < 4; j++) accO[i][j] = zero;

  // prologue: stage tiles 0 and 1 (K slots 0/1, V slots 0/1)
  glds16(gk, lK);
  glds16(gk + 2048, lK + 2048);
  glds16(gv, lV);
  glds16(gv + (size_t)32 * T_, lV + 2048);
  glds16(gk + 4096, lK + 4096);
  glds16(gk + 4096 + 2048, lK + 4096 + 2048);
  glds16(gv + 64, lV + 4096);
  glds16(gv + (size_t)32 * T_ + 64, lV + 4096 + 2048);
  __syncthreads();

  // prologue compute: QK^T(0) -> P[0] (no PV yet)
  {
    const hbf* Kc = &Ksb[0];
    bf16x8 kf[4][2];
#pragma unroll
    for (int j = 0; j < 4; j++)
#pragma unroll
      for (int hh = 0; hh < 2; hh++)
        kf[j][hh] =
            ldfrag(&Kc[(j * 16 + l16) * 64 + ((hh * 32 + quad * 8) ^ sx)]);
    __builtin_amdgcn_s_setprio(1);
    f32x4 accS[2][4];
#pragma unroll
    for (int i = 0; i < 2; i++)
#pragma unroll
      for (int j = 0; j < 4; j++) {
        f32x4 a = mfma16(kf[j][0], qf[i][0], zero);
        accS[i][j] = mfma16(kf[j][1], qf[i][1], a);
      }
    __builtin_amdgcn_s_setprio(0);
#pragma unroll
    for (int i = 0; i < 2; i++)
#pragma unroll
      for (int j = 0; j < 4; j++) {
        union {
          hbf h4[4];
          uint2 u;
        } pk;
#pragma unroll
        for (int r = 0; r < 4; r++)
          pk.h4[r] = __float2bfloat16(fexp2(accS[i][j][r]));
        *(uint2*)&Pw[(i * 16 + l16) * 72 + j * 16 + quad * 4] = pk.u;
      }
  }
  __syncthreads();  // protect K slot 0 from the st=1 prefetch (tile 2)

  for (int st = 1; st < T_ / 64; st++) {
    const int kcur = st & 1;
    const int pcur = st & 1, pprev = pcur ^ 1;
    const int vprev = (st - 1) % 3;
    if (st < T_ / 64 - 1) {  // async prefetch tile st+1 (drains at barrier)
      const int knxt = (st + 1) & 1, vnxt = (st + 1) % 3;
      size_t ko = (size_t)(st + 1) * 4096;
      glds16(gk + ko, lK + knxt * 4096);
      glds16(gk + ko + 2048, lK + knxt * 4096 + 2048);
      glds16(gv + (st + 1) * 64, lV + vnxt * 4096);
      glds16(gv + (size_t)32 * T_ + (st + 1) * 64, lV + vnxt * 4096 + 2048);
    }
    const hbf* Kc = &Ksb[kcur * 4096];
    const hbf* Vp = &Vsb[vprev * 4096];
    // issue kf loads for QK(st) early (in-order lgkm: complete before pf use)
    bf16x8 kf[4][2];
#pragma unroll
    for (int j = 0; j < 4; j++)
#pragma unroll
      for (int hh = 0; hh < 2; hh++)
        kf[j][hh] =
            ldfrag(&Kc[(j * 16 + l16) * 64 + ((hh * 32 + quad * 8) ^ sx)]);
    // PV(st-1): A = P[prev] rows q, B = V'[prev] rows v
    bf16x8 pf[2][2];
#pragma unroll
    for (int i = 0; i < 2; i++)
#pragma unroll
      for (int hh = 0; hh < 2; hh++)
        pf[i][hh] = ldfrag(
            &Pw[pprev * (32 * 72) + (i * 16 + l16) * 72 + hh * 32 + quad * 8]);
    __builtin_amdgcn_s_setprio(1);
#pragma unroll
    for (int j2 = 0; j2 < 4; j2++) {
      bf16x8 vf0 = ldfrag(&Vp[(j2 * 16 + l16) * 64 + ((quad * 8) ^ sx)]);
      bf16x8 vf1 = ldfrag(&Vp[(j2 * 16 + l16) * 64 + ((32 + quad * 8) ^ sx)]);
#pragma unroll
      for (int i = 0; i < 2; i++) {
        accO[i][j2] = mfma16(pf[i][0], vf0, accO[i][j2]);
        accO[i][j2] = mfma16(pf[i][1], vf1, accO[i][j2]);
      }
    }
    // QK^T(st) swapped: accS[i][j] = D[s][q]
    f32x4 accS[2][4];
#pragma unroll
    for (int i = 0; i < 2; i++)
#pragma unroll
      for (int j = 0; j < 4; j++) {
        f32x4 a = mfma16(kf[j][0], qf[i][0], zero);
        accS[i][j] = mfma16(kf[j][1], qf[i][1], a);
      }
    __builtin_amdgcn_s_setprio(0);
    // exp2 -> bf16 pack -> P[cur] (8 b64 writes, s-consecutive)
#pragma unroll
    for (int i = 0; i < 2; i++)
#pragma unroll
      for (int j = 0; j < 4; j++) {
        union {
          hbf h4[4];
          uint2 u;
        } pk;
#pragma unroll
        for (int r = 0; r < 4; r++)
          pk.h4[r] = __float2bfloat16(fexp2(accS[i][j][r]));
        *(uint2*)&Pw[pcur * (32 * 72) + (i * 16 + l16) * 72 + j * 16 +
                     quad * 4] = pk.u;
      }
    __syncthreads();
  }
  // epilogue: PV(last tile): P[(T/64-1)&1], V[(T/64-1)%3]
  {
    const int pl = (T_ / 64 - 1) & 1;
    const hbf* Vp = &Vsb[((T_ / 64 - 1) % 3) * 4096];
    bf16x8 pf[2][2];
#pragma unroll
    for (int i = 0; i < 2; i++)
#pragma unroll
      for (int hh = 0; hh < 2; hh++)
        pf[i][hh] = ldfrag(
            &Pw[pl * (32 * 72) + (i * 16 + l16) * 72 + hh * 32 + quad * 8]);
    __builtin_amdgcn_s_setprio(1);
#pragma unroll
    for (int j2 = 0; j2 < 4; j2++) {
      bf16x8 vf0 = ldfrag(&Vp[(j2 * 16 + l16) * 64 + ((quad * 8) ^ sx)]);
      bf16x8 vf1 = ldfrag(&Vp[(j2 * 16 + l16) * 64 + ((32 + quad * 8) ^ sx)]);
#pragma unroll
      for (int i = 0; i < 2; i++) {
        accO[i][j2] = mfma16(pf[i][0], vf0, accO[i][j2]);
        accO[i][j2] = mfma16(pf[i][1], vf1, accO[i][j2]);
      }
    }
    __builtin_amdgcn_s_setprio(0);
  }
#pragma unroll
  for (int i = 0; i < 2; i++)
#pragma unroll
    for (int j2 = 0; j2 < 4; j2++)
#pragma unroll
      for (int r = 0; r < 4; r++) {
        int q = q0 + qw + i * 16 + quad * 4 + r;
        int v = j2 * 16 + l16;
        heads[((size_t)(b * T_ + q)) * D_ + h * 64 + v] =
            __float2bfloat16(accO[i][j2][r]);
      }
}

// ---------------------------------------------------------------------------
// LN1 normalize (stats came fused from the out-proj GEMM).
// ---------------------------------------------------------------------------
__global__ __launch_bounds__(256) void ln_norm(const hbf* __restrict__ src,
                                               const float* __restrict__ red,
                                               void* dst,
                                               const int* __restrict__ flag,
                                               int force_bf) {
  const int isbf = force_bf ? 1 : *flag;
  const float invN = 1.f / (float)(T_ * D_);
  for (size_t i = (size_t)blockIdx.x * 256 + threadIdx.x;
       i < (size_t)B_ * T_ * D_; i += (size_t)gridDim.x * 256) {
    int b = (int)(i >> 21);
    float mu = red[b * 2 + 0] * invN;
    float var = red[b * 2 + 1] * invN - mu * mu;
    ston(dst, i, (bf2f(src[i]) - mu) * rsqrtf(var + EPS_), isbf);
  }
}

// ---------------------------------------------------------------------------
// LN2 stats over r2 = P0+P1+b2+o1 (r2 never materialized). Vectorized:
// float4 partial loads + uint2 (4x bf16) o1/b2 loads (G13).
// ---------------------------------------------------------------------------
__global__ __launch_bounds__(256) void ln2_stats(const float* __restrict__ P0,
                                                 const float* __restrict__ P1,
                                                 const hbf* __restrict__ o1,
                                                 const hbf* __restrict__ b2b,
                                                 float* __restrict__ red) {
  __shared__ float s1[256], s2[256];
  const int b = blockIdx.y;
  const size_t base = (size_t)b * (T_ * D_ / 4);
  const float4* P0v = (const float4*)P0;
  const float4* P1v = (const float4*)P1;
  const uint2* o1v = (const uint2*)o1;
  const uint2* b2v = (const uint2*)b2b;
  float sum = 0.f, sq = 0.f;
  for (size_t i = (size_t)blockIdx.x * 256 + threadIdx.x;
       i < (size_t)(T_ * D_ / 4); i += (size_t)gridDim.x * 256) {
    float4 p0 = P0v[base + i], p1 = P1v[base + i];
    union {
      uint2 u;
      hbf h[4];
    } o, bb;
    o.u = o1v[base + i];
    bb.u = b2v[i & (D_ / 4 - 1)];
#pragma unroll
    for (int r = 0; r < 4; r++) {
      float v = (&p0.x)[r] + (&p1.x)[r] + bf2f(bb.h[r]) + bf2f(o.h[r]);
      sum += v;
      sq += v * v;
    }
  }
  s1[threadIdx.x] = sum;
  s2[threadIdx.x] = sq;
  __syncthreads();
  for (int off = 128; off > 0; off >>= 1) {
    if ((int)threadIdx.x < off) {
      s1[threadIdx.x] += s1[threadIdx.x + off];
      s2[threadIdx.x] += s2[threadIdx.x + off];
    }
    __syncthreads();
  }
  if (threadIdx.x == 0) {
    atomicAdd(&red[b * 2 + 0], s1[0]);
    atomicAdd(&red[b * 2 + 1], s2[0]);
  }
}

__global__ __launch_bounds__(256) void ln2_norm(
    const float* __restrict__ P0, const float* __restrict__ P1,
    const hbf* __restrict__ o1, const hbf* __restrict__ b2b,
    const float* __restrict__ red, void* dst, const int* __restrict__ flag) {
  const int isbf = *flag;
  const float invN = 1.f / (float)(T_ * D_);
  const float4* P0v = (const float4*)P0;
  const float4* P1v = (const float4*)P1;
  const uint2* o1v = (const uint2*)o1;
  const uint2* b2v = (const uint2*)b2b;
  for (size_t i = (size_t)blockIdx.x * 256 + threadIdx.x;
       i < (size_t)B_ * T_ * D_ / 4; i += (size_t)gridDim.x * 256) {
    int b = (int)(i >> 19);  // per-batch float4 count = T*D/4 = 2^19
    float mu = red[b * 2 + 0] * invN;
    float var = red[b * 2 + 1] * invN - mu * mu;
    float rstd = rsqrtf(var + EPS_);
    float4 p0 = P0v[i], p1 = P1v[i];
    union {
      uint2 u;
      hbf h[4];
    } o, bb;
    o.u = o1v[i];
    bb.u = b2v[i & (D_ / 4 - 1)];
    float out[4];
#pragma unroll
    for (int r = 0; r < 4; r++)
      out[r] =
          ((&p0.x)[r] + (&p1.x)[r] + bf2f(bb.h[r]) + bf2f(o.h[r]) - mu) * rstd;
    if (isbf) {
      union {
        hbf h[4];
        uint2 u;
      } pk;
#pragma unroll
      for (int r = 0; r < 4; r++) pk.h[r] = __float2bfloat16(out[r]);
      ((uint2*)dst)[i] = pk.u;
    } else {
      float4 f{out[0], out[1], out[2], out[3]};
      ((float4*)dst)[i] = f;
    }
  }
}

// ---------------------------------------------------------------------------
// Workspace (MiB offsets), ~88.1 MB total:
//  [0,8) xb | [8,14) Wqkvt | [14,16) Wot | [16,24) W1t | [24,32) W2t
//  [32,40) Q | [40,48) K | [48,56) V | [56,64) Vt | [64,72) heads
//  [72,80) r1 | [80,88) o1 | ff1 aliases [32,64)
//  split-K partials (fp32, 16 MB each): P0 over [0,16), P1 over [64,80)
//  [88,..) b1b 8K | b2b 2K | red 32B | flag 4B
// ---------------------------------------------------------------------------
extern "C" void kernel_launch(void* const* d_in, const int* in_sizes, int n_in,
                              void* d_out, int out_size, void* d_ws,
                              size_t ws_size, hipStream_t stream) {
  const void* x = d_in[0];
  const void* Wq = d_in[1];
  const void* Wk = d_in[2];
  const void* Wv = d_in[3];
  const void* Wo = d_in[4];
  const void* W1 = d_in[5];
  const void* W2 = d_in[7];
  const void* b1 = d_in[6];
  const void* b2 = d_in[8];

  const size_t MB = 1024 * 1024;
  if (ws_size < 89 * MB) return;

  char* w = (char*)d_ws;
  hbf* xb = (hbf*)(w + 0 * MB);
  hbf* wqkvt = (hbf*)(w + 8 * MB);
  hbf* wot = (hbf*)(w + 14 * MB);
  hbf* w1t = (hbf*)(w + 16 * MB);
  hbf* w2t = (hbf*)(w + 24 * MB);
  hbf* Qb = (hbf*)(w + 32 * MB);
  hbf* Kb = (hbf*)(w + 40 * MB);
  hbf* Vb = (hbf*)(w + 48 * MB);
  hbf* Vtb = (hbf*)(w + 56 * MB);
  hbf* heads = (hbf*)(w + 64 * MB);
  hbf* r1 = (hbf*)(w + 72 * MB);
  hbf* o1 = (hbf*)(w + 80 * MB);
  hbf* ff1 = (hbf*)(w + 32 * MB);   // over dead Q/K/V/Vt
  float* P0 = (float*)(w + 0 * MB);   // over dead xb/wqkvt/wot (16 MB)
  float* P1 = (float*)(w + 64 * MB);  // over dead heads/r1 (16 MB)
  hbf* b1b = (hbf*)(w + 88 * MB);
  hbf* b2b = b1b + FF_;
  float* red = (float*)(b2b + D_);
  int* flag = (int*)(red + 8);

  hipMemsetAsync(red, 0, 8 * sizeof(float) + sizeof(int), stream);
  detect_dtype<<<1, 256, 0, stream>>>((const unsigned*)x, flag);

  const int M = B_ * T_;  // 4096
  // --- one-launch preconversion ---
  preconv<<<13314, 256, 0, stream>>>(x, Wq, Wk, Wv, Wo, W1, W2, b1, b2, xb,
                                     wqkvt, wot, w1t, w2t, b1b, b2b, flag);
  // --- QKV fused projection (Q pre-scaled by log2e/8) ---
  gemm_bt<0, 128, 128, 64><<<dim3(24, 32), 256, 0, stream>>>(
      xb, wqkvt, Qb, nullptr, nullptr, nullptr, nullptr, M, 3 * D_, D_, D_);
  // --- attention: col-softmax stats + fused V scale/transpose, then apply ---
  attn_stats<<<dim3(32, 32), 256, 0, stream>>>(Qb, Kb, Vb, Vtb);
  attn_apply<<<dim3(16, 32), 256, 0, stream>>>(Qb, Kb, Vtb, heads);
  // --- out-proj + residual + fused LN1 stats ---
  gemm_bt<1, 128, 64, 64><<<dim3(16, 32), 256, 0, stream>>>(
      heads, wot, r1, nullptr, nullptr, xb, red, M, D_, D_, D_);
  ln_norm<<<4096, 256, 0, stream>>>(r1, red, o1, flag, 1);
  // --- FFN1 ---
  gemm_bt<2, 128, 128, 64><<<dim3(32, 32), 256, 0, stream>>>(
      o1, w1t, ff1, nullptr, nullptr, b1b, nullptr, M, FF_, D_, D_);
  // --- FFN2 split-K=2 -> fp32 partials (BN=128: 32 MFMA/barrier + 512 blk) ---
  gemm_bt<4, 128, 128, 64><<<dim3(8, 32, 2), 256, 0, stream>>>(
      ff1, w2t, nullptr, P0, P1, nullptr, nullptr, M, D_, FF_ / 2, FF_);
  // --- LN2 (r2 = P0+P1+b2+o1, never materialized; vectorized) ---
  ln2_stats<<<dim3(256, B_), 256, 0, stream>>>(P0, P1, o1, b2b, red + 4);
  ln2_norm<<<2048, 256, 0, stream>>>(P0, P1, o1, b2b, red + 4, d_out, flag);
}

// Round 10
// 440.919 us; speedup vs baseline: 1.0926x; 1.0225x over previous
//
#include <hip/hip_runtime.h>
#include <hip/hip_bf16.h>
#include <cstddef>
#include <cstdint>

typedef __hip_bfloat16 hbf;
typedef __attribute__((ext_vector_type(8))) __bf16 bf16x8;
typedef __attribute__((ext_vector_type(4))) float f32x4;

#define B_ 2
#define T_ 2048
#define D_ 1024
#define H_ 16
#define FF_ 4096
#define EPS_ 1e-5f
// Q pre-scale = log2(e)/sqrt(dk): attention exponentials become native exp2
#define SCALE_ 0.18033688011112f

__device__ __forceinline__ float bf2f(hbf v) { return __bfloat162float(v); }
__device__ __forceinline__ float fexp2(float x) {
  return __builtin_amdgcn_exp2f(x);  // v_exp_f32 (2^x native)
}
__device__ __forceinline__ float flog2(float x) {
  return __builtin_amdgcn_logf(x);  // v_log_f32 (log2 native)
}
__device__ __forceinline__ float ldin(const void* p, size_t i, int isbf) {
  return isbf ? __bfloat162float(((const hbf*)p)[i]) : ((const float*)p)[i];
}
__device__ __forceinline__ void ston(void* p, size_t i, float v, int isbf) {
  if (isbf) ((hbf*)p)[i] = __float2bfloat16(v);
  else ((float*)p)[i] = v;
}
__device__ __forceinline__ f32x4 mfma16(bf16x8 a, bf16x8 b, f32x4 c) {
  return __builtin_amdgcn_mfma_f32_16x16x32_bf16(a, b, c, 0, 0, 0);
}
__device__ __forceinline__ bf16x8 ldfrag(const hbf* p) {
  return *(const bf16x8*)p;
}
// async global->LDS, 16B/lane; LDS base wave-uniform (HW: lane i -> base+i*16)
__device__ __forceinline__ void glds16(const hbf* g, hbf* l) {
  __builtin_amdgcn_global_load_lds(
      (const __attribute__((address_space(1))) void*)g,
      (__attribute__((address_space(3))) void*)l, 16, 0, 0);
}

// ---------------------------------------------------------------------------
// Runtime input-dtype detection (bf16 vs fp32), from bit patterns of x.
// ---------------------------------------------------------------------------
__global__ __launch_bounds__(256) void detect_dtype(const unsigned* x,
                                                    int* flag) {
  __shared__ int cnt[256];
  int c = 0;
  for (int i = threadIdx.x; i < 4096; i += 256) {
    unsigned low = x[i] & 0xFFFFu;
    unsigned e = (low >> 7) & 0xFFu;
    if (e >= 100u && e <= 142u) c++;
  }
  cnt[threadIdx.x] = c;
  __syncthreads();
  for (int off = 128; off > 0; off >>= 1) {
    if ((int)threadIdx.x < off) cnt[threadIdx.x] += cnt[threadIdx.x + off];
    __syncthreads();
  }
  if (threadIdx.x == 0) *flag = (cnt[0] > 2458) ? 1 : 0;
}

// ---------------------------------------------------------------------------
// Mega-preconversion: one launch does all weight transposes + x/bias converts.
// Flat block-id job table:
//  [0,3072)      Wq/Wk/Wv -> wqkvt (head-sliced transpose, R=1024,C=64,z=16)
//  [3072,4096)   Wo -> wot          (1024x1024)
//  [4096,8192)   W1 -> w1t          (1024x4096)
//  [8192,12288)  W2 -> w2t          (4096x1024)
//  [12288,13312) x -> xb            (4M elements, 4096/block, vectorized)
//  13312: b1 -> b1b ; 13313: b2 -> b2b
// ---------------------------------------------------------------------------
__device__ __forceinline__ void tr_tile(const void* __restrict__ src,
                                        hbf* __restrict__ dst, int R, int C,
                                        size_t zoff, int cx, int ry, int f,
                                        float (*tile)[33]) {
  const int tx = threadIdx.x & 31, ty = threadIdx.x >> 5;
  const int c0 = cx * 32, r0 = ry * 32;
#pragma unroll
  for (int p = 0; p < 4; p++) {
    int rr = p * 8 + ty;
    tile[rr][tx] = ldin(src, zoff + (size_t)(r0 + rr) * C + c0 + tx, f);
  }
  __syncthreads();
#pragma unroll
  for (int p = 0; p < 4; p++) {
    int cc = p * 8 + ty;
    dst[zoff + (size_t)(c0 + cc) * R + r0 + tx] = __float2bfloat16(tile[tx][cc]);
  }
}

__global__ __launch_bounds__(256) void preconv(
    const void* __restrict__ x, const void* __restrict__ Wq,
    const void* __restrict__ Wk, const void* __restrict__ Wv,
    const void* __restrict__ Wo, const void* __restrict__ W1,
    const void* __restrict__ W2, const void* __restrict__ b1,
    const void* __restrict__ b2, hbf* __restrict__ xb,
    hbf* __restrict__ wqkvt, hbf* __restrict__ wot, hbf* __restrict__ w1t,
    hbf* __restrict__ w2t, hbf* __restrict__ b1b, hbf* __restrict__ b2b,
    const int* __restrict__ flag) {
  __shared__ float tile[32][33];
  const int f = *flag;
  const int bid = blockIdx.x;
  if (bid < 3072) {
    int which = bid >> 10;  // 0=Wq 1=Wk 2=Wv
    int r = bid & 1023;
    int z = r >> 6, rem = r & 63;
    int ry = rem >> 1, cx = rem & 1;
    const void* src = (which == 0) ? Wq : (which == 1) ? Wk : Wv;
    hbf* dst = wqkvt + (size_t)which * (D_ * D_);
    tr_tile(src, dst, 1024, 64, (size_t)z * 65536, cx, ry, f, tile);
  } else if (bid < 4096) {
    int t = bid - 3072;
    tr_tile(Wo, wot, 1024, 1024, 0, t & 31, t >> 5, f, tile);
  } else if (bid < 8192) {
    int t = bid - 4096;
    tr_tile(W1, w1t, 1024, 4096, 0, t & 127, t >> 7, f, tile);
  } else if (bid < 12288) {
    int t = bid - 8192;
    tr_tile(W2, w2t, 4096, 1024, 0, t & 31, t >> 5, f, tile);
  } else if (bid < 13312) {
    size_t base = (size_t)(bid - 12288) * 4096;
    if (f) {
      // bf16 input: straight 16B copies
      const uint4* src = (const uint4*)((const hbf*)x + base);
      uint4* dst = (uint4*)(xb + base);
      for (int i = threadIdx.x; i < 512; i += 256) dst[i] = src[i];
    } else {
      // fp32 input: float4 x2 -> 8 bf16 packed (uint2x2)
      const float4* src = (const float4*)((const float*)x + base);
      for (int i = threadIdx.x; i < 512; i += 256) {
        float4 a = src[i * 2], b = src[i * 2 + 1];
        union {
          hbf h[8];
          uint4 u;
        } o;
        o.h[0] = __float2bfloat16(a.x);
        o.h[1] = __float2bfloat16(a.y);
        o.h[2] = __float2bfloat16(a.z);
        o.h[3] = __float2bfloat16(a.w);
        o.h[4] = __float2bfloat16(b.x);
        o.h[5] = __float2bfloat16(b.y);
        o.h[6] = __float2bfloat16(b.z);
        o.h[7] = __float2bfloat16(b.w);
        *(uint4*)(xb + base + (size_t)i * 8) = o.u;
      }
    }
  } else if (bid == 13312) {
    for (int i = threadIdx.x; i < FF_; i += 256)
      b1b[i] = __float2bfloat16(ldin(b1, i, f));
  } else {
    for (int i = threadIdx.x; i < D_; i += 256)
      b2b[i] = __float2bfloat16(ldin(b2, i, f));
  }
}

// ---------------------------------------------------------------------------
// MFMA GEMM (m97 structure): C(MxN) = A(MxK) @ Bt(NxK)^T, bf16, fp32 accum.
// BMxBN tile, BK=64, glds width-16 staging, 4 waves 2x2. Used for QKV,
// out-proj, FFN2-splitK (grids too small / ill-shaped for the 256 tile).
// Ledger: scalar epilogue; BK=64 (128 regressed: conflicts 12.6M->44M);
// no XCD swizzle (natural dispatch = bx%8 per XCD, fits L2; swizzle
// thrashed FETCH 41->70MB); FFN2 split-K z=2 BN=128.
// MODE 0: QKV fused (N=3072): scatter to (which,B,H,T,64); Q scaled.
// MODE 1: C = acc + e1[m*N+n]; fused LN stats -> atomicAdd red[batch]
// MODE 2: C = relu(acc + e1[n])            (FFN1 + bias; now unused)
// MODE 4: Cf_z[m*N+n] = acc  (fp32 split-K partial, z = blockIdx.z)
// ---------------------------------------------------------------------------
template <int MODE, int BM, int BN, int BK>
__global__ __launch_bounds__(256) void gemm_bt(
    const hbf* __restrict__ A, const hbf* __restrict__ Bt, hbf* __restrict__ C,
    float* __restrict__ Cf0, float* __restrict__ Cf1,
    const hbf* __restrict__ e1, float* __restrict__ red, int M, int N, int K,
    int LDK) {
  constexpr int WM = BM / 2, WN = BN / 2;
  constexpr int IF = WM / 16, JF = WN / 16;
  constexpr int HK = BK / 32;     // 32-wide k-chunks per K-step
  constexpr int LPT = BK / 8;     // lanes covering one row (8 hbf/lane)
  constexpr int CPR = 2048 / BK;  // rows staged per glds chunk (4KB)
  __shared__ alignas(16) hbf As[BM * BK];
  __shared__ alignas(16) hbf Bs[BN * BK];
  const int tid = threadIdx.x;
  const int wave = tid >> 6, lane = tid & 63;
  const int quad = lane >> 4, l16 = lane & 15;
  const int m0 = blockIdx.y * BM, n0 = blockIdx.x * BN;
  const int mw = (wave >> 1) * WM, nw = (wave & 1) * WN;
  const int srow = tid / LPT;
  const int scol = (tid % LPT) * 8;
  const int kbase = (MODE == 4) ? blockIdx.z * K : 0;
  const f32x4 zero = {0.f, 0.f, 0.f, 0.f};
  f32x4 acc[IF][JF];
#pragma unroll
  for (int i = 0; i < IF; i++)
#pragma unroll
    for (int j = 0; j < JF; j++) acc[i][j] = zero;

  const hbf* ga = &A[(size_t)(m0 + srow) * LDK + kbase + scol];
  const hbf* gb = &Bt[(size_t)(n0 + srow) * LDK + kbase + scol];
  hbf* lA = &As[wave * 512];
  hbf* lB = &Bs[wave * 512];

  for (int k0 = 0; k0 < K; k0 += BK) {
#pragma unroll
    for (int c = 0; c < BM / CPR; c++)
      glds16(ga + (size_t)(c * CPR) * LDK + k0, lA + c * 2048);
#pragma unroll
    for (int c = 0; c < BN / CPR; c++)
      glds16(gb + (size_t)(c * CPR) * LDK + k0, lB + c * 2048);
    __syncthreads();
    bf16x8 af[HK][IF], bfr[HK][JF];
#pragma unroll
    for (int h = 0; h < HK; h++) {
#pragma unroll
      for (int i = 0; i < IF; i++)
        af[h][i] = ldfrag(&As[(mw + i * 16 + l16) * BK + h * 32 + quad * 8]);
#pragma unroll
      for (int j = 0; j < JF; j++)
        bfr[h][j] = ldfrag(&Bs[(nw + j * 16 + l16) * BK + h * 32 + quad * 8]);
    }
#pragma unroll
    for (int h = 0; h < HK; h++)
#pragma unroll
      for (int i = 0; i < IF; i++)
#pragma unroll
        for (int j = 0; j < JF; j++)
          acc[i][j] = mfma16(af[h][i], bfr[h][j], acc[i][j]);
    __syncthreads();
  }
  float ssum = 0.f, ssq = 0.f;
#pragma unroll
  for (int i = 0; i < IF; i++)
#pragma unroll
    for (int j = 0; j < JF; j++)
#pragma unroll
      for (int r = 0; r < 4; r++) {
        int m = m0 + mw + i * 16 + quad * 4 + r;
        int n = n0 + nw + j * 16 + l16;
        float v = acc[i][j][r];
        if (MODE == 0) {
          int which = n >> 10, n1 = n & 1023;
          int h = n1 >> 6, cc = n1 & 63;
          int b = m >> 11, t = m & (T_ - 1);
          if (which == 0) v *= SCALE_;  // pre-scale Q by log2e/sqrt(dk)
          C[(size_t)which * ((size_t)B_ * H_ * T_ * 64) +
            (((size_t)(b * H_ + h)) * T_ + t) * 64 + cc] = __float2bfloat16(v);
        } else if (MODE == 1) {
          hbf hv = __float2bfloat16(v + bf2f(e1[(size_t)m * N + n]));
          C[(size_t)m * N + n] = hv;
          float fv = bf2f(hv);
          ssum += fv;
          ssq += fv * fv;
        } else if (MODE == 2) {
          C[(size_t)m * N + n] = __float2bfloat16(fmaxf(v + bf2f(e1[n]), 0.f));
        } else if (MODE == 4) {
          float* Cf = blockIdx.z ? Cf1 : Cf0;
          Cf[(size_t)m * N + n] = v;
        }
      }
  if (MODE == 1) {
    // fused LN stats: block tile lies within one batch (BM=128 | 2048)
    float* sc = (float*)As;  // dead LDS reuse (post final barrier)
    sc[tid] = ssum;
    sc[256 + tid] = ssq;
    __syncthreads();
    for (int off = 128; off > 0; off >>= 1) {
      if (tid < off) {
        sc[tid] += sc[tid + off];
        sc[256 + tid] += sc[256 + tid + off];
      }
      __syncthreads();
    }
    if (tid == 0) {
      int b = m0 >> 11;
      atomicAdd(&red[b * 2 + 0], sc[0]);
      atomicAdd(&red[b * 2 + 1], sc[256]);
    }
  }
}

// ---------------------------------------------------------------------------
// 256x256-tile double-buffered GEMM for FFN1 (the one GEMM whose grid is
// exactly 256 blocks at this tile). C = relu(A @ Bt^T + bias[n]).
// Structural upgrade over the 128 2-barrier kernel (FFN1: 494 TF, MfmaUtil
// 19.7%, stall-bound): 8 waves (2x4), per-wave C = 128x64, 64 MFMA per wave
// per K-tile against ONE barrier (double-buffered LDS, prefetch of tile t+1
// issued BEFORE compute of tile t so the vmcnt drain at the barrier is
// overlapped). LDS 128KB -> 1 block/CU (grid = 1/CU anyway).
// Per K-tile: 8 glds16 (A 4x64-row chunks + B 4), 24 ds_read_b128, 64 MFMA.
// Numerics: identical K-accumulation order to the 128 kernel.
// ---------------------------------------------------------------------------
__global__ __launch_bounds__(512) void gemm256_relu(
    const hbf* __restrict__ A, const hbf* __restrict__ Bt, hbf* __restrict__ C,
    const hbf* __restrict__ bias, int N, int K, int LDK) {
  __shared__ alignas(16) hbf As[2][256 * 64];
  __shared__ alignas(16) hbf Bs[2][256 * 64];
  const int tid = threadIdx.x;
  const int wave = tid >> 6, lane = tid & 63;
  const int quad = lane >> 4, l16 = lane & 15;
  const int wr = wave >> 2, wc = wave & 3;  // 2x4 wave grid
  const int m0 = blockIdx.y * 256, n0 = blockIdx.x * 256;
  const int mw = wr * 128, nw = wc * 64;
  const int srow = tid >> 3;       // 0..63 (rows within a 64-row chunk)
  const int scol = (tid & 7) * 8;  // 0..56
  const hbf* ga = &A[(size_t)(m0 + srow) * LDK + scol];
  const hbf* gb = &Bt[(size_t)(n0 + srow) * LDK + scol];
  const int lbase = wave * 512;  // wave-uniform LDS base within a chunk
  const f32x4 zero = {0.f, 0.f, 0.f, 0.f};
  f32x4 acc[8][4];
#pragma unroll
  for (int i = 0; i < 8; i++)
#pragma unroll
    for (int j = 0; j < 4; j++) acc[i][j] = zero;

  const int NT = K / 64;
  // prologue: stage tile 0 into buffer 0
#pragma unroll
  for (int c = 0; c < 4; c++) {
    glds16(ga + (size_t)(c * 64) * LDK, &As[0][c * 4096 + lbase]);
    glds16(gb + (size_t)(c * 64) * LDK, &Bs[0][c * 4096 + lbase]);
  }
  __syncthreads();

  for (int t = 0; t < NT; t++) {
    const int cur = t & 1;
    if (t < NT - 1) {  // async prefetch t+1 into the other buffer;
                       // drains at the end-of-iteration barrier
      size_t ko = (size_t)(t + 1) * 64;
#pragma unroll
      for (int c = 0; c < 4; c++) {
        glds16(ga + (size_t)(c * 64) * LDK + ko,
               &As[cur ^ 1][c * 4096 + lbase]);
        glds16(gb + (size_t)(c * 64) * LDK + ko,
               &Bs[cur ^ 1][c * 4096 + lbase]);
      }
    }
    // compute tile t from buffer cur: 2 k-halves x (8 m x 4 n) MFMA
#pragma unroll
    for (int h = 0; h < 2; h++) {
      bf16x8 bfr[4];
#pragma unroll
      for (int j = 0; j < 4; j++)
        bfr[j] = ldfrag(&Bs[cur][(nw + j * 16 + l16) * 64 + h * 32 + quad * 8]);
#pragma unroll
      for (int i = 0; i < 8; i++) {
        bf16x8 af =
            ldfrag(&As[cur][(mw + i * 16 + l16) * 64 + h * 32 + quad * 8]);
#pragma unroll
        for (int j = 0; j < 4; j++)
          acc[i][j] = mfma16(af, bfr[j], acc[i][j]);
      }
    }
    __syncthreads();  // drains prefetch vmcnt + protects buffer reuse
  }
  // epilogue: relu(acc + bias[n])
#pragma unroll
  for (int i = 0; i < 8; i++)
#pragma unroll
    for (int j = 0; j < 4; j++)
#pragma unroll
      for (int r = 0; r < 4; r++) {
        int m = m0 + mw + i * 16 + quad * 4 + r;
        int n = n0 + nw + j * 16 + l16;
        C[(size_t)m * N + n] =
            __float2bfloat16(fmaxf(acc[i][j][r] + bf2f(bias[n]), 0.f));
      }
}

// ---------------------------------------------------------------------------
// Attention stats + V-transform (MFMA): S = Q K^T (Q pre-scaled by log2e/8,
// so all exponentials are base-2 -> native v_exp_f32).
//   adj[s] = max_q S[q,s] + log2(sum_q 2^(S[q,s]-max))
// Tail (fused, block owns its 64 s-rows): Vt'[v,s] = V[s,v]*2^(-adj[s]).
// Block: 64 s (4 waves x 16), loops q-tiles of 64. Padded LDS stride 72.
// ---------------------------------------------------------------------------
__global__ __launch_bounds__(256) void attn_stats(const hbf* __restrict__ Q,
                                                  const hbf* __restrict__ K,
                                                  const hbf* __restrict__ V,
                                                  hbf* __restrict__ Vt) {
  __shared__ alignas(16) hbf Ks[64 * 72];
  __shared__ alignas(16) hbf Qs[64 * 72];
  __shared__ float sAdj[64];
  const int bh = blockIdx.y;
  const int s0 = blockIdx.x * 64;
  const int tid = threadIdx.x;
  const int wave = tid >> 6, lane = tid & 63;
  const int quad = lane >> 4, l16 = lane & 15;
  const int sw = wave * 16;
  const hbf* Kb = K + (size_t)bh * T_ * 64;
  const hbf* Qb = Q + (size_t)bh * T_ * 64;
  const hbf* Vb = V + (size_t)bh * T_ * 64;
  hbf* Vtb = Vt + (size_t)bh * 64 * T_;
  const int r_ = tid >> 3, c_ = (tid & 7) * 8;
#pragma unroll
  for (int c = 0; c < 2; c++) {
    int row = c * 32 + r_;
    *(float4*)(&Ks[row * 72 + c_]) =
        *(const float4*)(&Kb[(size_t)(s0 + row) * 64 + c_]);
  }
  __syncthreads();
  bf16x8 kf0 = ldfrag(&Ks[(sw + l16) * 72 + quad * 8]);
  bf16x8 kf1 = ldfrag(&Ks[(sw + l16) * 72 + 32 + quad * 8]);
  float m_thr[4], l_thr[4];
#pragma unroll
  for (int r = 0; r < 4; r++) {
    m_thr[r] = -1e30f;
    l_thr[r] = 0.f;
  }
  const f32x4 zero = {0.f, 0.f, 0.f, 0.f};
  for (int qt = 0; qt < T_ / 64; qt++) {
    if (qt) __syncthreads();
#pragma unroll
    for (int c = 0; c < 2; c++) {
      int row = c * 32 + r_;
      *(float4*)(&Qs[row * 72 + c_]) =
          *(const float4*)(&Qb[(size_t)(qt * 64 + row) * 64 + c_]);
    }
    __syncthreads();
    f32x4 acc[4];
#pragma unroll
    for (int j = 0; j < 4; j++) {
      bf16x8 qf0 = ldfrag(&Qs[(j * 16 + l16) * 72 + quad * 8]);
      bf16x8 qf1 = ldfrag(&Qs[(j * 16 + l16) * 72 + 32 + quad * 8]);
      f32x4 a = zero;
      a = mfma16(kf0, qf0, a);
      a = mfma16(kf1, qf1, a);
      acc[j] = a;
    }
#pragma unroll
    for (int r = 0; r < 4; r++) {
      float mt = fmaxf(fmaxf(acc[0][r], acc[1][r]),
                       fmaxf(acc[2][r], acc[3][r]));
      float nm = fmaxf(m_thr[r], mt);
      float s = l_thr[r] * fexp2(m_thr[r] - nm);
#pragma unroll
      for (int j = 0; j < 4; j++) s += fexp2(acc[j][r] - nm);
      l_thr[r] = s;
      m_thr[r] = nm;
    }
  }
#pragma unroll
  for (int d = 1; d < 16; d <<= 1) {
#pragma unroll
    for (int r = 0; r < 4; r++) {
      float om = __shfl_xor(m_thr[r], d);
      float ol = __shfl_xor(l_thr[r], d);
      float nm = fmaxf(m_thr[r], om);
      l_thr[r] = l_thr[r] * fexp2(m_thr[r] - nm) + ol * fexp2(om - nm);
      m_thr[r] = nm;
    }
  }
  if (l16 == 0) {
#pragma unroll
    for (int r = 0; r < 4; r++)
      sAdj[sw + quad * 4 + r] = m_thr[r] + flog2(l_thr[r]);
  }
  __syncthreads();
  // fused V scale+transpose for this block's s-range (reuse Ks as tile)
#pragma unroll
  for (int c = 0; c < 2; c++) {
    int e = (c * 256 + tid) * 8;
    int r = e >> 6, col = e & 63;
    union alignas(16) {
      hbf h[8];
      float4 f4;
    } u;
    u.f4 = *(const float4*)(&Vb[(size_t)(s0 + r) * 64 + col]);
    float sc = fexp2(-sAdj[r]);
#pragma unroll
    for (int k2 = 0; k2 < 8; k2++)
      u.h[k2] = __float2bfloat16(bf2f(u.h[k2]) * sc);
    *(float4*)(&Ks[r * 72 + col]) = u.f4;
  }
  __syncthreads();
#pragma unroll
  for (int c = 0; c < 2; c++) {
    int e = (c * 256 + tid) * 8;
    int v = e >> 6, tt = e & 63;
    union alignas(16) {
      hbf h[8];
      float4 f4;
    } u;
#pragma unroll
    for (int k2 = 0; k2 < 8; k2++) u.h[k2] = Ks[(tt + k2) * 72 + v];
    *(float4*)(&Vtb[(size_t)v * T_ + s0 + tt]) = u.f4;
  }
}

// ---------------------------------------------------------------------------
// Attention apply (MFMA): O[q,v] = sum_s 2^(S[q,s]) * V'[s,v]
// (normalizer folded into V'). Cross-iteration pipeline: iteration st
// computes QK^T(st) AND PV(st-1) so PV's MFMAs overlap QK's load/exp chain.
//  * K double-buffered (16KB), V triple-buffered (24KB), P per-wave
//    double-buffered (37KB). 77KB total -> 2 blocks/CU (grid cap).
//  * staging via global_load_lds + XOR swizzle, one barrier per iteration,
//    s_setprio(1) around MFMA clusters.
// Block: 128 q (4 waves x 32), s-tiles of 64, grid (16,32).
// ---------------------------------------------------------------------------
__global__ __launch_bounds__(256) void attn_apply(const hbf* __restrict__ Q,
                                                  const hbf* __restrict__ K,
                                                  const hbf* __restrict__ Vt,
                                                  hbf* __restrict__ heads) {
  __shared__ alignas(16) hbf Ksb[2 * 64 * 64];
  __shared__ alignas(16) hbf Vsb[3 * 64 * 64];
  __shared__ alignas(16) hbf Ps[4 * 2 * 32 * 72];
  const int bh = blockIdx.y;
  const int b = bh >> 4, h = bh & 15;
  const int q0 = blockIdx.x * 128;
  const int tid = threadIdx.x;
  const int wave = tid >> 6, lane = tid & 63;
  const int quad = lane >> 4, l16 = lane & 15;
  const int qw = wave * 32;
  const hbf* Qb = Q + (size_t)bh * T_ * 64;
  const hbf* Kb = K + (size_t)bh * T_ * 64;
  const hbf* Vtb = Vt + (size_t)bh * 64 * T_;
  hbf* Pw = &Ps[wave * (2 * 32 * 72)];
  // staging: lane -> LDS slot (row=tid>>3, chunk=tid&7); source chunk is
  // inverse-swizzled so LDS slot (r,c) holds global chunk c^(r&7).
  const int srow = tid >> 3, sc8 = tid & 7;
  const int swz = sc8 ^ (srow & 7);
  const hbf* gk = Kb + (size_t)srow * 64 + swz * 8;
  const hbf* gv = Vtb + (size_t)srow * T_ + swz * 8;
  hbf* lK = &Ksb[wave * 512];
  hbf* lV = &Vsb[wave * 512];
  const int sx = (l16 & 7) * 8;  // read-side elem swizzle for this lane's rows
  // Q fragments (B-operand): lane supplies Q[col=q(l16)][k=quad*8 in hh*32]
  bf16x8 qf[2][2];
#pragma unroll
  for (int i = 0; i < 2; i++)
#pragma unroll
    for (int hh = 0; hh < 2; hh++)
      qf[i][hh] = ldfrag(&Qb[(size_t)(q0 + qw + i * 16 + l16) * 64 + hh * 32 +
                             quad * 8]);
  const f32x4 zero = {0.f, 0.f, 0.f, 0.f};
  f32x4 accO[2][4];
#pragma unroll
  for (int i = 0; i < 2; i++)
#pragma unroll
    for (int j = 0; j < 4; j++) accO[i][j] = zero;

  // prologue: stage tiles 0 and 1 (K slots 0/1, V slots 0/1)
  glds16(gk, lK);
  glds16(gk + 2048, lK + 2048);
  glds16(gv, lV);
  glds16(gv + (size_t)32 * T_, lV + 2048);
  glds16(gk + 4096, lK + 4096);
  glds16(gk + 4096 + 2048, lK + 4096 + 2048);
  glds16(gv + 64, lV + 4096);
  glds16(gv + (size_t)32 * T_ + 64, lV + 4096 + 2048);
  __syncthreads();

  // prologue compute: QK^T(0) -> P[0] (no PV yet)
  {
    const hbf* Kc = &Ksb[0];
    bf16x8 kf[4][2];
#pragma unroll
    for (int j = 0; j < 4; j++)
#pragma unroll
      for (int hh = 0; hh < 2; hh++)
        kf[j][hh] =
            ldfrag(&Kc[(j * 16 + l16) * 64 + ((hh * 32 + quad * 8) ^ sx)]);
    __builtin_amdgcn_s_setprio(1);
    f32x4 accS[2][4];
#pragma unroll
    for (int i = 0; i < 2; i++)
#pragma unroll
      for (int j = 0; j < 4; j++) {
        f32x4 a = mfma16(kf[j][0], qf[i][0], zero);
        accS[i][j] = mfma16(kf[j][1], qf[i][1], a);
      }
    __builtin_amdgcn_s_setprio(0);
#pragma unroll
    for (int i = 0; i < 2; i++)
#pragma unroll
      for (int j = 0; j < 4; j++) {
        union {
          hbf h4[4];
          uint2 u;
        } pk;
#pragma unroll
        for (int r = 0; r < 4; r++)
          pk.h4[r] = __float2bfloat16(fexp2(accS[i][j][r]));
        *(uint2*)&Pw[(i * 16 + l16) * 72 + j * 16 + quad * 4] = pk.u;
      }
  }
  __syncthreads();  // protect K slot 0 from the st=1 prefetch (tile 2)

  for (int st = 1; st < T_ / 64; st++) {
    const int kcur = st & 1;
    const int pcur = st & 1, pprev = pcur ^ 1;
    const int vprev = (st - 1) % 3;
    if (st < T_ / 64 - 1) {  // async prefetch tile st+1 (drains at barrier)
      const int knxt = (st + 1) & 1, vnxt = (st + 1) % 3;
      size_t ko = (size_t)(st + 1) * 4096;
      glds16(gk + ko, lK + knxt * 4096);
      glds16(gk + ko + 2048, lK + knxt * 4096 + 2048);
      glds16(gv + (st + 1) * 64, lV + vnxt * 4096);
      glds16(gv + (size_t)32 * T_ + (st + 1) * 64, lV + vnxt * 4096 + 2048);
    }
    const hbf* Kc = &Ksb[kcur * 4096];
    const hbf* Vp = &Vsb[vprev * 4096];
    // issue kf loads for QK(st) early (in-order lgkm: complete before pf use)
    bf16x8 kf[4][2];
#pragma unroll
    for (int j = 0; j < 4; j++)
#pragma unroll
      for (int hh = 0; hh < 2; hh++)
        kf[j][hh] =
            ldfrag(&Kc[(j * 16 + l16) * 64 + ((hh * 32 + quad * 8) ^ sx)]);
    // PV(st-1): A = P[prev] rows q, B = V'[prev] rows v
    bf16x8 pf[2][2];
#pragma unroll
    for (int i = 0; i < 2; i++)
#pragma unroll
      for (int hh = 0; hh < 2; hh++)
        pf[i][hh] = ldfrag(
            &Pw[pprev * (32 * 72) + (i * 16 + l16) * 72 + hh * 32 + quad * 8]);
    __builtin_amdgcn_s_setprio(1);
#pragma unroll
    for (int j2 = 0; j2 < 4; j2++) {
      bf16x8 vf0 = ldfrag(&Vp[(j2 * 16 + l16) * 64 + ((quad * 8) ^ sx)]);
      bf16x8 vf1 = ldfrag(&Vp[(j2 * 16 + l16) * 64 + ((32 + quad * 8) ^ sx)]);
#pragma unroll
      for (int i = 0; i < 2; i++) {
        accO[i][j2] = mfma16(pf[i][0], vf0, accO[i][j2]);
        accO[i][j2] = mfma16(pf[i][1], vf1, accO[i][j2]);
      }
    }
    // QK^T(st) swapped: accS[i][j] = D[s][q]
    f32x4 accS[2][4];
#pragma unroll
    for (int i = 0; i < 2; i++)
#pragma unroll
      for (int j = 0; j < 4; j++) {
        f32x4 a = mfma16(kf[j][0], qf[i][0], zero);
        accS[i][j] = mfma16(kf[j][1], qf[i][1], a);
      }
    __builtin_amdgcn_s_setprio(0);
    // exp2 -> bf16 pack -> P[cur] (8 b64 writes, s-consecutive)
#pragma unroll
    for (int i = 0; i < 2; i++)
#pragma unroll
      for (int j = 0; j < 4; j++) {
        union {
          hbf h4[4];
          uint2 u;
        } pk;
#pragma unroll
        for (int r = 0; r < 4; r++)
          pk.h4[r] = __float2bfloat16(fexp2(accS[i][j][r]));
        *(uint2*)&Pw[pcur * (32 * 72) + (i * 16 + l16) * 72 + j * 16 +
                     quad * 4] = pk.u;
      }
    __syncthreads();
  }
  // epilogue: PV(last tile): P[(T/64-1)&1], V[(T/64-1)%3]
  {
    const int pl = (T_ / 64 - 1) & 1;
    const hbf* Vp = &Vsb[((T_ / 64 - 1) % 3) * 4096];
    bf16x8 pf[2][2];
#pragma unroll
    for (int i = 0; i < 2; i++)
#pragma unroll
      for (int hh = 0; hh < 2; hh++)
        pf[i][hh] = ldfrag(
            &Pw[pl * (32 * 72) + (i * 16 + l16) * 72 + hh * 32 + quad * 8]);
    __builtin_amdgcn_s_setprio(1);
#pragma unroll
    for (int j2 = 0; j2 < 4; j2++) {
      bf16x8 vf0 = ldfrag(&Vp[(j2 * 16 + l16) * 64 + ((quad * 8) ^ sx)]);
      bf16x8 vf1 = ldfrag(&Vp[(j2 * 16 + l16) * 64 + ((32 + quad * 8) ^ sx)]);
#pragma unroll
      for (int i = 0; i < 2; i++) {
        accO[i][j2] = mfma16(pf[i][0], vf0, accO[i][j2]);
        accO[i][j2] = mfma16(pf[i][1], vf1, accO[i][j2]);
      }
    }
    __builtin_amdgcn_s_setprio(0);
  }
#pragma unroll
  for (int i = 0; i < 2; i++)
#pragma unroll
    for (int j2 = 0; j2 < 4; j2++)
#pragma unroll
      for (int r = 0; r < 4; r++) {
        int q = q0 + qw + i * 16 + quad * 4 + r;
        int v = j2 * 16 + l16;
        heads[((size_t)(b * T_ + q)) * D_ + h * 64 + v] =
            __float2bfloat16(accO[i][j2][r]);
      }
}

// ---------------------------------------------------------------------------
// LN1 normalize (stats came fused from the out-proj GEMM). Vectorized
// 4x bf16 in/out (G13).
// ---------------------------------------------------------------------------
__global__ __launch_bounds__(256) void ln_norm(const hbf* __restrict__ src,
                                               const float* __restrict__ red,
                                               void* dst,
                                               const int* __restrict__ flag,
                                               int force_bf) {
  const int isbf = force_bf ? 1 : *flag;
  const float invN = 1.f / (float)(T_ * D_);
  const uint2* sv = (const uint2*)src;
  for (size_t i = (size_t)blockIdx.x * 256 + threadIdx.x;
       i < (size_t)B_ * T_ * D_ / 4; i += (size_t)gridDim.x * 256) {
    int b = (int)(i >> 19);  // per-batch 4-elem count = T*D/4 = 2^19
    float mu = red[b * 2 + 0] * invN;
    float var = red[b * 2 + 1] * invN - mu * mu;
    float rstd = rsqrtf(var + EPS_);
    union {
      uint2 u;
      hbf h[4];
    } s;
    s.u = sv[i];
    float out[4];
#pragma unroll
    for (int r = 0; r < 4; r++) out[r] = (bf2f(s.h[r]) - mu) * rstd;
    if (isbf) {
      union {
        hbf h[4];
        uint2 u;
      } pk;
#pragma unroll
      for (int r = 0; r < 4; r++) pk.h[r] = __float2bfloat16(out[r]);
      ((uint2*)dst)[i] = pk.u;
    } else {
      float4 f{out[0], out[1], out[2], out[3]};
      ((float4*)dst)[i] = f;
    }
  }
}

// ---------------------------------------------------------------------------
// LN2 stats over r2 = P0+P1+b2+o1 (r2 never materialized). Vectorized:
// float4 partial loads + uint2 (4x bf16) o1/b2 loads (G13).
// ---------------------------------------------------------------------------
__global__ __launch_bounds__(256) void ln2_stats(const float* __restrict__ P0,
                                                 const float* __restrict__ P1,
                                                 const hbf* __restrict__ o1,
                                                 const hbf* __restrict__ b2b,
                                                 float* __restrict__ red) {
  __shared__ float s1[256], s2[256];
  const int b = blockIdx.y;
  const size_t base = (size_t)b * (T_ * D_ / 4);
  const float4* P0v = (const float4*)P0;
  const float4* P1v = (const float4*)P1;
  const uint2* o1v = (const uint2*)o1;
  const uint2* b2v = (const uint2*)b2b;
  float sum = 0.f, sq = 0.f;
  for (size_t i = (size_t)blockIdx.x * 256 + threadIdx.x;
       i < (size_t)(T_ * D_ / 4); i += (size_t)gridDim.x * 256) {
    float4 p0 = P0v[base + i], p1 = P1v[base + i];
    union {
      uint2 u;
      hbf h[4];
    } o, bb;
    o.u = o1v[base + i];
    bb.u = b2v[i & (D_ / 4 - 1)];
#pragma unroll
    for (int r = 0; r < 4; r++) {
      float v = (&p0.x)[r] + (&p1.x)[r] + bf2f(bb.h[r]) + bf2f(o.h[r]);
      sum += v;
      sq += v * v;
    }
  }
  s1[threadIdx.x] = sum;
  s2[threadIdx.x] = sq;
  __syncthreads();
  for (int off = 128; off > 0; off >>= 1) {
    if ((int)threadIdx.x < off) {
      s1[threadIdx.x] += s1[threadIdx.x + off];
      s2[threadIdx.x] += s2[threadIdx.x + off];
    }
    __syncthreads();
  }
  if (threadIdx.x == 0) {
    atomicAdd(&red[b * 2 + 0], s1[0]);
    atomicAdd(&red[b * 2 + 1], s2[0]);
  }
}

__global__ __launch_bounds__(256) void ln2_norm(
    const float* __restrict__ P0, const float* __restrict__ P1,
    const hbf* __restrict__ o1, const hbf* __restrict__ b2b,
    const float* __restrict__ red, void* dst, const int* __restrict__ flag) {
  const int isbf = *flag;
  const float invN = 1.f / (float)(T_ * D_);
  const float4* P0v = (const float4*)P0;
  const float4* P1v = (const float4*)P1;
  const uint2* o1v = (const uint2*)o1;
  const uint2* b2v = (const uint2*)b2b;
  for (size_t i = (size_t)blockIdx.x * 256 + threadIdx.x;
       i < (size_t)B_ * T_ * D_ / 4; i += (size_t)gridDim.x * 256) {
    int b = (int)(i >> 19);  // per-batch float4 count = T*D/4 = 2^19
    float mu = red[b * 2 + 0] * invN;
    float var = red[b * 2 + 1] * invN - mu * mu;
    float rstd = rsqrtf(var + EPS_);
    float4 p0 = P0v[i], p1 = P1v[i];
    union {
      uint2 u;
      hbf h[4];
    } o, bb;
    o.u = o1v[i];
    bb.u = b2v[i & (D_ / 4 - 1)];
    float out[4];
#pragma unroll
    for (int r = 0; r < 4; r++)
      out[r] =
          ((&p0.x)[r] + (&p1.x)[r] + bf2f(bb.h[r]) + bf2f(o.h[r]) - mu) * rstd;
    if (isbf) {
      union {
        hbf h[4];
        uint2 u;
      } pk;
#pragma unroll
      for (int r = 0; r < 4; r++) pk.h[r] = __float2bfloat16(out[r]);
      ((uint2*)dst)[i] = pk.u;
    } else {
      float4 f{out[0], out[1], out[2], out[3]};
      ((float4*)dst)[i] = f;
    }
  }
}

// ---------------------------------------------------------------------------
// Workspace (MiB offsets), ~88.1 MB total:
//  [0,8) xb | [8,14) Wqkvt | [14,16) Wot | [16,24) W1t | [24,32) W2t
//  [32,40) Q | [40,48) K | [48,56) V | [56,64) Vt | [64,72) heads
//  [72,80) r1 | [80,88) o1 | ff1 aliases [32,64)
//  split-K partials (fp32, 16 MB each): P0 over [0,16), P1 over [64,80)
//  [88,..) b1b 8K | b2b 2K | red 32B | flag 4B
// ---------------------------------------------------------------------------
extern "C" void kernel_launch(void* const* d_in, const int* in_sizes, int n_in,
                              void* d_out, int out_size, void* d_ws,
                              size_t ws_size, hipStream_t stream) {
  const void* x = d_in[0];
  const void* Wq = d_in[1];
  const void* Wk = d_in[2];
  const void* Wv = d_in[3];
  const void* Wo = d_in[4];
  const void* W1 = d_in[5];
  const void* W2 = d_in[7];
  const void* b1 = d_in[6];
  const void* b2 = d_in[8];

  const size_t MB = 1024 * 1024;
  if (ws_size < 89 * MB) return;

  char* w = (char*)d_ws;
  hbf* xb = (hbf*)(w + 0 * MB);
  hbf* wqkvt = (hbf*)(w + 8 * MB);
  hbf* wot = (hbf*)(w + 14 * MB);
  hbf* w1t = (hbf*)(w + 16 * MB);
  hbf* w2t = (hbf*)(w + 24 * MB);
  hbf* Qb = (hbf*)(w + 32 * MB);
  hbf* Kb = (hbf*)(w + 40 * MB);
  hbf* Vb = (hbf*)(w + 48 * MB);
  hbf* Vtb = (hbf*)(w + 56 * MB);
  hbf* heads = (hbf*)(w + 64 * MB);
  hbf* r1 = (hbf*)(w + 72 * MB);
  hbf* o1 = (hbf*)(w + 80 * MB);
  hbf* ff1 = (hbf*)(w + 32 * MB);   // over dead Q/K/V/Vt
  float* P0 = (float*)(w + 0 * MB);   // over dead xb/wqkvt/wot (16 MB)
  float* P1 = (float*)(w + 64 * MB);  // over dead heads/r1 (16 MB)
  hbf* b1b = (hbf*)(w + 88 * MB);
  hbf* b2b = b1b + FF_;
  float* red = (float*)(b2b + D_);
  int* flag = (int*)(red + 8);

  hipMemsetAsync(red, 0, 8 * sizeof(float) + sizeof(int), stream);
  detect_dtype<<<1, 256, 0, stream>>>((const unsigned*)x, flag);

  const int M = B_ * T_;  // 4096
  // --- one-launch preconversion ---
  preconv<<<13314, 256, 0, stream>>>(x, Wq, Wk, Wv, Wo, W1, W2, b1, b2, xb,
                                     wqkvt, wot, w1t, w2t, b1b, b2b, flag);
  // --- QKV fused projection (Q pre-scaled by log2e/8) ---
  gemm_bt<0, 128, 128, 64><<<dim3(24, 32), 256, 0, stream>>>(
      xb, wqkvt, Qb, nullptr, nullptr, nullptr, nullptr, M, 3 * D_, D_, D_);
  // --- attention: col-softmax stats + fused V scale/transpose, then apply ---
  attn_stats<<<dim3(32, 32), 256, 0, stream>>>(Qb, Kb, Vb, Vtb);
  attn_apply<<<dim3(16, 32), 256, 0, stream>>>(Qb, Kb, Vtb, heads);
  // --- out-proj + residual + fused LN1 stats ---
  gemm_bt<1, 128, 64, 64><<<dim3(16, 32), 256, 0, stream>>>(
      heads, wot, r1, nullptr, nullptr, xb, red, M, D_, D_, D_);
  ln_norm<<<2048, 256, 0, stream>>>(r1, red, o1, flag, 1);
  // --- FFN1: 256x256 double-buffered single-barrier kernel (grid = 1/CU) ---
  gemm256_relu<<<dim3(FF_ / 256, M / 256), 512, 0, stream>>>(
      o1, w1t, ff1, b1b, FF_, D_, D_);
  // --- FFN2 split-K=2 -> fp32 partials (BN=128: 32 MFMA/barrier + 512 blk) ---
  gemm_bt<4, 128, 128, 64><<<dim3(8, 32, 2), 256, 0, stream>>>(
      ff1, w2t, nullptr, P0, P1, nullptr, nullptr, M, D_, FF_ / 2, FF_);
  // --- LN2 (r2 = P0+P1+b2+o1, never materialized; vectorized) ---
  ln2_stats<<<dim3(256, B_), 256, 0, stream>>>(P0, P1, o1, b2b, red + 4);
  ln2_norm<<<2048, 256, 0, stream>>>(P0, P1, o1, b2b, red + 4, d_out, flag);
}

// Round 11
// 438.155 us; speedup vs baseline: 1.0995x; 1.0063x over previous
//
#include <hip/hip_runtime.h>
#include <hip/hip_bf16.h>
#include <cstddef>
#include <cstdint>

typedef __hip_bfloat16 hbf;
typedef __attribute__((ext_vector_type(8))) __bf16 bf16x8;
typedef __attribute__((ext_vector_type(4))) float f32x4;

#define B_ 2
#define T_ 2048
#define D_ 1024
#define H_ 16
#define FF_ 4096
#define EPS_ 1e-5f
// Q pre-scale = log2(e)/sqrt(dk): attention exponentials become native exp2
#define SCALE_ 0.18033688011112f

__device__ __forceinline__ float bf2f(hbf v) { return __bfloat162float(v); }
__device__ __forceinline__ float fexp2(float x) {
  return __builtin_amdgcn_exp2f(x);  // v_exp_f32 (2^x native)
}
__device__ __forceinline__ float flog2(float x) {
  return __builtin_amdgcn_logf(x);  // v_log_f32 (log2 native)
}
__device__ __forceinline__ float ldin(const void* p, size_t i, int isbf) {
  return isbf ? __bfloat162float(((const hbf*)p)[i]) : ((const float*)p)[i];
}
__device__ __forceinline__ void ston(void* p, size_t i, float v, int isbf) {
  if (isbf) ((hbf*)p)[i] = __float2bfloat16(v);
  else ((float*)p)[i] = v;
}
__device__ __forceinline__ f32x4 mfma16(bf16x8 a, bf16x8 b, f32x4 c) {
  return __builtin_amdgcn_mfma_f32_16x16x32_bf16(a, b, c, 0, 0, 0);
}
__device__ __forceinline__ bf16x8 ldfrag(const hbf* p) {
  return *(const bf16x8*)p;
}
// async global->LDS, 16B/lane; LDS base wave-uniform (HW: lane i -> base+i*16)
__device__ __forceinline__ void glds16(const hbf* g, hbf* l) {
  __builtin_amdgcn_global_load_lds(
      (const __attribute__((address_space(1))) void*)g,
      (__attribute__((address_space(3))) void*)l, 16, 0, 0);
}

// ---------------------------------------------------------------------------
// Runtime input-dtype detection (bf16 vs fp32), from bit patterns of x.
// ---------------------------------------------------------------------------
__global__ __launch_bounds__(256) void detect_dtype(const unsigned* x,
                                                    int* flag) {
  __shared__ int cnt[256];
  int c = 0;
  for (int i = threadIdx.x; i < 4096; i += 256) {
    unsigned low = x[i] & 0xFFFFu;
    unsigned e = (low >> 7) & 0xFFu;
    if (e >= 100u && e <= 142u) c++;
  }
  cnt[threadIdx.x] = c;
  __syncthreads();
  for (int off = 128; off > 0; off >>= 1) {
    if ((int)threadIdx.x < off) cnt[threadIdx.x] += cnt[threadIdx.x + off];
    __syncthreads();
  }
  if (threadIdx.x == 0) *flag = (cnt[0] > 2458) ? 1 : 0;
}

// ---------------------------------------------------------------------------
// Mega-preconversion: one launch does all weight transposes + x/bias converts.
// Flat block-id job table:
//  [0,3072)      Wq/Wk/Wv -> wqkvt (head-sliced transpose, R=1024,C=64,z=16)
//  [3072,4096)   Wo -> wot          (1024x1024)
//  [4096,8192)   W1 -> w1t          (1024x4096)
//  [8192,12288)  W2 -> w2t          (4096x1024)
//  [12288,13312) x -> xb            (4M elements, 4096/block, vectorized)
//  13312: b1 -> b1b ; 13313: b2 -> b2b
// ---------------------------------------------------------------------------
__device__ __forceinline__ void tr_tile(const void* __restrict__ src,
                                        hbf* __restrict__ dst, int R, int C,
                                        size_t zoff, int cx, int ry, int f,
                                        float (*tile)[33]) {
  const int tx = threadIdx.x & 31, ty = threadIdx.x >> 5;
  const int c0 = cx * 32, r0 = ry * 32;
#pragma unroll
  for (int p = 0; p < 4; p++) {
    int rr = p * 8 + ty;
    tile[rr][tx] = ldin(src, zoff + (size_t)(r0 + rr) * C + c0 + tx, f);
  }
  __syncthreads();
#pragma unroll
  for (int p = 0; p < 4; p++) {
    int cc = p * 8 + ty;
    dst[zoff + (size_t)(c0 + cc) * R + r0 + tx] = __float2bfloat16(tile[tx][cc]);
  }
}

__global__ __launch_bounds__(256) void preconv(
    const void* __restrict__ x, const void* __restrict__ Wq,
    const void* __restrict__ Wk, const void* __restrict__ Wv,
    const void* __restrict__ Wo, const void* __restrict__ W1,
    const void* __restrict__ W2, const void* __restrict__ b1,
    const void* __restrict__ b2, hbf* __restrict__ xb,
    hbf* __restrict__ wqkvt, hbf* __restrict__ wot, hbf* __restrict__ w1t,
    hbf* __restrict__ w2t, hbf* __restrict__ b1b, hbf* __restrict__ b2b,
    const int* __restrict__ flag) {
  __shared__ float tile[32][33];
  const int f = *flag;
  const int bid = blockIdx.x;
  if (bid < 3072) {
    int which = bid >> 10;  // 0=Wq 1=Wk 2=Wv
    int r = bid & 1023;
    int z = r >> 6, rem = r & 63;
    int ry = rem >> 1, cx = rem & 1;
    const void* src = (which == 0) ? Wq : (which == 1) ? Wk : Wv;
    hbf* dst = wqkvt + (size_t)which * (D_ * D_);
    tr_tile(src, dst, 1024, 64, (size_t)z * 65536, cx, ry, f, tile);
  } else if (bid < 4096) {
    int t = bid - 3072;
    tr_tile(Wo, wot, 1024, 1024, 0, t & 31, t >> 5, f, tile);
  } else if (bid < 8192) {
    int t = bid - 4096;
    tr_tile(W1, w1t, 1024, 4096, 0, t & 127, t >> 7, f, tile);
  } else if (bid < 12288) {
    int t = bid - 8192;
    tr_tile(W2, w2t, 4096, 1024, 0, t & 31, t >> 5, f, tile);
  } else if (bid < 13312) {
    size_t base = (size_t)(bid - 12288) * 4096;
    if (f) {
      // bf16 input: straight 16B copies
      const uint4* src = (const uint4*)((const hbf*)x + base);
      uint4* dst = (uint4*)(xb + base);
      for (int i = threadIdx.x; i < 512; i += 256) dst[i] = src[i];
    } else {
      // fp32 input: float4 x2 -> 8 bf16 packed (uint2x2)
      const float4* src = (const float4*)((const float*)x + base);
      for (int i = threadIdx.x; i < 512; i += 256) {
        float4 a = src[i * 2], b = src[i * 2 + 1];
        union {
          hbf h[8];
          uint4 u;
        } o;
        o.h[0] = __float2bfloat16(a.x);
        o.h[1] = __float2bfloat16(a.y);
        o.h[2] = __float2bfloat16(a.z);
        o.h[3] = __float2bfloat16(a.w);
        o.h[4] = __float2bfloat16(b.x);
        o.h[5] = __float2bfloat16(b.y);
        o.h[6] = __float2bfloat16(b.z);
        o.h[7] = __float2bfloat16(b.w);
        *(uint4*)(xb + base + (size_t)i * 8) = o.u;
      }
    }
  } else if (bid == 13312) {
    for (int i = threadIdx.x; i < FF_; i += 256)
      b1b[i] = __float2bfloat16(ldin(b1, i, f));
  } else {
    for (int i = threadIdx.x; i < D_; i += 256)
      b2b[i] = __float2bfloat16(ldin(b2, i, f));
  }
}

// ---------------------------------------------------------------------------
// MFMA GEMM (m97 structure): C(MxN) = A(MxK) @ Bt(NxK)^T, bf16, fp32 accum.
// BMxBN tile, BK=64, glds width-16 staging, 4 waves 2x2.
// TR: grid transpose -- blockIdx.x walks M-tiles (gridDim.x = 32 == 0 mod 8
// so XCD = bx%8 pins A-PANELS per XCD instead of B). Rule (from measured
// XCD=flat%8 model, R5/R6 FETCH A/B): pin the operand with the larger
// stream. FFN2: A-stream 135MB measured vs B-stream <=64MB -> TR=1.
// Ledger: scalar epilogue; BK=64 (128: conflicts 12.6M->44M); no remapped
// XCD swizzle (thrashed: FETCH 41->70MB on FFN1).
// MODE 0: QKV fused (N=3072): scatter to (which,B,H,T,64); Q scaled.
// MODE 1: C = acc + e1[m*N+n]; fused LN stats -> atomicAdd red[batch]
// MODE 2: C = relu(acc + e1[n])            (FFN1 + bias; now unused)
// MODE 4: Cf_z[m*N+n] = acc  (fp32 split-K partial, z = blockIdx.z)
// ---------------------------------------------------------------------------
template <int MODE, int BM, int BN, int BK, int TR>
__global__ __launch_bounds__(256) void gemm_bt(
    const hbf* __restrict__ A, const hbf* __restrict__ Bt, hbf* __restrict__ C,
    float* __restrict__ Cf0, float* __restrict__ Cf1,
    const hbf* __restrict__ e1, float* __restrict__ red, int M, int N, int K,
    int LDK) {
  constexpr int WM = BM / 2, WN = BN / 2;
  constexpr int IF = WM / 16, JF = WN / 16;
  constexpr int HK = BK / 32;     // 32-wide k-chunks per K-step
  constexpr int LPT = BK / 8;     // lanes covering one row (8 hbf/lane)
  constexpr int CPR = 2048 / BK;  // rows staged per glds chunk (4KB)
  __shared__ alignas(16) hbf As[BM * BK];
  __shared__ alignas(16) hbf Bs[BN * BK];
  const int tid = threadIdx.x;
  const int wave = tid >> 6, lane = tid & 63;
  const int quad = lane >> 4, l16 = lane & 15;
  const int m0 = (TR ? blockIdx.x : blockIdx.y) * BM;
  const int n0 = (TR ? blockIdx.y : blockIdx.x) * BN;
  const int mw = (wave >> 1) * WM, nw = (wave & 1) * WN;
  const int srow = tid / LPT;
  const int scol = (tid % LPT) * 8;
  const int kbase = (MODE == 4) ? blockIdx.z * K : 0;
  const f32x4 zero = {0.f, 0.f, 0.f, 0.f};
  f32x4 acc[IF][JF];
#pragma unroll
  for (int i = 0; i < IF; i++)
#pragma unroll
    for (int j = 0; j < JF; j++) acc[i][j] = zero;

  const hbf* ga = &A[(size_t)(m0 + srow) * LDK + kbase + scol];
  const hbf* gb = &Bt[(size_t)(n0 + srow) * LDK + kbase + scol];
  hbf* lA = &As[wave * 512];
  hbf* lB = &Bs[wave * 512];

  for (int k0 = 0; k0 < K; k0 += BK) {
#pragma unroll
    for (int c = 0; c < BM / CPR; c++)
      glds16(ga + (size_t)(c * CPR) * LDK + k0, lA + c * 2048);
#pragma unroll
    for (int c = 0; c < BN / CPR; c++)
      glds16(gb + (size_t)(c * CPR) * LDK + k0, lB + c * 2048);
    __syncthreads();
    bf16x8 af[HK][IF], bfr[HK][JF];
#pragma unroll
    for (int h = 0; h < HK; h++) {
#pragma unroll
      for (int i = 0; i < IF; i++)
        af[h][i] = ldfrag(&As[(mw + i * 16 + l16) * BK + h * 32 + quad * 8]);
#pragma unroll
      for (int j = 0; j < JF; j++)
        bfr[h][j] = ldfrag(&Bs[(nw + j * 16 + l16) * BK + h * 32 + quad * 8]);
    }
#pragma unroll
    for (int h = 0; h < HK; h++)
#pragma unroll
      for (int i = 0; i < IF; i++)
#pragma unroll
        for (int j = 0; j < JF; j++)
          acc[i][j] = mfma16(af[h][i], bfr[h][j], acc[i][j]);
    __syncthreads();
  }
  float ssum = 0.f, ssq = 0.f;
#pragma unroll
  for (int i = 0; i < IF; i++)
#pragma unroll
    for (int j = 0; j < JF; j++)
#pragma unroll
      for (int r = 0; r < 4; r++) {
        int m = m0 + mw + i * 16 + quad * 4 + r;
        int n = n0 + nw + j * 16 + l16;
        float v = acc[i][j][r];
        if (MODE == 0) {
          int which = n >> 10, n1 = n & 1023;
          int h = n1 >> 6, cc = n1 & 63;
          int b = m >> 11, t = m & (T_ - 1);
          if (which == 0) v *= SCALE_;  // pre-scale Q by log2e/sqrt(dk)
          C[(size_t)which * ((size_t)B_ * H_ * T_ * 64) +
            (((size_t)(b * H_ + h)) * T_ + t) * 64 + cc] = __float2bfloat16(v);
        } else if (MODE == 1) {
          hbf hv = __float2bfloat16(v + bf2f(e1[(size_t)m * N + n]));
          C[(size_t)m * N + n] = hv;
          float fv = bf2f(hv);
          ssum += fv;
          ssq += fv * fv;
        } else if (MODE == 2) {
          C[(size_t)m * N + n] = __float2bfloat16(fmaxf(v + bf2f(e1[n]), 0.f));
        } else if (MODE == 4) {
          float* Cf = blockIdx.z ? Cf1 : Cf0;
          Cf[(size_t)m * N + n] = v;
        }
      }
  if (MODE == 1) {
    // fused LN stats: block tile lies within one batch (BM=128 | 2048)
    float* sc = (float*)As;  // dead LDS reuse (post final barrier)
    sc[tid] = ssum;
    sc[256 + tid] = ssq;
    __syncthreads();
    for (int off = 128; off > 0; off >>= 1) {
      if (tid < off) {
        sc[tid] += sc[tid + off];
        sc[256 + tid] += sc[256 + tid + off];
      }
      __syncthreads();
    }
    if (tid == 0) {
      int b = m0 >> 11;
      atomicAdd(&red[b * 2 + 0], sc[0]);
      atomicAdd(&red[b * 2 + 1], sc[256]);
    }
  }
}

// ---------------------------------------------------------------------------
// 256x256-tile double-buffered GEMM for FFN1 (grid = 256 blocks = 1/CU).
// C = relu(A @ Bt^T + bias[n]). 8 waves (2x4), 64 MFMA per wave per K-tile
// against ONE barrier; prefetch of t+1 issued before compute of t. Verified
// R10: FFN1 dropped out of top-5 (was 69.6us at the 128 2-barrier tile).
// A/B-symmetric operand traffic -> no TR benefit here.
// ---------------------------------------------------------------------------
__global__ __launch_bounds__(512) void gemm256_relu(
    const hbf* __restrict__ A, const hbf* __restrict__ Bt, hbf* __restrict__ C,
    const hbf* __restrict__ bias, int N, int K, int LDK) {
  __shared__ alignas(16) hbf As[2][256 * 64];
  __shared__ alignas(16) hbf Bs[2][256 * 64];
  const int tid = threadIdx.x;
  const int wave = tid >> 6, lane = tid & 63;
  const int quad = lane >> 4, l16 = lane & 15;
  const int wr = wave >> 2, wc = wave & 3;  // 2x4 wave grid
  const int m0 = blockIdx.y * 256, n0 = blockIdx.x * 256;
  const int mw = wr * 128, nw = wc * 64;
  const int srow = tid >> 3;       // 0..63 (rows within a 64-row chunk)
  const int scol = (tid & 7) * 8;  // 0..56
  const hbf* ga = &A[(size_t)(m0 + srow) * LDK + scol];
  const hbf* gb = &Bt[(size_t)(n0 + srow) * LDK + scol];
  const int lbase = wave * 512;  // wave-uniform LDS base within a chunk
  const f32x4 zero = {0.f, 0.f, 0.f, 0.f};
  f32x4 acc[8][4];
#pragma unroll
  for (int i = 0; i < 8; i++)
#pragma unroll
    for (int j = 0; j < 4; j++) acc[i][j] = zero;

  const int NT = K / 64;
  // prologue: stage tile 0 into buffer 0
#pragma unroll
  for (int c = 0; c < 4; c++) {
    glds16(ga + (size_t)(c * 64) * LDK, &As[0][c * 4096 + lbase]);
    glds16(gb + (size_t)(c * 64) * LDK, &Bs[0][c * 4096 + lbase]);
  }
  __syncthreads();

  for (int t = 0; t < NT; t++) {
    const int cur = t & 1;
    if (t < NT - 1) {  // async prefetch t+1 into the other buffer;
                       // drains at the end-of-iteration barrier
      size_t ko = (size_t)(t + 1) * 64;
#pragma unroll
      for (int c = 0; c < 4; c++) {
        glds16(ga + (size_t)(c * 64) * LDK + ko,
               &As[cur ^ 1][c * 4096 + lbase]);
        glds16(gb + (size_t)(c * 64) * LDK + ko,
               &Bs[cur ^ 1][c * 4096 + lbase]);
      }
    }
    // compute tile t from buffer cur: 2 k-halves x (8 m x 4 n) MFMA
#pragma unroll
    for (int h = 0; h < 2; h++) {
      bf16x8 bfr[4];
#pragma unroll
      for (int j = 0; j < 4; j++)
        bfr[j] = ldfrag(&Bs[cur][(nw + j * 16 + l16) * 64 + h * 32 + quad * 8]);
#pragma unroll
      for (int i = 0; i < 8; i++) {
        bf16x8 af =
            ldfrag(&As[cur][(mw + i * 16 + l16) * 64 + h * 32 + quad * 8]);
#pragma unroll
        for (int j = 0; j < 4; j++)
          acc[i][j] = mfma16(af, bfr[j], acc[i][j]);
      }
    }
    __syncthreads();  // drains prefetch vmcnt + protects buffer reuse
  }
  // epilogue: relu(acc + bias[n])
#pragma unroll
  for (int i = 0; i < 8; i++)
#pragma unroll
    for (int j = 0; j < 4; j++)
#pragma unroll
      for (int r = 0; r < 4; r++) {
        int m = m0 + mw + i * 16 + quad * 4 + r;
        int n = n0 + nw + j * 16 + l16;
        C[(size_t)m * N + n] =
            __float2bfloat16(fmaxf(acc[i][j][r] + bf2f(bias[n]), 0.f));
      }
}

// ---------------------------------------------------------------------------
// Attention stats + V-transform (MFMA): S = Q K^T (Q pre-scaled by log2e/8,
// so all exponentials are base-2 -> native v_exp_f32).
//   adj[s] = max_q S[q,s] + log2(sum_q 2^(S[q,s]-max))
// Tail (fused, block owns its 64 s-rows): Vt'[v,s] = V[s,v]*2^(-adj[s]).
// Block: 64 s (4 waves x 16), loops q-tiles of 64. Padded LDS stride 72.
// ---------------------------------------------------------------------------
__global__ __launch_bounds__(256) void attn_stats(const hbf* __restrict__ Q,
                                                  const hbf* __restrict__ K,
                                                  const hbf* __restrict__ V,
                                                  hbf* __restrict__ Vt) {
  __shared__ alignas(16) hbf Ks[64 * 72];
  __shared__ alignas(16) hbf Qs[64 * 72];
  __shared__ float sAdj[64];
  const int bh = blockIdx.y;
  const int s0 = blockIdx.x * 64;
  const int tid = threadIdx.x;
  const int wave = tid >> 6, lane = tid & 63;
  const int quad = lane >> 4, l16 = lane & 15;
  const int sw = wave * 16;
  const hbf* Kb = K + (size_t)bh * T_ * 64;
  const hbf* Qb = Q + (size_t)bh * T_ * 64;
  const hbf* Vb = V + (size_t)bh * T_ * 64;
  hbf* Vtb = Vt + (size_t)bh * 64 * T_;
  const int r_ = tid >> 3, c_ = (tid & 7) * 8;
#pragma unroll
  for (int c = 0; c < 2; c++) {
    int row = c * 32 + r_;
    *(float4*)(&Ks[row * 72 + c_]) =
        *(const float4*)(&Kb[(size_t)(s0 + row) * 64 + c_]);
  }
  __syncthreads();
  bf16x8 kf0 = ldfrag(&Ks[(sw + l16) * 72 + quad * 8]);
  bf16x8 kf1 = ldfrag(&Ks[(sw + l16) * 72 + 32 + quad * 8]);
  float m_thr[4], l_thr[4];
#pragma unroll
  for (int r = 0; r < 4; r++) {
    m_thr[r] = -1e30f;
    l_thr[r] = 0.f;
  }
  const f32x4 zero = {0.f, 0.f, 0.f, 0.f};
  for (int qt = 0; qt < T_ / 64; qt++) {
    if (qt) __syncthreads();
#pragma unroll
    for (int c = 0; c < 2; c++) {
      int row = c * 32 + r_;
      *(float4*)(&Qs[row * 72 + c_]) =
          *(const float4*)(&Qb[(size_t)(qt * 64 + row) * 64 + c_]);
    }
    __syncthreads();
    f32x4 acc[4];
#pragma unroll
    for (int j = 0; j < 4; j++) {
      bf16x8 qf0 = ldfrag(&Qs[(j * 16 + l16) * 72 + quad * 8]);
      bf16x8 qf1 = ldfrag(&Qs[(j * 16 + l16) * 72 + 32 + quad * 8]);
      f32x4 a = zero;
      a = mfma16(kf0, qf0, a);
      a = mfma16(kf1, qf1, a);
      acc[j] = a;
    }
#pragma unroll
    for (int r = 0; r < 4; r++) {
      float mt = fmaxf(fmaxf(acc[0][r], acc[1][r]),
                       fmaxf(acc[2][r], acc[3][r]));
      float nm = fmaxf(m_thr[r], mt);
      float s = l_thr[r] * fexp2(m_thr[r] - nm);
#pragma unroll
      for (int j = 0; j < 4; j++) s += fexp2(acc[j][r] - nm);
      l_thr[r] = s;
      m_thr[r] = nm;
    }
  }
#pragma unroll
  for (int d = 1; d < 16; d <<= 1) {
#pragma unroll
    for (int r = 0; r < 4; r++) {
      float om = __shfl_xor(m_thr[r], d);
      float ol = __shfl_xor(l_thr[r], d);
      float nm = fmaxf(m_thr[r], om);
      l_thr[r] = l_thr[r] * fexp2(m_thr[r] - nm) + ol * fexp2(om - nm);
      m_thr[r] = nm;
    }
  }
  if (l16 == 0) {
#pragma unroll
    for (int r = 0; r < 4; r++)
      sAdj[sw + quad * 4 + r] = m_thr[r] + flog2(l_thr[r]);
  }
  __syncthreads();
  // fused V scale+transpose for this block's s-range (reuse Ks as tile)
#pragma unroll
  for (int c = 0; c < 2; c++) {
    int e = (c * 256 + tid) * 8;
    int r = e >> 6, col = e & 63;
    union alignas(16) {
      hbf h[8];
      float4 f4;
    } u;
    u.f4 = *(const float4*)(&Vb[(size_t)(s0 + r) * 64 + col]);
    float sc = fexp2(-sAdj[r]);
#pragma unroll
    for (int k2 = 0; k2 < 8; k2++)
      u.h[k2] = __float2bfloat16(bf2f(u.h[k2]) * sc);
    *(float4*)(&Ks[r * 72 + col]) = u.f4;
  }
  __syncthreads();
#pragma unroll
  for (int c = 0; c < 2; c++) {
    int e = (c * 256 + tid) * 8;
    int v = e >> 6, tt = e & 63;
    union alignas(16) {
      hbf h[8];
      float4 f4;
    } u;
#pragma unroll
    for (int k2 = 0; k2 < 8; k2++) u.h[k2] = Ks[(tt + k2) * 72 + v];
    *(float4*)(&Vtb[(size_t)v * T_ + s0 + tt]) = u.f4;
  }
}

// ---------------------------------------------------------------------------
// Attention apply (MFMA): O[q,v] = sum_s 2^(S[q,s]) * V'[s,v]
// (normalizer folded into V'). Cross-iteration pipeline: iteration st
// computes QK^T(st) AND PV(st-1) so PV's MFMAs overlap QK's load/exp chain.
//  * K double-buffered (16KB), V triple-buffered (24KB), P per-wave
//    double-buffered (37KB). 77KB total -> 2 blocks/CU (grid cap).
//  * staging via global_load_lds + XOR swizzle, one barrier per iteration,
//    s_setprio(1) around MFMA clusters.
// Block: 128 q (4 waves x 32), s-tiles of 64, grid (16,32).
// ---------------------------------------------------------------------------
__global__ __launch_bounds__(256) void attn_apply(const hbf* __restrict__ Q,
                                                  const hbf* __restrict__ K,
                                                  const hbf* __restrict__ Vt,
                                                  hbf* __restrict__ heads) {
  __shared__ alignas(16) hbf Ksb[2 * 64 * 64];
  __shared__ alignas(16) hbf Vsb[3 * 64 * 64];
  __shared__ alignas(16) hbf Ps[4 * 2 * 32 * 72];
  const int bh = blockIdx.y;
  const int b = bh >> 4, h = bh & 15;
  const int q0 = blockIdx.x * 128;
  const int tid = threadIdx.x;
  const int wave = tid >> 6, lane = tid & 63;
  const int quad = lane >> 4, l16 = lane & 15;
  const int qw = wave * 32;
  const hbf* Qb = Q + (size_t)bh * T_ * 64;
  const hbf* Kb = K + (size_t)bh * T_ * 64;
  const hbf* Vtb = Vt + (size_t)bh * 64 * T_;
  hbf* Pw = &Ps[wave * (2 * 32 * 72)];
  // staging: lane -> LDS slot (row=tid>>3, chunk=tid&7); source chunk is
  // inverse-swizzled so LDS slot (r,c) holds global chunk c^(r&7).
  const int srow = tid >> 3, sc8 = tid & 7;
  const int swz = sc8 ^ (srow & 7);
  const hbf* gk = Kb + (size_t)srow * 64 + swz * 8;
  const hbf* gv = Vtb + (size_t)srow * T_ + swz * 8;
  hbf* lK = &Ksb[wave * 512];
  hbf* lV = &Vsb[wave * 512];
  const int sx = (l16 & 7) * 8;  // read-side elem swizzle for this lane's rows
  // Q fragments (B-operand): lane supplies Q[col=q(l16)][k=quad*8 in hh*32]
  bf16x8 qf[2][2];
#pragma unroll
  for (int i = 0; i < 2; i++)
#pragma unroll
    for (int hh = 0; hh < 2; hh++)
      qf[i][hh] = ldfrag(&Qb[(size_t)(q0 + qw + i * 16 + l16) * 64 + hh * 32 +
                             quad * 8]);
  const f32x4 zero = {0.f, 0.f, 0.f, 0.f};
  f32x4 accO[2][4];
#pragma unroll
  for (int i = 0; i < 2; i++)
#pragma unroll
    for (int j = 0; j < 4; j++) accO[i][j] = zero;

  // prologue: stage tiles 0 and 1 (K slots 0/1, V slots 0/1)
  glds16(gk, lK);
  glds16(gk + 2048, lK + 2048);
  glds16(gv, lV);
  glds16(gv + (size_t)32 * T_, lV + 2048);
  glds16(gk + 4096, lK + 4096);
  glds16(gk + 4096 + 2048, lK + 4096 + 2048);
  glds16(gv + 64, lV + 4096);
  glds16(gv + (size_t)32 * T_ + 64, lV + 4096 + 2048);
  __syncthreads();

  // prologue compute: QK^T(0) -> P[0] (no PV yet)
  {
    const hbf* Kc = &Ksb[0];
    bf16x8 kf[4][2];
#pragma unroll
    for (int j = 0; j < 4; j++)
#pragma unroll
      for (int hh = 0; hh < 2; hh++)
        kf[j][hh] =
            ldfrag(&Kc[(j * 16 + l16) * 64 + ((hh * 32 + quad * 8) ^ sx)]);
    __builtin_amdgcn_s_setprio(1);
    f32x4 accS[2][4];
#pragma unroll
    for (int i = 0; i < 2; i++)
#pragma unroll
      for (int j = 0; j < 4; j++) {
        f32x4 a = mfma16(kf[j][0], qf[i][0], zero);
        accS[i][j] = mfma16(kf[j][1], qf[i][1], a);
      }
    __builtin_amdgcn_s_setprio(0);
#pragma unroll
    for (int i = 0; i < 2; i++)
#pragma unroll
      for (int j = 0; j < 4; j++) {
        union {
          hbf h4[4];
          uint2 u;
        } pk;
#pragma unroll
        for (int r = 0; r < 4; r++)
          pk.h4[r] = __float2bfloat16(fexp2(accS[i][j][r]));
        *(uint2*)&Pw[(i * 16 + l16) * 72 + j * 16 + quad * 4] = pk.u;
      }
  }
  __syncthreads();  // protect K slot 0 from the st=1 prefetch (tile 2)

  for (int st = 1; st < T_ / 64; st++) {
    const int kcur = st & 1;
    const int pcur = st & 1, pprev = pcur ^ 1;
    const int vprev = (st - 1) % 3;
    if (st < T_ / 64 - 1) {  // async prefetch tile st+1 (drains at barrier)
      const int knxt = (st + 1) & 1, vnxt = (st + 1) % 3;
      size_t ko = (size_t)(st + 1) * 4096;
      glds16(gk + ko, lK + knxt * 4096);
      glds16(gk + ko + 2048, lK + knxt * 4096 + 2048);
      glds16(gv + (st + 1) * 64, lV + vnxt * 4096);
      glds16(gv + (size_t)32 * T_ + (st + 1) * 64, lV + vnxt * 4096 + 2048);
    }
    const hbf* Kc = &Ksb[kcur * 4096];
    const hbf* Vp = &Vsb[vprev * 4096];
    // issue kf loads for QK(st) early (in-order lgkm: complete before pf use)
    bf16x8 kf[4][2];
#pragma unroll
    for (int j = 0; j < 4; j++)
#pragma unroll
      for (int hh = 0; hh < 2; hh++)
        kf[j][hh] =
            ldfrag(&Kc[(j * 16 + l16) * 64 + ((hh * 32 + quad * 8) ^ sx)]);
    // PV(st-1): A = P[prev] rows q, B = V'[prev] rows v
    bf16x8 pf[2][2];
#pragma unroll
    for (int i = 0; i < 2; i++)
#pragma unroll
      for (int hh = 0; hh < 2; hh++)
        pf[i][hh] = ldfrag(
            &Pw[pprev * (32 * 72) + (i * 16 + l16) * 72 + hh * 32 + quad * 8]);
    __builtin_amdgcn_s_setprio(1);
#pragma unroll
    for (int j2 = 0; j2 < 4; j2++) {
      bf16x8 vf0 = ldfrag(&Vp[(j2 * 16 + l16) * 64 + ((quad * 8) ^ sx)]);
      bf16x8 vf1 = ldfrag(&Vp[(j2 * 16 + l16) * 64 + ((32 + quad * 8) ^ sx)]);
#pragma unroll
      for (int i = 0; i < 2; i++) {
        accO[i][j2] = mfma16(pf[i][0], vf0, accO[i][j2]);
        accO[i][j2] = mfma16(pf[i][1], vf1, accO[i][j2]);
      }
    }
    // QK^T(st) swapped: accS[i][j] = D[s][q]
    f32x4 accS[2][4];
#pragma unroll
    for (int i = 0; i < 2; i++)
#pragma unroll
      for (int j = 0; j < 4; j++) {
        f32x4 a = mfma16(kf[j][0], qf[i][0], zero);
        accS[i][j] = mfma16(kf[j][1], qf[i][1], a);
      }
    __builtin_amdgcn_s_setprio(0);
    // exp2 -> bf16 pack -> P[cur] (8 b64 writes, s-consecutive)
#pragma unroll
    for (int i = 0; i < 2; i++)
#pragma unroll
      for (int j = 0; j < 4; j++) {
        union {
          hbf h4[4];
          uint2 u;
        } pk;
#pragma unroll
        for (int r = 0; r < 4; r++)
          pk.h4[r] = __float2bfloat16(fexp2(accS[i][j][r]));
        *(uint2*)&Pw[pcur * (32 * 72) + (i * 16 + l16) * 72 + j * 16 +
                     quad * 4] = pk.u;
      }
    __syncthreads();
  }
  // epilogue: PV(last tile): P[(T/64-1)&1], V[(T/64-1)%3]
  {
    const int pl = (T_ / 64 - 1) & 1;
    const hbf* Vp = &Vsb[((T_ / 64 - 1) % 3) * 4096];
    bf16x8 pf[2][2];
#pragma unroll
    for (int i = 0; i < 2; i++)
#pragma unroll
      for (int hh = 0; hh < 2; hh++)
        pf[i][hh] = ldfrag(
            &Pw[pl * (32 * 72) + (i * 16 + l16) * 72 + hh * 32 + quad * 8]);
    __builtin_amdgcn_s_setprio(1);
#pragma unroll
    for (int j2 = 0; j2 < 4; j2++) {
      bf16x8 vf0 = ldfrag(&Vp[(j2 * 16 + l16) * 64 + ((quad * 8) ^ sx)]);
      bf16x8 vf1 = ldfrag(&Vp[(j2 * 16 + l16) * 64 + ((32 + quad * 8) ^ sx)]);
#pragma unroll
      for (int i = 0; i < 2; i++) {
        accO[i][j2] = mfma16(pf[i][0], vf0, accO[i][j2]);
        accO[i][j2] = mfma16(pf[i][1], vf1, accO[i][j2]);
      }
    }
    __builtin_amdgcn_s_setprio(0);
  }
#pragma unroll
  for (int i = 0; i < 2; i++)
#pragma unroll
    for (int j2 = 0; j2 < 4; j2++)
#pragma unroll
      for (int r = 0; r < 4; r++) {
        int q = q0 + qw + i * 16 + quad * 4 + r;
        int v = j2 * 16 + l16;
        heads[((size_t)(b * T_ + q)) * D_ + h * 64 + v] =
            __float2bfloat16(accO[i][j2][r]);
      }
}

// ---------------------------------------------------------------------------
// LN1 normalize (stats came fused from the out-proj GEMM). Vectorized
// 4x bf16 in/out (G13).
// ---------------------------------------------------------------------------
__global__ __launch_bounds__(256) void ln_norm(const hbf* __restrict__ src,
                                               const float* __restrict__ red,
                                               void* dst,
                                               const int* __restrict__ flag,
                                               int force_bf) {
  const int isbf = force_bf ? 1 : *flag;
  const float invN = 1.f / (float)(T_ * D_);
  const uint2* sv = (const uint2*)src;
  for (size_t i = (size_t)blockIdx.x * 256 + threadIdx.x;
       i < (size_t)B_ * T_ * D_ / 4; i += (size_t)gridDim.x * 256) {
    int b = (int)(i >> 19);  // per-batch 4-elem count = T*D/4 = 2^19
    float mu = red[b * 2 + 0] * invN;
    float var = red[b * 2 + 1] * invN - mu * mu;
    float rstd = rsqrtf(var + EPS_);
    union {
      uint2 u;
      hbf h[4];
    } s;
    s.u = sv[i];
    float out[4];
#pragma unroll
    for (int r = 0; r < 4; r++) out[r] = (bf2f(s.h[r]) - mu) * rstd;
    if (isbf) {
      union {
        hbf h[4];
        uint2 u;
      } pk;
#pragma unroll
      for (int r = 0; r < 4; r++) pk.h[r] = __float2bfloat16(out[r]);
      ((uint2*)dst)[i] = pk.u;
    } else {
      float4 f{out[0], out[1], out[2], out[3]};
      ((float4*)dst)[i] = f;
    }
  }
}

// ---------------------------------------------------------------------------
// LN2 stats over r2 = P0+P1+b2+o1 (r2 never materialized). Vectorized:
// float4 partial loads + uint2 (4x bf16) o1/b2 loads (G13).
// ---------------------------------------------------------------------------
__global__ __launch_bounds__(256) void ln2_stats(const float* __restrict__ P0,
                                                 const float* __restrict__ P1,
                                                 const hbf* __restrict__ o1,
                                                 const hbf* __restrict__ b2b,
                                                 float* __restrict__ red) {
  __shared__ float s1[256], s2[256];
  const int b = blockIdx.y;
  const size_t base = (size_t)b * (T_ * D_ / 4);
  const float4* P0v = (const float4*)P0;
  const float4* P1v = (const float4*)P1;
  const uint2* o1v = (const uint2*)o1;
  const uint2* b2v = (const uint2*)b2b;
  float sum = 0.f, sq = 0.f;
  for (size_t i = (size_t)blockIdx.x * 256 + threadIdx.x;
       i < (size_t)(T_ * D_ / 4); i += (size_t)gridDim.x * 256) {
    float4 p0 = P0v[base + i], p1 = P1v[base + i];
    union {
      uint2 u;
      hbf h[4];
    } o, bb;
    o.u = o1v[base + i];
    bb.u = b2v[i & (D_ / 4 - 1)];
#pragma unroll
    for (int r = 0; r < 4; r++) {
      float v = (&p0.x)[r] + (&p1.x)[r] + bf2f(bb.h[r]) + bf2f(o.h[r]);
      sum += v;
      sq += v * v;
    }
  }
  s1[threadIdx.x] = sum;
  s2[threadIdx.x] = sq;
  __syncthreads();
  for (int off = 128; off > 0; off >>= 1) {
    if ((int)threadIdx.x < off) {
      s1[threadIdx.x] += s1[threadIdx.x + off];
      s2[threadIdx.x] += s2[threadIdx.x + off];
    }
    __syncthreads();
  }
  if (threadIdx.x == 0) {
    atomicAdd(&red[b * 2 + 0], s1[0]);
    atomicAdd(&red[b * 2 + 1], s2[0]);
  }
}

__global__ __launch_bounds__(256) void ln2_norm(
    const float* __restrict__ P0, const float* __restrict__ P1,
    const hbf* __restrict__ o1, const hbf* __restrict__ b2b,
    const float* __restrict__ red, void* dst, const int* __restrict__ flag) {
  const int isbf = *flag;
  const float invN = 1.f / (float)(T_ * D_);
  const float4* P0v = (const float4*)P0;
  const float4* P1v = (const float4*)P1;
  const uint2* o1v = (const uint2*)o1;
  const uint2* b2v = (const uint2*)b2b;
  for (size_t i = (size_t)blockIdx.x * 256 + threadIdx.x;
       i < (size_t)B_ * T_ * D_ / 4; i += (size_t)gridDim.x * 256) {
    int b = (int)(i >> 19);  // per-batch float4 count = T*D/4 = 2^19
    float mu = red[b * 2 + 0] * invN;
    float var = red[b * 2 + 1] * invN - mu * mu;
    float rstd = rsqrtf(var + EPS_);
    float4 p0 = P0v[i], p1 = P1v[i];
    union {
      uint2 u;
      hbf h[4];
    } o, bb;
    o.u = o1v[i];
    bb.u = b2v[i & (D_ / 4 - 1)];
    float out[4];
#pragma unroll
    for (int r = 0; r < 4; r++)
      out[r] =
          ((&p0.x)[r] + (&p1.x)[r] + bf2f(bb.h[r]) + bf2f(o.h[r]) - mu) * rstd;
    if (isbf) {
      union {
        hbf h[4];
        uint2 u;
      } pk;
#pragma unroll
      for (int r = 0; r < 4; r++) pk.h[r] = __float2bfloat16(out[r]);
      ((uint2*)dst)[i] = pk.u;
    } else {
      float4 f{out[0], out[1], out[2], out[3]};
      ((float4*)dst)[i] = f;
    }
  }
}

// ---------------------------------------------------------------------------
// Workspace (MiB offsets), ~88.1 MB total:
//  [0,8) xb | [8,14) Wqkvt | [14,16) Wot | [16,24) W1t | [24,32) W2t
//  [32,40) Q | [40,48) K | [48,56) V | [56,64) Vt | [64,72) heads
//  [72,80) r1 | [80,88) o1 | ff1 aliases [32,64)
//  split-K partials (fp32, 16 MB each): P0 over [0,16), P1 over [64,80)
//  [88,..) b1b 8K | b2b 2K | red 32B | flag 4B
// ---------------------------------------------------------------------------
extern "C" void kernel_launch(void* const* d_in, const int* in_sizes, int n_in,
                              void* d_out, int out_size, void* d_ws,
                              size_t ws_size, hipStream_t stream) {
  const void* x = d_in[0];
  const void* Wq = d_in[1];
  const void* Wk = d_in[2];
  const void* Wv = d_in[3];
  const void* Wo = d_in[4];
  const void* W1 = d_in[5];
  const void* W2 = d_in[7];
  const void* b1 = d_in[6];
  const void* b2 = d_in[8];

  const size_t MB = 1024 * 1024;
  if (ws_size < 89 * MB) return;

  char* w = (char*)d_ws;
  hbf* xb = (hbf*)(w + 0 * MB);
  hbf* wqkvt = (hbf*)(w + 8 * MB);
  hbf* wot = (hbf*)(w + 14 * MB);
  hbf* w1t = (hbf*)(w + 16 * MB);
  hbf* w2t = (hbf*)(w + 24 * MB);
  hbf* Qb = (hbf*)(w + 32 * MB);
  hbf* Kb = (hbf*)(w + 40 * MB);
  hbf* Vb = (hbf*)(w + 48 * MB);
  hbf* Vtb = (hbf*)(w + 56 * MB);
  hbf* heads = (hbf*)(w + 64 * MB);
  hbf* r1 = (hbf*)(w + 72 * MB);
  hbf* o1 = (hbf*)(w + 80 * MB);
  hbf* ff1 = (hbf*)(w + 32 * MB);   // over dead Q/K/V/Vt
  float* P0 = (float*)(w + 0 * MB);   // over dead xb/wqkvt/wot (16 MB)
  float* P1 = (float*)(w + 64 * MB);  // over dead heads/r1 (16 MB)
  hbf* b1b = (hbf*)(w + 88 * MB);
  hbf* b2b = b1b + FF_;
  float* red = (float*)(b2b + D_);
  int* flag = (int*)(red + 8);

  hipMemsetAsync(red, 0, 8 * sizeof(float) + sizeof(int), stream);
  detect_dtype<<<1, 256, 0, stream>>>((const unsigned*)x, flag);

  const int M = B_ * T_;  // 4096
  // --- one-launch preconversion ---
  preconv<<<13314, 256, 0, stream>>>(x, Wq, Wk, Wv, Wo, W1, W2, b1, b2, xb,
                                     wqkvt, wot, w1t, w2t, b1b, b2b, flag);
  // --- QKV fused projection; TR grid: bx = m-tiles (32), pins A per XCD ---
  gemm_bt<0, 128, 128, 64, 1><<<dim3(32, 24), 256, 0, stream>>>(
      xb, wqkvt, Qb, nullptr, nullptr, nullptr, nullptr, M, 3 * D_, D_, D_);
  // --- attention: col-softmax stats + fused V scale/transpose, then apply ---
  attn_stats<<<dim3(32, 32), 256, 0, stream>>>(Qb, Kb, Vb, Vtb);
  attn_apply<<<dim3(16, 32), 256, 0, stream>>>(Qb, Kb, Vtb, heads);
  // --- out-proj + residual + fused LN1 stats; TR grid (32 m-tiles first) ---
  gemm_bt<1, 128, 64, 64, 1><<<dim3(32, 16), 256, 0, stream>>>(
      heads, wot, r1, nullptr, nullptr, xb, red, M, D_, D_, D_);
  ln_norm<<<2048, 256, 0, stream>>>(r1, red, o1, flag, 1);
  // --- FFN1: 256x256 double-buffered single-barrier kernel (grid = 1/CU) ---
  gemm256_relu<<<dim3(FF_ / 256, M / 256), 512, 0, stream>>>(
      o1, w1t, ff1, b1b, FF_, D_, D_);
  // --- FFN2 split-K=2 -> fp32 partials; TR grid: A(ff1) panels pinned per
  //     XCD (A-stream was 135MB measured; B-stream <= 64MB) ---
  gemm_bt<4, 128, 128, 64, 1><<<dim3(32, 8, 2), 256, 0, stream>>>(
      ff1, w2t, nullptr, P0, P1, nullptr, nullptr, M, D_, FF_ / 2, FF_);
  // --- LN2 (r2 = P0+P1+b2+o1, never materialized; vectorized) ---
  ln2_stats<<<dim3(256, B_), 256, 0, stream>>>(P0, P1, o1, b2b, red + 4);
  ln2_norm<<<2048, 256, 0, stream>>>(P0, P1, o1, b2b, red + 4, d_out, flag);
}

// Round 13
// 429.708 us; speedup vs baseline: 1.1211x; 1.0197x over previous
//
#include <hip/hip_runtime.h>
#include <hip/hip_bf16.h>
#include <cstddef>
#include <cstdint>

typedef __hip_bfloat16 hbf;
typedef __attribute__((ext_vector_type(8))) __bf16 bf16x8;
typedef __attribute__((ext_vector_type(4))) float f32x4;

#define B_ 2
#define T_ 2048
#define D_ 1024
#define H_ 16
#define FF_ 4096
#define EPS_ 1e-5f
// Q pre-scale = log2(e)/sqrt(dk): attention exponentials become native exp2
#define SCALE_ 0.18033688011112f

__device__ __forceinline__ float bf2f(hbf v) { return __bfloat162float(v); }
__device__ __forceinline__ float fexp2(float x) {
  return __builtin_amdgcn_exp2f(x);  // v_exp_f32 (2^x native)
}
__device__ __forceinline__ float flog2(float x) {
  return __builtin_amdgcn_logf(x);  // v_log_f32 (log2 native)
}
__device__ __forceinline__ float ldin(const void* p, size_t i, int isbf) {
  return isbf ? __bfloat162float(((const hbf*)p)[i]) : ((const float*)p)[i];
}
__device__ __forceinline__ void ston(void* p, size_t i, float v, int isbf) {
  if (isbf) ((hbf*)p)[i] = __float2bfloat16(v);
  else ((float*)p)[i] = v;
}
__device__ __forceinline__ f32x4 mfma16(bf16x8 a, bf16x8 b, f32x4 c) {
  return __builtin_amdgcn_mfma_f32_16x16x32_bf16(a, b, c, 0, 0, 0);
}
__device__ __forceinline__ bf16x8 ldfrag(const hbf* p) {
  return *(const bf16x8*)p;
}
// async global->LDS, 16B/lane; LDS base wave-uniform (HW: lane i -> base+i*16)
__device__ __forceinline__ void glds16(const hbf* g, hbf* l) {
  __builtin_amdgcn_global_load_lds(
      (const __attribute__((address_space(1))) void*)g,
      (__attribute__((address_space(3))) void*)l, 16, 0, 0);
}

// ---------------------------------------------------------------------------
// Runtime input-dtype detection (bf16 vs fp32), from bit patterns of x.
// ---------------------------------------------------------------------------
__global__ __launch_bounds__(256) void detect_dtype(const unsigned* x,
                                                    int* flag) {
  __shared__ int cnt[256];
  int c = 0;
  for (int i = threadIdx.x; i < 4096; i += 256) {
    unsigned low = x[i] & 0xFFFFu;
    unsigned e = (low >> 7) & 0xFFu;
    if (e >= 100u && e <= 142u) c++;
  }
  cnt[threadIdx.x] = c;
  __syncthreads();
  for (int off = 128; off > 0; off >>= 1) {
    if ((int)threadIdx.x < off) cnt[threadIdx.x] += cnt[threadIdx.x + off];
    __syncthreads();
  }
  if (threadIdx.x == 0) *flag = (cnt[0] > 2458) ? 1 : 0;
}

// ---------------------------------------------------------------------------
// Mega-preconversion: one launch does all weight transposes + x/bias converts.
// Flat block-id job table:
//  [0,3072)      Wq/Wk/Wv -> wqkvt (head-sliced transpose, R=1024,C=64,z=16)
//  [3072,4096)   Wo -> wot          (1024x1024)
//  [4096,8192)   W1 -> w1t          (1024x4096)
//  [8192,12288)  W2 -> w2t          (4096x1024)
//  [12288,13312) x -> xb            (4M elements, 4096/block, vectorized)
//  13312: b1 -> b1b ; 13313: b2 -> b2b
// ---------------------------------------------------------------------------
__device__ __forceinline__ void tr_tile(const void* __restrict__ src,
                                        hbf* __restrict__ dst, int R, int C,
                                        size_t zoff, int cx, int ry, int f,
                                        float (*tile)[33]) {
  const int tx = threadIdx.x & 31, ty = threadIdx.x >> 5;
  const int c0 = cx * 32, r0 = ry * 32;
#pragma unroll
  for (int p = 0; p < 4; p++) {
    int rr = p * 8 + ty;
    tile[rr][tx] = ldin(src, zoff + (size_t)(r0 + rr) * C + c0 + tx, f);
  }
  __syncthreads();
#pragma unroll
  for (int p = 0; p < 4; p++) {
    int cc = p * 8 + ty;
    dst[zoff + (size_t)(c0 + cc) * R + r0 + tx] = __float2bfloat16(tile[tx][cc]);
  }
}

__global__ __launch_bounds__(256) void preconv(
    const void* __restrict__ x, const void* __restrict__ Wq,
    const void* __restrict__ Wk, const void* __restrict__ Wv,
    const void* __restrict__ Wo, const void* __restrict__ W1,
    const void* __restrict__ W2, const void* __restrict__ b1,
    const void* __restrict__ b2, hbf* __restrict__ xb,
    hbf* __restrict__ wqkvt, hbf* __restrict__ wot, hbf* __restrict__ w1t,
    hbf* __restrict__ w2t, hbf* __restrict__ b1b, hbf* __restrict__ b2b,
    const int* __restrict__ flag) {
  __shared__ float tile[32][33];
  const int f = *flag;
  const int bid = blockIdx.x;
  if (bid < 3072) {
    int which = bid >> 10;  // 0=Wq 1=Wk 2=Wv
    int r = bid & 1023;
    int z = r >> 6, rem = r & 63;
    int ry = rem >> 1, cx = rem & 1;
    const void* src = (which == 0) ? Wq : (which == 1) ? Wk : Wv;
    hbf* dst = wqkvt + (size_t)which * (D_ * D_);
    tr_tile(src, dst, 1024, 64, (size_t)z * 65536, cx, ry, f, tile);
  } else if (bid < 4096) {
    int t = bid - 3072;
    tr_tile(Wo, wot, 1024, 1024, 0, t & 31, t >> 5, f, tile);
  } else if (bid < 8192) {
    int t = bid - 4096;
    tr_tile(W1, w1t, 1024, 4096, 0, t & 127, t >> 7, f, tile);
  } else if (bid < 12288) {
    int t = bid - 8192;
    tr_tile(W2, w2t, 4096, 1024, 0, t & 31, t >> 5, f, tile);
  } else if (bid < 13312) {
    size_t base = (size_t)(bid - 12288) * 4096;
    if (f) {
      // bf16 input: straight 16B copies
      const uint4* src = (const uint4*)((const hbf*)x + base);
      uint4* dst = (uint4*)(xb + base);
      for (int i = threadIdx.x; i < 512; i += 256) dst[i] = src[i];
    } else {
      // fp32 input: float4 x2 -> 8 bf16 packed (uint2x2)
      const float4* src = (const float4*)((const float*)x + base);
      for (int i = threadIdx.x; i < 512; i += 256) {
        float4 a = src[i * 2], b = src[i * 2 + 1];
        union {
          hbf h[8];
          uint4 u;
        } o;
        o.h[0] = __float2bfloat16(a.x);
        o.h[1] = __float2bfloat16(a.y);
        o.h[2] = __float2bfloat16(a.z);
        o.h[3] = __float2bfloat16(a.w);
        o.h[4] = __float2bfloat16(b.x);
        o.h[5] = __float2bfloat16(b.y);
        o.h[6] = __float2bfloat16(b.z);
        o.h[7] = __float2bfloat16(b.w);
        *(uint4*)(xb + base + (size_t)i * 8) = o.u;
      }
    }
  } else if (bid == 13312) {
    for (int i = threadIdx.x; i < FF_; i += 256)
      b1b[i] = __float2bfloat16(ldin(b1, i, f));
  } else {
    for (int i = threadIdx.x; i < D_; i += 256)
      b2b[i] = __float2bfloat16(ldin(b2, i, f));
  }
}

// ---------------------------------------------------------------------------
// MFMA GEMM (m97 structure): C(MxN) = A(MxK) @ Bt(NxK)^T, bf16, fp32 accum.
// BMxBN tile, BK=64, glds width-16 staging, 4 waves 2x2.
// TR: grid transpose -- blockIdx.x walks M-tiles (gridDim.x % 8 == 0 so
// XCD = bx%8 pins A-PANELS per XCD instead of B). Rule: pin the operand
// with the larger stream (verified R11: FFN2 FETCH 135->33MB, out of top5).
// Used for out-proj and FFN2-splitK (grids too small for the 256 tile).
// MODE 1: C = acc + e1[m*N+n]; fused LN stats -> atomicAdd red[batch]
// MODE 4: Cf_z[m*N+n] = acc  (fp32 split-K partial, z = blockIdx.z)
// ---------------------------------------------------------------------------
template <int MODE, int BM, int BN, int BK, int TR>
__global__ __launch_bounds__(256) void gemm_bt(
    const hbf* __restrict__ A, const hbf* __restrict__ Bt, hbf* __restrict__ C,
    float* __restrict__ Cf0, float* __restrict__ Cf1,
    const hbf* __restrict__ e1, float* __restrict__ red, int M, int N, int K,
    int LDK) {
  constexpr int WM = BM / 2, WN = BN / 2;
  constexpr int IF = WM / 16, JF = WN / 16;
  constexpr int HK = BK / 32;     // 32-wide k-chunks per K-step
  constexpr int LPT = BK / 8;     // lanes covering one row (8 hbf/lane)
  constexpr int CPR = 2048 / BK;  // rows staged per glds chunk (4KB)
  __shared__ alignas(16) hbf As[BM * BK];
  __shared__ alignas(16) hbf Bs[BN * BK];
  const int tid = threadIdx.x;
  const int wave = tid >> 6, lane = tid & 63;
  const int quad = lane >> 4, l16 = lane & 15;
  const int m0 = (TR ? blockIdx.x : blockIdx.y) * BM;
  const int n0 = (TR ? blockIdx.y : blockIdx.x) * BN;
  const int mw = (wave >> 1) * WM, nw = (wave & 1) * WN;
  const int srow = tid / LPT;
  const int scol = (tid % LPT) * 8;
  const int kbase = (MODE == 4) ? blockIdx.z * K : 0;
  const f32x4 zero = {0.f, 0.f, 0.f, 0.f};
  f32x4 acc[IF][JF];
#pragma unroll
  for (int i = 0; i < IF; i++)
#pragma unroll
    for (int j = 0; j < JF; j++) acc[i][j] = zero;

  const hbf* ga = &A[(size_t)(m0 + srow) * LDK + kbase + scol];
  const hbf* gb = &Bt[(size_t)(n0 + srow) * LDK + kbase + scol];
  hbf* lA = &As[wave * 512];
  hbf* lB = &Bs[wave * 512];

  for (int k0 = 0; k0 < K; k0 += BK) {
#pragma unroll
    for (int c = 0; c < BM / CPR; c++)
      glds16(ga + (size_t)(c * CPR) * LDK + k0, lA + c * 2048);
#pragma unroll
    for (int c = 0; c < BN / CPR; c++)
      glds16(gb + (size_t)(c * CPR) * LDK + k0, lB + c * 2048);
    __syncthreads();
    bf16x8 af[HK][IF], bfr[HK][JF];
#pragma unroll
    for (int h = 0; h < HK; h++) {
#pragma unroll
      for (int i = 0; i < IF; i++)
        af[h][i] = ldfrag(&As[(mw + i * 16 + l16) * BK + h * 32 + quad * 8]);
#pragma unroll
      for (int j = 0; j < JF; j++)
        bfr[h][j] = ldfrag(&Bs[(nw + j * 16 + l16) * BK + h * 32 + quad * 8]);
    }
#pragma unroll
    for (int h = 0; h < HK; h++)
#pragma unroll
      for (int i = 0; i < IF; i++)
#pragma unroll
        for (int j = 0; j < JF; j++)
          acc[i][j] = mfma16(af[h][i], bfr[h][j], acc[i][j]);
    __syncthreads();
  }
  float ssum = 0.f, ssq = 0.f;
#pragma unroll
  for (int i = 0; i < IF; i++)
#pragma unroll
    for (int j = 0; j < JF; j++)
#pragma unroll
      for (int r = 0; r < 4; r++) {
        int m = m0 + mw + i * 16 + quad * 4 + r;
        int n = n0 + nw + j * 16 + l16;
        float v = acc[i][j][r];
        if (MODE == 1) {
          hbf hv = __float2bfloat16(v + bf2f(e1[(size_t)m * N + n]));
          C[(size_t)m * N + n] = hv;
          float fv = bf2f(hv);
          ssum += fv;
          ssq += fv * fv;
        } else if (MODE == 4) {
          float* Cf = blockIdx.z ? Cf1 : Cf0;
          Cf[(size_t)m * N + n] = v;
        }
      }
  if (MODE == 1) {
    // fused LN stats: block tile lies within one batch (BM=128 | 2048)
    float* sc = (float*)As;  // dead LDS reuse (post final barrier)
    sc[tid] = ssum;
    sc[256 + tid] = ssq;
    __syncthreads();
    for (int off = 128; off > 0; off >>= 1) {
      if (tid < off) {
        sc[tid] += sc[tid + off];
        sc[256 + tid] += sc[256 + tid + off];
      }
      __syncthreads();
    }
    if (tid == 0) {
      int b = m0 >> 11;
      atomicAdd(&red[b * 2 + 0], sc[0]);
      atomicAdd(&red[b * 2 + 1], sc[256]);
    }
  }
}

// ---------------------------------------------------------------------------
// 256x256-tile double-buffered GEMM (8 waves 2x4, 64 MFMA per wave per
// K-tile against ONE barrier; prefetch of t+1 issued before compute of t;
// 128KB LDS, 1 block/CU). Verified R10: FFN1 69.6us -> out of top-5 vs the
// 128 2-barrier tile. Templated:
//  MODE 2: C = relu(acc + bias[n])                       (FFN1; grid 16x16)
//  MODE 0: QKV scatter to (which,B,H,T,64), Q pre-scaled (grid 12x16;
//          256 | 1024 so a tile never straddles a which boundary)
// ---------------------------------------------------------------------------
template <int MODE>
__global__ __launch_bounds__(512) void gemm256(
    const hbf* __restrict__ A, const hbf* __restrict__ Bt, hbf* __restrict__ C,
    const hbf* __restrict__ bias, int N, int K, int LDK) {
  __shared__ alignas(16) hbf As[2][256 * 64];
  __shared__ alignas(16) hbf Bs[2][256 * 64];
  const int tid = threadIdx.x;
  const int wave = tid >> 6, lane = tid & 63;
  const int quad = lane >> 4, l16 = lane & 15;
  const int wr = wave >> 2, wc = wave & 3;  // 2x4 wave grid
  const int m0 = blockIdx.y * 256, n0 = blockIdx.x * 256;
  const int mw = wr * 128, nw = wc * 64;
  const int srow = tid >> 3;       // 0..63 (rows within a 64-row chunk)
  const int scol = (tid & 7) * 8;  // 0..56
  const hbf* ga = &A[(size_t)(m0 + srow) * LDK + scol];
  const hbf* gb = &Bt[(size_t)(n0 + srow) * LDK + scol];
  const int lbase = wave * 512;  // wave-uniform LDS base within a chunk
  const f32x4 zero = {0.f, 0.f, 0.f, 0.f};
  f32x4 acc[8][4];
#pragma unroll
  for (int i = 0; i < 8; i++)
#pragma unroll
    for (int j = 0; j < 4; j++) acc[i][j] = zero;

  const int NT = K / 64;
  // prologue: stage tile 0 into buffer 0
#pragma unroll
  for (int c = 0; c < 4; c++) {
    glds16(ga + (size_t)(c * 64) * LDK, &As[0][c * 4096 + lbase]);
    glds16(gb + (size_t)(c * 64) * LDK, &Bs[0][c * 4096 + lbase]);
  }
  __syncthreads();

  for (int t = 0; t < NT; t++) {
    const int cur = t & 1;
    if (t < NT - 1) {  // async prefetch t+1 into the other buffer;
                       // drains at the end-of-iteration barrier
      size_t ko = (size_t)(t + 1) * 64;
#pragma unroll
      for (int c = 0; c < 4; c++) {
        glds16(ga + (size_t)(c * 64) * LDK + ko,
               &As[cur ^ 1][c * 4096 + lbase]);
        glds16(gb + (size_t)(c * 64) * LDK + ko,
               &Bs[cur ^ 1][c * 4096 + lbase]);
      }
    }
    // compute tile t from buffer cur: 2 k-halves x (8 m x 4 n) MFMA
#pragma unroll
    for (int h = 0; h < 2; h++) {
      bf16x8 bfr[4];
#pragma unroll
      for (int j = 0; j < 4; j++)
        bfr[j] = ldfrag(&Bs[cur][(nw + j * 16 + l16) * 64 + h * 32 + quad * 8]);
#pragma unroll
      for (int i = 0; i < 8; i++) {
        bf16x8 af =
            ldfrag(&As[cur][(mw + i * 16 + l16) * 64 + h * 32 + quad * 8]);
#pragma unroll
        for (int j = 0; j < 4; j++)
          acc[i][j] = mfma16(af, bfr[j], acc[i][j]);
      }
    }
    __syncthreads();  // drains prefetch vmcnt + protects buffer reuse
  }
  // epilogue
#pragma unroll
  for (int i = 0; i < 8; i++)
#pragma unroll
    for (int j = 0; j < 4; j++)
#pragma unroll
      for (int r = 0; r < 4; r++) {
        int m = m0 + mw + i * 16 + quad * 4 + r;
        int n = n0 + nw + j * 16 + l16;
        float v = acc[i][j][r];
        if (MODE == 2) {
          C[(size_t)m * N + n] =
              __float2bfloat16(fmaxf(v + bf2f(bias[n]), 0.f));
        } else if (MODE == 0) {
          int which = n >> 10, n1 = n & 1023;
          int hd = n1 >> 6, cc = n1 & 63;
          int bb = m >> 11, tt = m & (T_ - 1);
          if (which == 0) v *= SCALE_;  // pre-scale Q by log2e/sqrt(dk)
          C[(size_t)which * ((size_t)B_ * H_ * T_ * 64) +
            (((size_t)(bb * H_ + hd)) * T_ + tt) * 64 + cc] =
              __float2bfloat16(v);
        }
      }
}

// ---------------------------------------------------------------------------
// Attention stats + V-transform (MFMA): S = Q K^T (Q pre-scaled by log2e/8,
// so all exponentials are base-2 -> native v_exp_f32).
//   adj[s] = max_q S[q,s] + log2(sum_q 2^(S[q,s]-max))
// Tail (fused, block owns its 64 s-rows): Vt'[v,s] = V[s,v]*2^(-adj[s]).
// Block: 64 s (4 waves x 16), loops q-tiles of 64. Padded LDS stride 72.
// ---------------------------------------------------------------------------
__global__ __launch_bounds__(256) void attn_stats(const hbf* __restrict__ Q,
                                                  const hbf* __restrict__ K,
                                                  const hbf* __restrict__ V,
                                                  hbf* __restrict__ Vt) {
  __shared__ alignas(16) hbf Ks[64 * 72];
  __shared__ alignas(16) hbf Qs[64 * 72];
  __shared__ float sAdj[64];
  const int bh = blockIdx.y;
  const int s0 = blockIdx.x * 64;
  const int tid = threadIdx.x;
  const int wave = tid >> 6, lane = tid & 63;
  const int quad = lane >> 4, l16 = lane & 15;
  const int sw = wave * 16;
  const hbf* Kb = K + (size_t)bh * T_ * 64;
  const hbf* Qb = Q + (size_t)bh * T_ * 64;
  const hbf* Vb = V + (size_t)bh * T_ * 64;
  hbf* Vtb = Vt + (size_t)bh * 64 * T_;
  const int r_ = tid >> 3, c_ = (tid & 7) * 8;
#pragma unroll
  for (int c = 0; c < 2; c++) {
    int row = c * 32 + r_;
    *(float4*)(&Ks[row * 72 + c_]) =
        *(const float4*)(&Kb[(size_t)(s0 + row) * 64 + c_]);
  }
  __syncthreads();
  bf16x8 kf0 = ldfrag(&Ks[(sw + l16) * 72 + quad * 8]);
  bf16x8 kf1 = ldfrag(&Ks[(sw + l16) * 72 + 32 + quad * 8]);
  float m_thr[4], l_thr[4];
#pragma unroll
  for (int r = 0; r < 4; r++) {
    m_thr[r] = -1e30f;
    l_thr[r] = 0.f;
  }
  const f32x4 zero = {0.f, 0.f, 0.f, 0.f};
  for (int qt = 0; qt < T_ / 64; qt++) {
    if (qt) __syncthreads();
#pragma unroll
    for (int c = 0; c < 2; c++) {
      int row = c * 32 + r_;
      *(float4*)(&Qs[row * 72 + c_]) =
          *(const float4*)(&Qb[(size_t)(qt * 64 + row) * 64 + c_]);
    }
    __syncthreads();
    f32x4 acc[4];
#pragma unroll
    for (int j = 0; j < 4; j++) {
      bf16x8 qf0 = ldfrag(&Qs[(j * 16 + l16) * 72 + quad * 8]);
      bf16x8 qf1 = ldfrag(&Qs[(j * 16 + l16) * 72 + 32 + quad * 8]);
      f32x4 a = zero;
      a = mfma16(kf0, qf0, a);
      a = mfma16(kf1, qf1, a);
      acc[j] = a;
    }
#pragma unroll
    for (int r = 0; r < 4; r++) {
      float mt = fmaxf(fmaxf(acc[0][r], acc[1][r]),
                       fmaxf(acc[2][r], acc[3][r]));
      float nm = fmaxf(m_thr[r], mt);
      float s = l_thr[r] * fexp2(m_thr[r] - nm);
#pragma unroll
      for (int j = 0; j < 4; j++) s += fexp2(acc[j][r] - nm);
      l_thr[r] = s;
      m_thr[r] = nm;
    }
  }
#pragma unroll
  for (int d = 1; d < 16; d <<= 1) {
#pragma unroll
    for (int r = 0; r < 4; r++) {
      float om = __shfl_xor(m_thr[r], d);
      float ol = __shfl_xor(l_thr[r], d);
      float nm = fmaxf(m_thr[r], om);
      l_thr[r] = l_thr[r] * fexp2(m_thr[r] - nm) + ol * fexp2(om - nm);
      m_thr[r] = nm;
    }
  }
  if (l16 == 0) {
#pragma unroll
    for (int r = 0; r < 4; r++)
      sAdj[sw + quad * 4 + r] = m_thr[r] + flog2(l_thr[r]);
  }
  __syncthreads();
  // fused V scale+transpose for this block's s-range (reuse Ks as tile)
#pragma unroll
  for (int c = 0; c < 2; c++) {
    int e = (c * 256 + tid) * 8;
    int r = e >> 6, col = e & 63;
    union alignas(16) {
      hbf h[8];
      float4 f4;
    } u;
    u.f4 = *(const float4*)(&Vb[(size_t)(s0 + r) * 64 + col]);
    float sc = fexp2(-sAdj[r]);
#pragma unroll
    for (int k2 = 0; k2 < 8; k2++)
      u.h[k2] = __float2bfloat16(bf2f(u.h[k2]) * sc);
    *(float4*)(&Ks[r * 72 + col]) = u.f4;
  }
  __syncthreads();
#pragma unroll
  for (int c = 0; c < 2; c++) {
    int e = (c * 256 + tid) * 8;
    int v = e >> 6, tt = e & 63;
    union alignas(16) {
      hbf h[8];
      float4 f4;
    } u;
#pragma unroll
    for (int k2 = 0; k2 < 8; k2++) u.h[k2] = Ks[(tt + k2) * 72 + v];
    *(float4*)(&Vtb[(size_t)v * T_ + s0 + tt]) = u.f4;
  }
}

// ---------------------------------------------------------------------------
// Attention apply (MFMA): O[q,v] = sum_s 2^(S[q,s]) * V'[s,v]
// (normalizer folded into V'). Cross-iteration pipeline: iteration st
// computes QK^T(st) AND PV(st-1) so PV's MFMAs overlap QK's load/exp chain.
//  * K double-buffered (16KB), V triple-buffered (24KB), P per-wave
//    double-buffered (37KB). 77KB total -> 2 blocks/CU (grid cap).
//  * staging via global_load_lds + XOR swizzle, one barrier per iteration,
//    s_setprio(1) around MFMA clusters.
// Block: 128 q (4 waves x 32), s-tiles of 64, grid (16,32).
// ---------------------------------------------------------------------------
__global__ __launch_bounds__(256) void attn_apply(const hbf* __restrict__ Q,
                                                  const hbf* __restrict__ K,
                                                  const hbf* __restrict__ Vt,
                                                  hbf* __restrict__ heads) {
  __shared__ alignas(16) hbf Ksb[2 * 64 * 64];
  __shared__ alignas(16) hbf Vsb[3 * 64 * 64];
  __shared__ alignas(16) hbf Ps[4 * 2 * 32 * 72];
  const int bh = blockIdx.y;
  const int b = bh >> 4, h = bh & 15;
  const int q0 = blockIdx.x * 128;
  const int tid = threadIdx.x;
  const int wave = tid >> 6, lane = tid & 63;
  const int quad = lane >> 4, l16 = lane & 15;
  const int qw = wave * 32;
  const hbf* Qb = Q + (size_t)bh * T_ * 64;
  const hbf* Kb = K + (size_t)bh * T_ * 64;
  const hbf* Vtb = Vt + (size_t)bh * 64 * T_;
  hbf* Pw = &Ps[wave * (2 * 32 * 72)];
  // staging: lane -> LDS slot (row=tid>>3, chunk=tid&7); source chunk is
  // inverse-swizzled so LDS slot (r,c) holds global chunk c^(r&7).
  const int srow = tid >> 3, sc8 = tid & 7;
  const int swz = sc8 ^ (srow & 7);
  const hbf* gk = Kb + (size_t)srow * 64 + swz * 8;
  const hbf* gv = Vtb + (size_t)srow * T_ + swz * 8;
  hbf* lK = &Ksb[wave * 512];
  hbf* lV = &Vsb[wave * 512];
  const int sx = (l16 & 7) * 8;  // read-side elem swizzle for this lane's rows
  // Q fragments (B-operand): lane supplies Q[col=q(l16)][k=quad*8 in hh*32]
  bf16x8 qf[2][2];
#pragma unroll
  for (int i = 0; i < 2; i++)
#pragma unroll
    for (int hh = 0; hh < 2; hh++)
      qf[i][hh] = ldfrag(&Qb[(size_t)(q0 + qw + i * 16 + l16) * 64 + hh * 32 +
                             quad * 8]);
  const f32x4 zero = {0.f, 0.f, 0.f, 0.f};
  f32x4 accO[2][4];
#pragma unroll
  for (int i = 0; i < 2; i++)
#pragma unroll
    for (int j = 0; j < 4; j++) accO[i][j] = zero;

  // prologue: stage tiles 0 and 1 (K slots 0/1, V slots 0/1)
  glds16(gk, lK);
  glds16(gk + 2048, lK + 2048);
  glds16(gv, lV);
  glds16(gv + (size_t)32 * T_, lV + 2048);
  glds16(gk + 4096, lK + 4096);
  glds16(gk + 4096 + 2048, lK + 4096 + 2048);
  glds16(gv + 64, lV + 4096);
  glds16(gv + (size_t)32 * T_ + 64, lV + 4096 + 2048);
  __syncthreads();

  // prologue compute: QK^T(0) -> P[0] (no PV yet)
  {
    const hbf* Kc = &Ksb[0];
    bf16x8 kf[4][2];
#pragma unroll
    for (int j = 0; j < 4; j++)
#pragma unroll
      for (int hh = 0; hh < 2; hh++)
        kf[j][hh] =
            ldfrag(&Kc[(j * 16 + l16) * 64 + ((hh * 32 + quad * 8) ^ sx)]);
    __builtin_amdgcn_s_setprio(1);
    f32x4 accS[2][4];
#pragma unroll
    for (int i = 0; i < 2; i++)
#pragma unroll
      for (int j = 0; j < 4; j++) {
        f32x4 a = mfma16(kf[j][0], qf[i][0], zero);
        accS[i][j] = mfma16(kf[j][1], qf[i][1], a);
      }
    __builtin_amdgcn_s_setprio(0);
#pragma unroll
    for (int i = 0; i < 2; i++)
#pragma unroll
      for (int j = 0; j < 4; j++) {
        union {
          hbf h4[4];
          uint2 u;
        } pk;
#pragma unroll
        for (int r = 0; r < 4; r++)
          pk.h4[r] = __float2bfloat16(fexp2(accS[i][j][r]));
        *(uint2*)&Pw[(i * 16 + l16) * 72 + j * 16 + quad * 4] = pk.u;
      }
  }
  __syncthreads();  // protect K slot 0 from the st=1 prefetch (tile 2)

  for (int st = 1; st < T_ / 64; st++) {
    const int kcur = st & 1;
    const int pcur = st & 1, pprev = pcur ^ 1;
    const int vprev = (st - 1) % 3;
    if (st < T_ / 64 - 1) {  // async prefetch tile st+1 (drains at barrier)
      const int knxt = (st + 1) & 1, vnxt = (st + 1) % 3;
      size_t ko = (size_t)(st + 1) * 4096;
      glds16(gk + ko, lK + knxt * 4096);
      glds16(gk + ko + 2048, lK + knxt * 4096 + 2048);
      glds16(gv + (st + 1) * 64, lV + vnxt * 4096);
      glds16(gv + (size_t)32 * T_ + (st + 1) * 64, lV + vnxt * 4096 + 2048);
    }
    const hbf* Kc = &Ksb[kcur * 4096];
    const hbf* Vp = &Vsb[vprev * 4096];
    // issue kf loads for QK(st) early (in-order lgkm: complete before pf use)
    bf16x8 kf[4][2];
#pragma unroll
    for (int j = 0; j < 4; j++)
#pragma unroll
      for (int hh = 0; hh < 2; hh++)
        kf[j][hh] =
            ldfrag(&Kc[(j * 16 + l16) * 64 + ((hh * 32 + quad * 8) ^ sx)]);
    // PV(st-1): A = P[prev] rows q, B = V'[prev] rows v
    bf16x8 pf[2][2];
#pragma unroll
    for (int i = 0; i < 2; i++)
#pragma unroll
      for (int hh = 0; hh < 2; hh++)
        pf[i][hh] = ldfrag(
            &Pw[pprev * (32 * 72) + (i * 16 + l16) * 72 + hh * 32 + quad * 8]);
    __builtin_amdgcn_s_setprio(1);
#pragma unroll
    for (int j2 = 0; j2 < 4; j2++) {
      bf16x8 vf0 = ldfrag(&Vp[(j2 * 16 + l16) * 64 + ((quad * 8) ^ sx)]);
      bf16x8 vf1 = ldfrag(&Vp[(j2 * 16 + l16) * 64 + ((32 + quad * 8) ^ sx)]);
#pragma unroll
      for (int i = 0; i < 2; i++) {
        accO[i][j2] = mfma16(pf[i][0], vf0, accO[i][j2]);
        accO[i][j2] = mfma16(pf[i][1], vf1, accO[i][j2]);
      }
    }
    // QK^T(st) swapped: accS[i][j] = D[s][q]
    f32x4 accS[2][4];
#pragma unroll
    for (int i = 0; i < 2; i++)
#pragma unroll
      for (int j = 0; j < 4; j++) {
        f32x4 a = mfma16(kf[j][0], qf[i][0], zero);
        accS[i][j] = mfma16(kf[j][1], qf[i][1], a);
      }
    __builtin_amdgcn_s_setprio(0);
    // exp2 -> bf16 pack -> P[cur] (8 b64 writes, s-consecutive)
#pragma unroll
    for (int i = 0; i < 2; i++)
#pragma unroll
      for (int j = 0; j < 4; j++) {
        union {
          hbf h4[4];
          uint2 u;
        } pk;
#pragma unroll
        for (int r = 0; r < 4; r++)
          pk.h4[r] = __float2bfloat16(fexp2(accS[i][j][r]));
        *(uint2*)&Pw[pcur * (32 * 72) + (i * 16 + l16) * 72 + j * 16 +
                     quad * 4] = pk.u;
      }
    __syncthreads();
  }
  // epilogue: PV(last tile): P[(T/64-1)&1], V[(T/64-1)%3]
  {
    const int pl = (T_ / 64 - 1) & 1;
    const hbf* Vp = &Vsb[((T_ / 64 - 1) % 3) * 4096];
    bf16x8 pf[2][2];
#pragma unroll
    for (int i = 0; i < 2; i++)
#pragma unroll
      for (int hh = 0; hh < 2; hh++)
        pf[i][hh] = ldfrag(
            &Pw[pl * (32 * 72) + (i * 16 + l16) * 72 + hh * 32 + quad * 8]);
    __builtin_amdgcn_s_setprio(1);
#pragma unroll
    for (int j2 = 0; j2 < 4; j2++) {
      bf16x8 vf0 = ldfrag(&Vp[(j2 * 16 + l16) * 64 + ((quad * 8) ^ sx)]);
      bf16x8 vf1 = ldfrag(&Vp[(j2 * 16 + l16) * 64 + ((32 + quad * 8) ^ sx)]);
#pragma unroll
      for (int i = 0; i < 2; i++) {
        accO[i][j2] = mfma16(pf[i][0], vf0, accO[i][j2]);
        accO[i][j2] = mfma16(pf[i][1], vf1, accO[i][j2]);
      }
    }
    __builtin_amdgcn_s_setprio(0);
  }
#pragma unroll
  for (int i = 0; i < 2; i++)
#pragma unroll
    for (int j2 = 0; j2 < 4; j2++)
#pragma unroll
      for (int r = 0; r < 4; r++) {
        int q = q0 + qw + i * 16 + quad * 4 + r;
        int v = j2 * 16 + l16;
        heads[((size_t)(b * T_ + q)) * D_ + h * 64 + v] =
            __float2bfloat16(accO[i][j2][r]);
      }
}

// ---------------------------------------------------------------------------
// LN1 normalize (stats came fused from the out-proj GEMM). Vectorized
// 4x bf16 in/out (G13).
// ---------------------------------------------------------------------------
__global__ __launch_bounds__(256) void ln_norm(const hbf* __restrict__ src,
                                               const float* __restrict__ red,
                                               void* dst,
                                               const int* __restrict__ flag,
                                               int force_bf) {
  const int isbf = force_bf ? 1 : *flag;
  const float invN = 1.f / (float)(T_ * D_);
  const uint2* sv = (const uint2*)src;
  for (size_t i = (size_t)blockIdx.x * 256 + threadIdx.x;
       i < (size_t)B_ * T_ * D_ / 4; i += (size_t)gridDim.x * 256) {
    int b = (int)(i >> 19);  // per-batch 4-elem count = T*D/4 = 2^19
    float mu = red[b * 2 + 0] * invN;
    float var = red[b * 2 + 1] * invN - mu * mu;
    float rstd = rsqrtf(var + EPS_);
    union {
      uint2 u;
      hbf h[4];
    } s;
    s.u = sv[i];
    float out[4];
#pragma unroll
    for (int r = 0; r < 4; r++) out[r] = (bf2f(s.h[r]) - mu) * rstd;
    if (isbf) {
      union {
        hbf h[4];
        uint2 u;
      } pk;
#pragma unroll
      for (int r = 0; r < 4; r++) pk.h[r] = __float2bfloat16(out[r]);
      ((uint2*)dst)[i] = pk.u;
    } else {
      float4 f{out[0], out[1], out[2], out[3]};
      ((float4*)dst)[i] = f;
    }
  }
}

// ---------------------------------------------------------------------------
// LN2 stats over r2 = P0+P1+b2+o1 (r2 never materialized). Vectorized:
// float4 partial loads + uint2 (4x bf16) o1/b2 loads (G13).
// ---------------------------------------------------------------------------
__global__ __launch_bounds__(256) void ln2_stats(const float* __restrict__ P0,
                                                 const float* __restrict__ P1,
                                                 const hbf* __restrict__ o1,
                                                 const hbf* __restrict__ b2b,
                                                 float* __restrict__ red) {
  __shared__ float s1[256], s2[256];
  const int b = blockIdx.y;
  const size_t base = (size_t)b * (T_ * D_ / 4);
  const float4* P0v = (const float4*)P0;
  const float4* P1v = (const float4*)P1;
  const uint2* o1v = (const uint2*)o1;
  const uint2* b2v = (const uint2*)b2b;
  float sum = 0.f, sq = 0.f;
  for (size_t i = (size_t)blockIdx.x * 256 + threadIdx.x;
       i < (size_t)(T_ * D_ / 4); i += (size_t)gridDim.x * 256) {
    float4 p0 = P0v[base + i], p1 = P1v[base + i];
    union {
      uint2 u;
      hbf h[4];
    } o, bb;
    o.u = o1v[base + i];
    bb.u = b2v[i & (D_ / 4 - 1)];
#pragma unroll
    for (int r = 0; r < 4; r++) {
      float v = (&p0.x)[r] + (&p1.x)[r] + bf2f(bb.h[r]) + bf2f(o.h[r]);
      sum += v;
      sq += v * v;
    }
  }
  s1[threadIdx.x] = sum;
  s2[threadIdx.x] = sq;
  __syncthreads();
  for (int off = 128; off > 0; off >>= 1) {
    if ((int)threadIdx.x < off) {
      s1[threadIdx.x] += s1[threadIdx.x + off];
      s2[threadIdx.x] += s2[threadIdx.x + off];
    }
    __syncthreads();
  }
  if (threadIdx.x == 0) {
    atomicAdd(&red[b * 2 + 0], s1[0]);
    atomicAdd(&red[b * 2 + 1], s2[0]);
  }
}

__global__ __launch_bounds__(256) void ln2_norm(
    const float* __restrict__ P0, const float* __restrict__ P1,
    const hbf* __restrict__ o1, const hbf* __restrict__ b2b,
    const float* __restrict__ red, void* dst, const int* __restrict__ flag) {
  const int isbf = *flag;
  const float invN = 1.f / (float)(T_ * D_);
  const float4* P0v = (const float4*)P0;
  const float4* P1v = (const float4*)P1;
  const uint2* o1v = (const uint2*)o1;
  const uint2* b2v = (const uint2*)b2b;
  for (size_t i = (size_t)blockIdx.x * 256 + threadIdx.x;
       i < (size_t)B_ * T_ * D_ / 4; i += (size_t)gridDim.x * 256) {
    int b = (int)(i >> 19);  // per-batch float4 count = T*D/4 = 2^19
    float mu = red[b * 2 + 0] * invN;
    float var = red[b * 2 + 1] * invN - mu * mu;
    float rstd = rsqrtf(var + EPS_);
    float4 p0 = P0v[i], p1 = P1v[i];
    union {
      uint2 u;
      hbf h[4];
    } o, bb;
    o.u = o1v[i];
    bb.u = b2v[i & (D_ / 4 - 1)];
    float out[4];
#pragma unroll
    for (int r = 0; r < 4; r++)
      out[r] =
          ((&p0.x)[r] + (&p1.x)[r] + bf2f(bb.h[r]) + bf2f(o.h[r]) - mu) * rstd;
    if (isbf) {
      union {
        hbf h[4];
        uint2 u;
      } pk;
#pragma unroll
      for (int r = 0; r < 4; r++) pk.h[r] = __float2bfloat16(out[r]);
      ((uint2*)dst)[i] = pk.u;
    } else {
      float4 f{out[0], out[1], out[2], out[3]};
      ((float4*)dst)[i] = f;
    }
  }
}

// ---------------------------------------------------------------------------
// Workspace (MiB offsets), ~88.1 MB total:
//  [0,8) xb | [8,14) Wqkvt | [14,16) Wot | [16,24) W1t | [24,32) W2t
//  [32,40) Q | [40,48) K | [48,56) V | [56,64) Vt | [64,72) heads
//  [72,80) r1 | [80,88) o1 | ff1 aliases [32,64)
//  split-K partials (fp32, 16 MB each): P0 over [0,16), P1 over [64,80)
//  [88,..) b1b 8K | b2b 2K | red 32B | flag 4B
// ---------------------------------------------------------------------------
extern "C" void kernel_launch(void* const* d_in, const int* in_sizes, int n_in,
                              void* d_out, int out_size, void* d_ws,
                              size_t ws_size, hipStream_t stream) {
  const void* x = d_in[0];
  const void* Wq = d_in[1];
  const void* Wk = d_in[2];
  const void* Wv = d_in[3];
  const void* Wo = d_in[4];
  const void* W1 = d_in[5];
  const void* W2 = d_in[7];
  const void* b1 = d_in[6];
  const void* b2 = d_in[8];

  const size_t MB = 1024 * 1024;
  if (ws_size < 89 * MB) return;

  char* w = (char*)d_ws;
  hbf* xb = (hbf*)(w + 0 * MB);
  hbf* wqkvt = (hbf*)(w + 8 * MB);
  hbf* wot = (hbf*)(w + 14 * MB);
  hbf* w1t = (hbf*)(w + 16 * MB);
  hbf* w2t = (hbf*)(w + 24 * MB);
  hbf* Qb = (hbf*)(w + 32 * MB);
  hbf* Kb = (hbf*)(w + 40 * MB);
  hbf* Vb = (hbf*)(w + 48 * MB);
  hbf* Vtb = (hbf*)(w + 56 * MB);
  hbf* heads = (hbf*)(w + 64 * MB);
  hbf* r1 = (hbf*)(w + 72 * MB);
  hbf* o1 = (hbf*)(w + 80 * MB);
  hbf* ff1 = (hbf*)(w + 32 * MB);   // over dead Q/K/V/Vt
  float* P0 = (float*)(w + 0 * MB);   // over dead xb/wqkvt/wot (16 MB)
  float* P1 = (float*)(w + 64 * MB);  // over dead heads/r1 (16 MB)
  hbf* b1b = (hbf*)(w + 88 * MB);
  hbf* b2b = b1b + FF_;
  float* red = (float*)(b2b + D_);
  int* flag = (int*)(red + 8);

  hipMemsetAsync(red, 0, 8 * sizeof(float) + sizeof(int), stream);
  detect_dtype<<<1, 256, 0, stream>>>((const unsigned*)x, flag);

  const int M = B_ * T_;  // 4096
  // --- one-launch preconversion ---
  preconv<<<13314, 256, 0, stream>>>(x, Wq, Wk, Wv, Wo, W1, W2, b1, b2, xb,
                                     wqkvt, wot, w1t, w2t, b1b, b2b, flag);
  // --- QKV fused projection: 256x256 double-buffered kernel (192 blocks,
  //     one pass; 256 | 1024 so tiles never straddle a which boundary) ---
  gemm256<0><<<dim3(3 * D_ / 256, M / 256), 512, 0, stream>>>(
      xb, wqkvt, Qb, nullptr, 3 * D_, D_, D_);
  // --- attention: col-softmax stats + fused V scale/transpose, then apply ---
  attn_stats<<<dim3(32, 32), 256, 0, stream>>>(Qb, Kb, Vb, Vtb);
  attn_apply<<<dim3(16, 32), 256, 0, stream>>>(Qb, Kb, Vtb, heads);
  // --- out-proj + residual + fused LN1 stats; TR grid (32 m-tiles first) ---
  gemm_bt<1, 128, 64, 64, 1><<<dim3(32, 16), 256, 0, stream>>>(
      heads, wot, r1, nullptr, nullptr, xb, red, M, D_, D_, D_);
  ln_norm<<<2048, 256, 0, stream>>>(r1, red, o1, flag, 1);
  // --- FFN1: 256x256 double-buffered single-barrier kernel (grid = 1/CU) ---
  gemm256<2><<<dim3(FF_ / 256, M / 256), 512, 0, stream>>>(
      o1, w1t, ff1, b1b, FF_, D_, D_);
  // --- FFN2 split-K=2 -> fp32 partials; TR grid: A(ff1) panels pinned per
  //     XCD (A-stream was 135MB measured; B-stream <= 64MB) ---
  gemm_bt<4, 128, 128, 64, 1><<<dim3(32, 8, 2), 256, 0, stream>>>(
      ff1, w2t, nullptr, P0, P1, nullptr, nullptr, M, D_, FF_ / 2, FF_);
  // --- LN2 (r2 = P0+P1+b2+o1, never materialized; vectorized) ---
  ln2_stats<<<dim3(256, B_), 256, 0, stream>>>(P0, P1, o1, b2b, red + 4);
  ln2_norm<<<2048, 256, 0, stream>>>(P0, P1, o1, b2b, red + 4, d_out, flag);
}

// Round 14
// 429.629 us; speedup vs baseline: 1.1213x; 1.0002x over previous
//
#include <hip/hip_runtime.h>
#include <hip/hip_bf16.h>
#include <cstddef>
#include <cstdint>

typedef __hip_bfloat16 hbf;
typedef __attribute__((ext_vector_type(8))) __bf16 bf16x8;
typedef __attribute__((ext_vector_type(4))) float f32x4;

#define B_ 2
#define T_ 2048
#define D_ 1024
#define H_ 16
#define FF_ 4096
#define EPS_ 1e-5f
// Q pre-scale = log2(e)/sqrt(dk): attention exponentials become native exp2
#define SCALE_ 0.18033688011112f

__device__ __forceinline__ float bf2f(hbf v) { return __bfloat162float(v); }
__device__ __forceinline__ float fexp2(float x) {
  return __builtin_amdgcn_exp2f(x);  // v_exp_f32 (2^x native)
}
__device__ __forceinline__ float flog2(float x) {
  return __builtin_amdgcn_logf(x);  // v_log_f32 (log2 native)
}
__device__ __forceinline__ float ldin(const void* p, size_t i, int isbf) {
  return isbf ? __bfloat162float(((const hbf*)p)[i]) : ((const float*)p)[i];
}
__device__ __forceinline__ void ston(void* p, size_t i, float v, int isbf) {
  if (isbf) ((hbf*)p)[i] = __float2bfloat16(v);
  else ((float*)p)[i] = v;
}
__device__ __forceinline__ f32x4 mfma16(bf16x8 a, bf16x8 b, f32x4 c) {
  return __builtin_amdgcn_mfma_f32_16x16x32_bf16(a, b, c, 0, 0, 0);
}
__device__ __forceinline__ bf16x8 ldfrag(const hbf* p) {
  return *(const bf16x8*)p;
}
// async global->LDS, 16B/lane; LDS base wave-uniform (HW: lane i -> base+i*16)
__device__ __forceinline__ void glds16(const hbf* g, hbf* l) {
  __builtin_amdgcn_global_load_lds(
      (const __attribute__((address_space(1))) void*)g,
      (__attribute__((address_space(3))) void*)l, 16, 0, 0);
}

// ---------------------------------------------------------------------------
// Runtime input-dtype detection (bf16 vs fp32), from bit patterns of x.
// ---------------------------------------------------------------------------
__global__ __launch_bounds__(256) void detect_dtype(const unsigned* x,
                                                    int* flag) {
  __shared__ int cnt[256];
  int c = 0;
  for (int i = threadIdx.x; i < 4096; i += 256) {
    unsigned low = x[i] & 0xFFFFu;
    unsigned e = (low >> 7) & 0xFFu;
    if (e >= 100u && e <= 142u) c++;
  }
  cnt[threadIdx.x] = c;
  __syncthreads();
  for (int off = 128; off > 0; off >>= 1) {
    if ((int)threadIdx.x < off) cnt[threadIdx.x] += cnt[threadIdx.x + off];
    __syncthreads();
  }
  if (threadIdx.x == 0) *flag = (cnt[0] > 2458) ? 1 : 0;
}

// ---------------------------------------------------------------------------
// Mega-preconversion: one launch does all weight transposes + x/bias converts.
// Flat block-id job table:
//  [0,3072)      Wq/Wk/Wv -> wqkvt (head-sliced transpose, R=1024,C=64,z=16)
//  [3072,4096)   Wo -> wot          (1024x1024)
//  [4096,8192)   W1 -> w1t          (1024x4096)
//  [8192,12288)  W2 -> w2t          (4096x1024)
//  [12288,13312) x -> xb            (4M elements, 4096/block, vectorized)
//  13312: b1 -> b1b ; 13313: b2 -> b2b
// ---------------------------------------------------------------------------
__device__ __forceinline__ void tr_tile(const void* __restrict__ src,
                                        hbf* __restrict__ dst, int R, int C,
                                        size_t zoff, int cx, int ry, int f,
                                        float (*tile)[33]) {
  const int tx = threadIdx.x & 31, ty = threadIdx.x >> 5;
  const int c0 = cx * 32, r0 = ry * 32;
#pragma unroll
  for (int p = 0; p < 4; p++) {
    int rr = p * 8 + ty;
    tile[rr][tx] = ldin(src, zoff + (size_t)(r0 + rr) * C + c0 + tx, f);
  }
  __syncthreads();
#pragma unroll
  for (int p = 0; p < 4; p++) {
    int cc = p * 8 + ty;
    dst[zoff + (size_t)(c0 + cc) * R + r0 + tx] = __float2bfloat16(tile[tx][cc]);
  }
}

__global__ __launch_bounds__(256) void preconv(
    const void* __restrict__ x, const void* __restrict__ Wq,
    const void* __restrict__ Wk, const void* __restrict__ Wv,
    const void* __restrict__ Wo, const void* __restrict__ W1,
    const void* __restrict__ W2, const void* __restrict__ b1,
    const void* __restrict__ b2, hbf* __restrict__ xb,
    hbf* __restrict__ wqkvt, hbf* __restrict__ wot, hbf* __restrict__ w1t,
    hbf* __restrict__ w2t, hbf* __restrict__ b1b, hbf* __restrict__ b2b,
    const int* __restrict__ flag) {
  __shared__ float tile[32][33];
  const int f = *flag;
  const int bid = blockIdx.x;
  if (bid < 3072) {
    int which = bid >> 10;  // 0=Wq 1=Wk 2=Wv
    int r = bid & 1023;
    int z = r >> 6, rem = r & 63;
    int ry = rem >> 1, cx = rem & 1;
    const void* src = (which == 0) ? Wq : (which == 1) ? Wk : Wv;
    hbf* dst = wqkvt + (size_t)which * (D_ * D_);
    tr_tile(src, dst, 1024, 64, (size_t)z * 65536, cx, ry, f, tile);
  } else if (bid < 4096) {
    int t = bid - 3072;
    tr_tile(Wo, wot, 1024, 1024, 0, t & 31, t >> 5, f, tile);
  } else if (bid < 8192) {
    int t = bid - 4096;
    tr_tile(W1, w1t, 1024, 4096, 0, t & 127, t >> 7, f, tile);
  } else if (bid < 12288) {
    int t = bid - 8192;
    tr_tile(W2, w2t, 4096, 1024, 0, t & 31, t >> 5, f, tile);
  } else if (bid < 13312) {
    size_t base = (size_t)(bid - 12288) * 4096;
    if (f) {
      // bf16 input: straight 16B copies
      const uint4* src = (const uint4*)((const hbf*)x + base);
      uint4* dst = (uint4*)(xb + base);
      for (int i = threadIdx.x; i < 512; i += 256) dst[i] = src[i];
    } else {
      // fp32 input: float4 x2 -> 8 bf16 packed (uint2x2)
      const float4* src = (const float4*)((const float*)x + base);
      for (int i = threadIdx.x; i < 512; i += 256) {
        float4 a = src[i * 2], b = src[i * 2 + 1];
        union {
          hbf h[8];
          uint4 u;
        } o;
        o.h[0] = __float2bfloat16(a.x);
        o.h[1] = __float2bfloat16(a.y);
        o.h[2] = __float2bfloat16(a.z);
        o.h[3] = __float2bfloat16(a.w);
        o.h[4] = __float2bfloat16(b.x);
        o.h[5] = __float2bfloat16(b.y);
        o.h[6] = __float2bfloat16(b.z);
        o.h[7] = __float2bfloat16(b.w);
        *(uint4*)(xb + base + (size_t)i * 8) = o.u;
      }
    }
  } else if (bid == 13312) {
    for (int i = threadIdx.x; i < FF_; i += 256)
      b1b[i] = __float2bfloat16(ldin(b1, i, f));
  } else {
    for (int i = threadIdx.x; i < D_; i += 256)
      b2b[i] = __float2bfloat16(ldin(b2, i, f));
  }
}

// ---------------------------------------------------------------------------
// MFMA GEMM (m97 structure): C(MxN) = A(MxK) @ Bt(NxK)^T, bf16, fp32 accum.
// BMxBN tile, BK=64, glds width-16 staging, 4 waves 2x2.
// TR: grid transpose -- blockIdx.x walks M-tiles (gridDim.x % 8 == 0 so
// XCD = bx%8 pins A-PANELS per XCD instead of B). Rule: pin the operand
// with the larger stream (verified R11: FFN2 FETCH 135->49MB).
// Used for out-proj and FFN2-splitK (grids too small for the 256 tile).
// MODE 1: C = acc + e1[m*N+n]; fused LN stats -> atomicAdd red[batch]
// MODE 4: Cf_z[m*N+n] = acc  (fp32 split-K partial, z = blockIdx.z)
// ---------------------------------------------------------------------------
template <int MODE, int BM, int BN, int BK, int TR>
__global__ __launch_bounds__(256) void gemm_bt(
    const hbf* __restrict__ A, const hbf* __restrict__ Bt, hbf* __restrict__ C,
    float* __restrict__ Cf0, float* __restrict__ Cf1,
    const hbf* __restrict__ e1, float* __restrict__ red, int M, int N, int K,
    int LDK) {
  constexpr int WM = BM / 2, WN = BN / 2;
  constexpr int IF = WM / 16, JF = WN / 16;
  constexpr int HK = BK / 32;     // 32-wide k-chunks per K-step
  constexpr int LPT = BK / 8;     // lanes covering one row (8 hbf/lane)
  constexpr int CPR = 2048 / BK;  // rows staged per glds chunk (4KB)
  __shared__ alignas(16) hbf As[BM * BK];
  __shared__ alignas(16) hbf Bs[BN * BK];
  const int tid = threadIdx.x;
  const int wave = tid >> 6, lane = tid & 63;
  const int quad = lane >> 4, l16 = lane & 15;
  const int m0 = (TR ? blockIdx.x : blockIdx.y) * BM;
  const int n0 = (TR ? blockIdx.y : blockIdx.x) * BN;
  const int mw = (wave >> 1) * WM, nw = (wave & 1) * WN;
  const int srow = tid / LPT;
  const int scol = (tid % LPT) * 8;
  const int kbase = (MODE == 4) ? blockIdx.z * K : 0;
  const f32x4 zero = {0.f, 0.f, 0.f, 0.f};
  f32x4 acc[IF][JF];
#pragma unroll
  for (int i = 0; i < IF; i++)
#pragma unroll
    for (int j = 0; j < JF; j++) acc[i][j] = zero;

  const hbf* ga = &A[(size_t)(m0 + srow) * LDK + kbase + scol];
  const hbf* gb = &Bt[(size_t)(n0 + srow) * LDK + kbase + scol];
  hbf* lA = &As[wave * 512];
  hbf* lB = &Bs[wave * 512];

  for (int k0 = 0; k0 < K; k0 += BK) {
#pragma unroll
    for (int c = 0; c < BM / CPR; c++)
      glds16(ga + (size_t)(c * CPR) * LDK + k0, lA + c * 2048);
#pragma unroll
    for (int c = 0; c < BN / CPR; c++)
      glds16(gb + (size_t)(c * CPR) * LDK + k0, lB + c * 2048);
    __syncthreads();
    bf16x8 af[HK][IF], bfr[HK][JF];
#pragma unroll
    for (int h = 0; h < HK; h++) {
#pragma unroll
      for (int i = 0; i < IF; i++)
        af[h][i] = ldfrag(&As[(mw + i * 16 + l16) * BK + h * 32 + quad * 8]);
#pragma unroll
      for (int j = 0; j < JF; j++)
        bfr[h][j] = ldfrag(&Bs[(nw + j * 16 + l16) * BK + h * 32 + quad * 8]);
    }
#pragma unroll
    for (int h = 0; h < HK; h++)
#pragma unroll
      for (int i = 0; i < IF; i++)
#pragma unroll
        for (int j = 0; j < JF; j++)
          acc[i][j] = mfma16(af[h][i], bfr[h][j], acc[i][j]);
    __syncthreads();
  }
  float ssum = 0.f, ssq = 0.f;
#pragma unroll
  for (int i = 0; i < IF; i++)
#pragma unroll
    for (int j = 0; j < JF; j++)
#pragma unroll
      for (int r = 0; r < 4; r++) {
        int m = m0 + mw + i * 16 + quad * 4 + r;
        int n = n0 + nw + j * 16 + l16;
        float v = acc[i][j][r];
        if (MODE == 1) {
          hbf hv = __float2bfloat16(v + bf2f(e1[(size_t)m * N + n]));
          C[(size_t)m * N + n] = hv;
          float fv = bf2f(hv);
          ssum += fv;
          ssq += fv * fv;
        } else if (MODE == 4) {
          float* Cf = blockIdx.z ? Cf1 : Cf0;
          Cf[(size_t)m * N + n] = v;
        }
      }
  if (MODE == 1) {
    // fused LN stats: block tile lies within one batch (BM=128 | 2048)
    float* sc = (float*)As;  // dead LDS reuse (post final barrier)
    sc[tid] = ssum;
    sc[256 + tid] = ssq;
    __syncthreads();
    for (int off = 128; off > 0; off >>= 1) {
      if (tid < off) {
        sc[tid] += sc[tid + off];
        sc[256 + tid] += sc[256 + tid + off];
      }
      __syncthreads();
    }
    if (tid == 0) {
      int b = m0 >> 11;
      atomicAdd(&red[b * 2 + 0], sc[0]);
      atomicAdd(&red[b * 2 + 1], sc[256]);
    }
  }
}

// ---------------------------------------------------------------------------
// 256x256-tile double-buffered GEMM (8 waves 2x4, 64 MFMA per wave per
// K-tile against ONE barrier; prefetch of t+1 issued before compute of t;
// 128KB LDS, 1 block/CU). Verified R10/R13: FFN1 and QKV both left top-5
// vs the 128 2-barrier tile. Templated:
//  MODE 2: C = relu(acc + bias[n])                       (FFN1; grid 16x16)
//  MODE 0: QKV scatter to (which,B,H,T,64), Q pre-scaled (grid 12x16)
// ---------------------------------------------------------------------------
template <int MODE>
__global__ __launch_bounds__(512) void gemm256(
    const hbf* __restrict__ A, const hbf* __restrict__ Bt, hbf* __restrict__ C,
    const hbf* __restrict__ bias, int N, int K, int LDK) {
  __shared__ alignas(16) hbf As[2][256 * 64];
  __shared__ alignas(16) hbf Bs[2][256 * 64];
  const int tid = threadIdx.x;
  const int wave = tid >> 6, lane = tid & 63;
  const int quad = lane >> 4, l16 = lane & 15;
  const int wr = wave >> 2, wc = wave & 3;  // 2x4 wave grid
  const int m0 = blockIdx.y * 256, n0 = blockIdx.x * 256;
  const int mw = wr * 128, nw = wc * 64;
  const int srow = tid >> 3;       // 0..63 (rows within a 64-row chunk)
  const int scol = (tid & 7) * 8;  // 0..56
  const hbf* ga = &A[(size_t)(m0 + srow) * LDK + scol];
  const hbf* gb = &Bt[(size_t)(n0 + srow) * LDK + scol];
  const int lbase = wave * 512;  // wave-uniform LDS base within a chunk
  const f32x4 zero = {0.f, 0.f, 0.f, 0.f};
  f32x4 acc[8][4];
#pragma unroll
  for (int i = 0; i < 8; i++)
#pragma unroll
    for (int j = 0; j < 4; j++) acc[i][j] = zero;

  const int NT = K / 64;
  // prologue: stage tile 0 into buffer 0
#pragma unroll
  for (int c = 0; c < 4; c++) {
    glds16(ga + (size_t)(c * 64) * LDK, &As[0][c * 4096 + lbase]);
    glds16(gb + (size_t)(c * 64) * LDK, &Bs[0][c * 4096 + lbase]);
  }
  __syncthreads();

  for (int t = 0; t < NT; t++) {
    const int cur = t & 1;
    if (t < NT - 1) {  // async prefetch t+1 into the other buffer;
                       // drains at the end-of-iteration barrier
      size_t ko = (size_t)(t + 1) * 64;
#pragma unroll
      for (int c = 0; c < 4; c++) {
        glds16(ga + (size_t)(c * 64) * LDK + ko,
               &As[cur ^ 1][c * 4096 + lbase]);
        glds16(gb + (size_t)(c * 64) * LDK + ko,
               &Bs[cur ^ 1][c * 4096 + lbase]);
      }
    }
    // compute tile t from buffer cur: 2 k-halves x (8 m x 4 n) MFMA
#pragma unroll
    for (int h = 0; h < 2; h++) {
      bf16x8 bfr[4];
#pragma unroll
      for (int j = 0; j < 4; j++)
        bfr[j] = ldfrag(&Bs[cur][(nw + j * 16 + l16) * 64 + h * 32 + quad * 8]);
#pragma unroll
      for (int i = 0; i < 8; i++) {
        bf16x8 af =
            ldfrag(&As[cur][(mw + i * 16 + l16) * 64 + h * 32 + quad * 8]);
#pragma unroll
        for (int j = 0; j < 4; j++)
          acc[i][j] = mfma16(af, bfr[j], acc[i][j]);
      }
    }
    __syncthreads();  // drains prefetch vmcnt + protects buffer reuse
  }
  // epilogue
#pragma unroll
  for (int i = 0; i < 8; i++)
#pragma unroll
    for (int j = 0; j < 4; j++)
#pragma unroll
      for (int r = 0; r < 4; r++) {
        int m = m0 + mw + i * 16 + quad * 4 + r;
        int n = n0 + nw + j * 16 + l16;
        float v = acc[i][j][r];
        if (MODE == 2) {
          C[(size_t)m * N + n] =
              __float2bfloat16(fmaxf(v + bf2f(bias[n]), 0.f));
        } else if (MODE == 0) {
          int which = n >> 10, n1 = n & 1023;
          int hd = n1 >> 6, cc = n1 & 63;
          int bb = m >> 11, tt = m & (T_ - 1);
          if (which == 0) v *= SCALE_;  // pre-scale Q by log2e/sqrt(dk)
          C[(size_t)which * ((size_t)B_ * H_ * T_ * 64) +
            (((size_t)(bb * H_ + hd)) * T_ + tt) * 64 + cc] =
              __float2bfloat16(v);
        }
      }
}

// ---------------------------------------------------------------------------
// Attention stats + V-transform (MFMA): S = Q K^T (Q pre-scaled by log2e/8,
// so all exponentials are base-2 -> native v_exp_f32).
//   adj[s] = max_q S[q,s] + log2(sum_q 2^(S[q,s]-max))
// Tail (fused, block owns its 64 s-rows): Vt'[v,s] = V[s,v]*2^(-adj[s]).
// Block: 64 s (4 waves x 16), loops 32 q-tiles of 64.
// R14: Q staging converted to double-buffered global_load_lds with
// prefetch-before-compute and ONE barrier/iter (was 2-barrier wave-issued
// float4 staging -- the stall pattern already fixed in FFN1/QKV). glds
// writes are linear, so the attn_apply-proven XOR-swizzle pair is used:
// inverse-swizzled global source + ^sx fragment reads. K staging (one-time,
// padded-72) and the fused V tail unchanged.
// ---------------------------------------------------------------------------
__global__ __launch_bounds__(256) void attn_stats(const hbf* __restrict__ Q,
                                                  const hbf* __restrict__ K,
                                                  const hbf* __restrict__ V,
                                                  hbf* __restrict__ Vt) {
  __shared__ alignas(16) hbf Ks[64 * 72];
  __shared__ alignas(16) hbf Qs[2][64 * 64];
  __shared__ float sAdj[64];
  const int bh = blockIdx.y;
  const int s0 = blockIdx.x * 64;
  const int tid = threadIdx.x;
  const int wave = tid >> 6, lane = tid & 63;
  const int quad = lane >> 4, l16 = lane & 15;
  const int sw = wave * 16;
  const hbf* Kb = K + (size_t)bh * T_ * 64;
  const hbf* Qb = Q + (size_t)bh * T_ * 64;
  const hbf* Vb = V + (size_t)bh * T_ * 64;
  hbf* Vtb = Vt + (size_t)bh * 64 * T_;
  const int r_ = tid >> 3, c_ = (tid & 7) * 8;
  // swizzled glds staging for Q: LDS slot (row=tid>>3, chunk=tid&7) holds
  // global chunk (tid&7)^(row&7); reads use ^sx (sx = (l16&7)*8 elems)
  const int swz = (tid & 7) ^ (r_ & 7);
  const hbf* gq = Qb + (size_t)r_ * 64 + swz * 8;
  hbf* lQ0 = &Qs[0][wave * 512];
  hbf* lQ1 = &Qs[1][wave * 512];
  const int sx = (l16 & 7) * 8;
  // one-time K staging (padded stride 72, conflict-lite)
#pragma unroll
  for (int c = 0; c < 2; c++) {
    int row = c * 32 + r_;
    *(float4*)(&Ks[row * 72 + c_]) =
        *(const float4*)(&Kb[(size_t)(s0 + row) * 64 + c_]);
  }
  // prologue: stage Q tile 0 into buf 0 (rows 0..31 and 32..63)
  glds16(gq, lQ0);
  glds16(gq + (size_t)32 * 64, lQ0 + 2048);
  __syncthreads();
  bf16x8 kf0 = ldfrag(&Ks[(sw + l16) * 72 + quad * 8]);
  bf16x8 kf1 = ldfrag(&Ks[(sw + l16) * 72 + 32 + quad * 8]);
  float m_thr[4], l_thr[4];
#pragma unroll
  for (int r = 0; r < 4; r++) {
    m_thr[r] = -1e30f;
    l_thr[r] = 0.f;
  }
  const f32x4 zero = {0.f, 0.f, 0.f, 0.f};
  for (int qt = 0; qt < T_ / 64; qt++) {
    const int cur = qt & 1;
    if (qt < T_ / 64 - 1) {  // async prefetch next Q tile (drains at barrier)
      size_t qo = (size_t)(qt + 1) * 4096;
      hbf* lQn = cur ? lQ0 : lQ1;
      glds16(gq + qo, lQn);
      glds16(gq + qo + (size_t)32 * 64, lQn + 2048);
    }
    const hbf* Qc = &Qs[cur][0];
    f32x4 acc[4];
#pragma unroll
    for (int j = 0; j < 4; j++) {
      bf16x8 qf0 = ldfrag(&Qc[(j * 16 + l16) * 64 + ((quad * 8) ^ sx)]);
      bf16x8 qf1 = ldfrag(&Qc[(j * 16 + l16) * 64 + ((32 + quad * 8) ^ sx)]);
      f32x4 a = zero;
      a = mfma16(kf0, qf0, a);
      a = mfma16(kf1, qf1, a);
      acc[j] = a;
    }
#pragma unroll
    for (int r = 0; r < 4; r++) {
      float mt = fmaxf(fmaxf(acc[0][r], acc[1][r]),
                       fmaxf(acc[2][r], acc[3][r]));
      float nm = fmaxf(m_thr[r], mt);
      float s = l_thr[r] * fexp2(m_thr[r] - nm);
#pragma unroll
      for (int j = 0; j < 4; j++) s += fexp2(acc[j][r] - nm);
      l_thr[r] = s;
      m_thr[r] = nm;
    }
    __syncthreads();  // prefetch complete + buffer reuse safe
  }
#pragma unroll
  for (int d = 1; d < 16; d <<= 1) {
#pragma unroll
    for (int r = 0; r < 4; r++) {
      float om = __shfl_xor(m_thr[r], d);
      float ol = __shfl_xor(l_thr[r], d);
      float nm = fmaxf(m_thr[r], om);
      l_thr[r] = l_thr[r] * fexp2(m_thr[r] - nm) + ol * fexp2(om - nm);
      m_thr[r] = nm;
    }
  }
  if (l16 == 0) {
#pragma unroll
    for (int r = 0; r < 4; r++)
      sAdj[sw + quad * 4 + r] = m_thr[r] + flog2(l_thr[r]);
  }
  __syncthreads();
  // fused V scale+transpose for this block's s-range (reuse Ks as tile)
#pragma unroll
  for (int c = 0; c < 2; c++) {
    int e = (c * 256 + tid) * 8;
    int r = e >> 6, col = e & 63;
    union alignas(16) {
      hbf h[8];
      float4 f4;
    } u;
    u.f4 = *(const float4*)(&Vb[(size_t)(s0 + r) * 64 + col]);
    float sc = fexp2(-sAdj[r]);
#pragma unroll
    for (int k2 = 0; k2 < 8; k2++)
      u.h[k2] = __float2bfloat16(bf2f(u.h[k2]) * sc);
    *(float4*)(&Ks[r * 72 + col]) = u.f4;
  }
  __syncthreads();
#pragma unroll
  for (int c = 0; c < 2; c++) {
    int e = (c * 256 + tid) * 8;
    int v = e >> 6, tt = e & 63;
    union alignas(16) {
      hbf h[8];
      float4 f4;
    } u;
#pragma unroll
    for (int k2 = 0; k2 < 8; k2++) u.h[k2] = Ks[(tt + k2) * 72 + v];
    *(float4*)(&Vtb[(size_t)v * T_ + s0 + tt]) = u.f4;
  }
}

// ---------------------------------------------------------------------------
// Attention apply (MFMA): O[q,v] = sum_s 2^(S[q,s]) * V'[s,v]
// (normalizer folded into V'). Cross-iteration pipeline: iteration st
// computes QK^T(st) AND PV(st-1) so PV's MFMAs overlap QK's load/exp chain.
//  * K double-buffered (16KB), V triple-buffered (24KB), P per-wave
//    double-buffered (37KB). 77KB total -> 2 blocks/CU (grid cap).
//  * staging via global_load_lds + XOR swizzle, one barrier per iteration,
//    s_setprio(1) around MFMA clusters.
// Block: 128 q (4 waves x 32), s-tiles of 64, grid (16,32).
// ---------------------------------------------------------------------------
__global__ __launch_bounds__(256) void attn_apply(const hbf* __restrict__ Q,
                                                  const hbf* __restrict__ K,
                                                  const hbf* __restrict__ Vt,
                                                  hbf* __restrict__ heads) {
  __shared__ alignas(16) hbf Ksb[2 * 64 * 64];
  __shared__ alignas(16) hbf Vsb[3 * 64 * 64];
  __shared__ alignas(16) hbf Ps[4 * 2 * 32 * 72];
  const int bh = blockIdx.y;
  const int b = bh >> 4, h = bh & 15;
  const int q0 = blockIdx.x * 128;
  const int tid = threadIdx.x;
  const int wave = tid >> 6, lane = tid & 63;
  const int quad = lane >> 4, l16 = lane & 15;
  const int qw = wave * 32;
  const hbf* Qb = Q + (size_t)bh * T_ * 64;
  const hbf* Kb = K + (size_t)bh * T_ * 64;
  const hbf* Vtb = Vt + (size_t)bh * 64 * T_;
  hbf* Pw = &Ps[wave * (2 * 32 * 72)];
  // staging: lane -> LDS slot (row=tid>>3, chunk=tid&7); source chunk is
  // inverse-swizzled so LDS slot (r,c) holds global chunk c^(r&7).
  const int srow = tid >> 3, sc8 = tid & 7;
  const int swz = sc8 ^ (srow & 7);
  const hbf* gk = Kb + (size_t)srow * 64 + swz * 8;
  const hbf* gv = Vtb + (size_t)srow * T_ + swz * 8;
  hbf* lK = &Ksb[wave * 512];
  hbf* lV = &Vsb[wave * 512];
  const int sx = (l16 & 7) * 8;  // read-side elem swizzle for this lane's rows
  // Q fragments (B-operand): lane supplies Q[col=q(l16)][k=quad*8 in hh*32]
  bf16x8 qf[2][2];
#pragma unroll
  for (int i = 0; i < 2; i++)
#pragma unroll
    for (int hh = 0; hh < 2; hh++)
      qf[i][hh] = ldfrag(&Qb[(size_t)(q0 + qw + i * 16 + l16) * 64 + hh * 32 +
                             quad * 8]);
  const f32x4 zero = {0.f, 0.f, 0.f, 0.f};
  f32x4 accO[2][4];
#pragma unroll
  for (int i = 0; i < 2; i++)
#pragma unroll
    for (int j = 0; j < 4; j++) accO[i][j] = zero;

  // prologue: stage tiles 0 and 1 (K slots 0/1, V slots 0/1)
  glds16(gk, lK);
  glds16(gk + 2048, lK + 2048);
  glds16(gv, lV);
  glds16(gv + (size_t)32 * T_, lV + 2048);
  glds16(gk + 4096, lK + 4096);
  glds16(gk + 4096 + 2048, lK + 4096 + 2048);
  glds16(gv + 64, lV + 4096);
  glds16(gv + (size_t)32 * T_ + 64, lV + 4096 + 2048);
  __syncthreads();

  // prologue compute: QK^T(0) -> P[0] (no PV yet)
  {
    const hbf* Kc = &Ksb[0];
    bf16x8 kf[4][2];
#pragma unroll
    for (int j = 0; j < 4; j++)
#pragma unroll
      for (int hh = 0; hh < 2; hh++)
        kf[j][hh] =
            ldfrag(&Kc[(j * 16 + l16) * 64 + ((hh * 32 + quad * 8) ^ sx)]);
    __builtin_amdgcn_s_setprio(1);
    f32x4 accS[2][4];
#pragma unroll
    for (int i = 0; i < 2; i++)
#pragma unroll
      for (int j = 0; j < 4; j++) {
        f32x4 a = mfma16(kf[j][0], qf[i][0], zero);
        accS[i][j] = mfma16(kf[j][1], qf[i][1], a);
      }
    __builtin_amdgcn_s_setprio(0);
#pragma unroll
    for (int i = 0; i < 2; i++)
#pragma unroll
      for (int j = 0; j < 4; j++) {
        union {
          hbf h4[4];
          uint2 u;
        } pk;
#pragma unroll
        for (int r = 0; r < 4; r++)
          pk.h4[r] = __float2bfloat16(fexp2(accS[i][j][r]));
        *(uint2*)&Pw[(i * 16 + l16) * 72 + j * 16 + quad * 4] = pk.u;
      }
  }
  __syncthreads();  // protect K slot 0 from the st=1 prefetch (tile 2)

  for (int st = 1; st < T_ / 64; st++) {
    const int kcur = st & 1;
    const int pcur = st & 1, pprev = pcur ^ 1;
    const int vprev = (st - 1) % 3;
    if (st < T_ / 64 - 1) {  // async prefetch tile st+1 (drains at barrier)
      const int knxt = (st + 1) & 1, vnxt = (st + 1) % 3;
      size_t ko = (size_t)(st + 1) * 4096;
      glds16(gk + ko, lK + knxt * 4096);
      glds16(gk + ko + 2048, lK + knxt * 4096 + 2048);
      glds16(gv + (st + 1) * 64, lV + vnxt * 4096);
      glds16(gv + (size_t)32 * T_ + (st + 1) * 64, lV + vnxt * 4096 + 2048);
    }
    const hbf* Kc = &Ksb[kcur * 4096];
    const hbf* Vp = &Vsb[vprev * 4096];
    // issue kf loads for QK(st) early (in-order lgkm: complete before pf use)
    bf16x8 kf[4][2];
#pragma unroll
    for (int j = 0; j < 4; j++)
#pragma unroll
      for (int hh = 0; hh < 2; hh++)
        kf[j][hh] =
            ldfrag(&Kc[(j * 16 + l16) * 64 + ((hh * 32 + quad * 8) ^ sx)]);
    // PV(st-1): A = P[prev] rows q, B = V'[prev] rows v
    bf16x8 pf[2][2];
#pragma unroll
    for (int i = 0; i < 2; i++)
#pragma unroll
      for (int hh = 0; hh < 2; hh++)
        pf[i][hh] = ldfrag(
            &Pw[pprev * (32 * 72) + (i * 16 + l16) * 72 + hh * 32 + quad * 8]);
    __builtin_amdgcn_s_setprio(1);
#pragma unroll
    for (int j2 = 0; j2 < 4; j2++) {
      bf16x8 vf0 = ldfrag(&Vp[(j2 * 16 + l16) * 64 + ((quad * 8) ^ sx)]);
      bf16x8 vf1 = ldfrag(&Vp[(j2 * 16 + l16) * 64 + ((32 + quad * 8) ^ sx)]);
#pragma unroll
      for (int i = 0; i < 2; i++) {
        accO[i][j2] = mfma16(pf[i][0], vf0, accO[i][j2]);
        accO[i][j2] = mfma16(pf[i][1], vf1, accO[i][j2]);
      }
    }
    // QK^T(st) swapped: accS[i][j] = D[s][q]
    f32x4 accS[2][4];
#pragma unroll
    for (int i = 0; i < 2; i++)
#pragma unroll
      for (int j = 0; j < 4; j++) {
        f32x4 a = mfma16(kf[j][0], qf[i][0], zero);
        accS[i][j] = mfma16(kf[j][1], qf[i][1], a);
      }
    __builtin_amdgcn_s_setprio(0);
    // exp2 -> bf16 pack -> P[cur] (8 b64 writes, s-consecutive)
#pragma unroll
    for (int i = 0; i < 2; i++)
#pragma unroll
      for (int j = 0; j < 4; j++) {
        union {
          hbf h4[4];
          uint2 u;
        } pk;
#pragma unroll
        for (int r = 0; r < 4; r++)
          pk.h4[r] = __float2bfloat16(fexp2(accS[i][j][r]));
        *(uint2*)&Pw[pcur * (32 * 72) + (i * 16 + l16) * 72 + j * 16 +
                     quad * 4] = pk.u;
      }
    __syncthreads();
  }
  // epilogue: PV(last tile): P[(T/64-1)&1], V[(T/64-1)%3]
  {
    const int pl = (T_ / 64 - 1) & 1;
    const hbf* Vp = &Vsb[((T_ / 64 - 1) % 3) * 4096];
    bf16x8 pf[2][2];
#pragma unroll
    for (int i = 0; i < 2; i++)
#pragma unroll
      for (int hh = 0; hh < 2; hh++)
        pf[i][hh] = ldfrag(
            &Pw[pl * (32 * 72) + (i * 16 + l16) * 72 + hh * 32 + quad * 8]);
    __builtin_amdgcn_s_setprio(1);
#pragma unroll
    for (int j2 = 0; j2 < 4; j2++) {
      bf16x8 vf0 = ldfrag(&Vp[(j2 * 16 + l16) * 64 + ((quad * 8) ^ sx)]);
      bf16x8 vf1 = ldfrag(&Vp[(j2 * 16 + l16) * 64 + ((32 + quad * 8) ^ sx)]);
#pragma unroll
      for (int i = 0; i < 2; i++) {
        accO[i][j2] = mfma16(pf[i][0], vf0, accO[i][j2]);
        accO[i][j2] = mfma16(pf[i][1], vf1, accO[i][j2]);
      }
    }
    __builtin_amdgcn_s_setprio(0);
  }
#pragma unroll
  for (int i = 0; i < 2; i++)
#pragma unroll
    for (int j2 = 0; j2 < 4; j2++)
#pragma unroll
      for (int r = 0; r < 4; r++) {
        int q = q0 + qw + i * 16 + quad * 4 + r;
        int v = j2 * 16 + l16;
        heads[((size_t)(b * T_ + q)) * D_ + h * 64 + v] =
            __float2bfloat16(accO[i][j2][r]);
      }
}

// ---------------------------------------------------------------------------
// LN1 normalize (stats came fused from the out-proj GEMM). Vectorized
// 4x bf16 in/out (G13).
// ---------------------------------------------------------------------------
__global__ __launch_bounds__(256) void ln_norm(const hbf* __restrict__ src,
                                               const float* __restrict__ red,
                                               void* dst,
                                               const int* __restrict__ flag,
                                               int force_bf) {
  const int isbf = force_bf ? 1 : *flag;
  const float invN = 1.f / (float)(T_ * D_);
  const uint2* sv = (const uint2*)src;
  for (size_t i = (size_t)blockIdx.x * 256 + threadIdx.x;
       i < (size_t)B_ * T_ * D_ / 4; i += (size_t)gridDim.x * 256) {
    int b = (int)(i >> 19);  // per-batch 4-elem count = T*D/4 = 2^19
    float mu = red[b * 2 + 0] * invN;
    float var = red[b * 2 + 1] * invN - mu * mu;
    float rstd = rsqrtf(var + EPS_);
    union {
      uint2 u;
      hbf h[4];
    } s;
    s.u = sv[i];
    float out[4];
#pragma unroll
    for (int r = 0; r < 4; r++) out[r] = (bf2f(s.h[r]) - mu) * rstd;
    if (isbf) {
      union {
        hbf h[4];
        uint2 u;
      } pk;
#pragma unroll
      for (int r = 0; r < 4; r++) pk.h[r] = __float2bfloat16(out[r]);
      ((uint2*)dst)[i] = pk.u;
    } else {
      float4 f{out[0], out[1], out[2], out[3]};
      ((float4*)dst)[i] = f;
    }
  }
}

// ---------------------------------------------------------------------------
// LN2 stats over r2 = P0+P1+b2+o1 (r2 never materialized). Vectorized:
// float4 partial loads + uint2 (4x bf16) o1/b2 loads (G13).
// ---------------------------------------------------------------------------
__global__ __launch_bounds__(256) void ln2_stats(const float* __restrict__ P0,
                                                 const float* __restrict__ P1,
                                                 const hbf* __restrict__ o1,
                                                 const hbf* __restrict__ b2b,
                                                 float* __restrict__ red) {
  __shared__ float s1[256], s2[256];
  const int b = blockIdx.y;
  const size_t base = (size_t)b * (T_ * D_ / 4);
  const float4* P0v = (const float4*)P0;
  const float4* P1v = (const float4*)P1;
  const uint2* o1v = (const uint2*)o1;
  const uint2* b2v = (const uint2*)b2b;
  float sum = 0.f, sq = 0.f;
  for (size_t i = (size_t)blockIdx.x * 256 + threadIdx.x;
       i < (size_t)(T_ * D_ / 4); i += (size_t)gridDim.x * 256) {
    float4 p0 = P0v[base + i], p1 = P1v[base + i];
    union {
      uint2 u;
      hbf h[4];
    } o, bb;
    o.u = o1v[base + i];
    bb.u = b2v[i & (D_ / 4 - 1)];
#pragma unroll
    for (int r = 0; r < 4; r++) {
      float v = (&p0.x)[r] + (&p1.x)[r] + bf2f(bb.h[r]) + bf2f(o.h[r]);
      sum += v;
      sq += v * v;
    }
  }
  s1[threadIdx.x] = sum;
  s2[threadIdx.x] = sq;
  __syncthreads();
  for (int off = 128; off > 0; off >>= 1) {
    if ((int)threadIdx.x < off) {
      s1[threadIdx.x] += s1[threadIdx.x + off];
      s2[threadIdx.x] += s2[threadIdx.x + off];
    }
    __syncthreads();
  }
  if (threadIdx.x == 0) {
    atomicAdd(&red[b * 2 + 0], s1[0]);
    atomicAdd(&red[b * 2 + 1], s2[0]);
  }
}

__global__ __launch_bounds__(256) void ln2_norm(
    const float* __restrict__ P0, const float* __restrict__ P1,
    const hbf* __restrict__ o1, const hbf* __restrict__ b2b,
    const float* __restrict__ red, void* dst, const int* __restrict__ flag) {
  const int isbf = *flag;
  const float invN = 1.f / (float)(T_ * D_);
  const float4* P0v = (const float4*)P0;
  const float4* P1v = (const float4*)P1;
  const uint2* o1v = (const uint2*)o1;
  const uint2* b2v = (const uint2*)b2b;
  for (size_t i = (size_t)blockIdx.x * 256 + threadIdx.x;
       i < (size_t)B_ * T_ * D_ / 4; i += (size_t)gridDim.x * 256) {
    int b = (int)(i >> 19);  // per-batch float4 count = T*D/4 = 2^19
    float mu = red[b * 2 + 0] * invN;
    float var = red[b * 2 + 1] * invN - mu * mu;
    float rstd = rsqrtf(var + EPS_);
    float4 p0 = P0v[i], p1 = P1v[i];
    union {
      uint2 u;
      hbf h[4];
    } o, bb;
    o.u = o1v[i];
    bb.u = b2v[i & (D_ / 4 - 1)];
    float out[4];
#pragma unroll
    for (int r = 0; r < 4; r++)
      out[r] =
          ((&p0.x)[r] + (&p1.x)[r] + bf2f(bb.h[r]) + bf2f(o.h[r]) - mu) * rstd;
    if (isbf) {
      union {
        hbf h[4];
        uint2 u;
      } pk;
#pragma unroll
      for (int r = 0; r < 4; r++) pk.h[r] = __float2bfloat16(out[r]);
      ((uint2*)dst)[i] = pk.u;
    } else {
      float4 f{out[0], out[1], out[2], out[3]};
      ((float4*)dst)[i] = f;
    }
  }
}

// ---------------------------------------------------------------------------
// Workspace (MiB offsets), ~88.1 MB total:
//  [0,8) xb | [8,14) Wqkvt | [14,16) Wot | [16,24) W1t | [24,32) W2t
//  [32,40) Q | [40,48) K | [48,56) V | [56,64) Vt | [64,72) heads
//  [72,80) r1 | [80,88) o1 | ff1 aliases [32,64)
//  split-K partials (fp32, 16 MB each): P0 over [0,16), P1 over [64,80)
//  [88,..) b1b 8K | b2b 2K | red 32B | flag 4B
// ---------------------------------------------------------------------------
extern "C" void kernel_launch(void* const* d_in, const int* in_sizes, int n_in,
                              void* d_out, int out_size, void* d_ws,
                              size_t ws_size, hipStream_t stream) {
  const void* x = d_in[0];
  const void* Wq = d_in[1];
  const void* Wk = d_in[2];
  const void* Wv = d_in[3];
  const void* Wo = d_in[4];
  const void* W1 = d_in[5];
  const void* W2 = d_in[7];
  const void* b1 = d_in[6];
  const void* b2 = d_in[8];

  const size_t MB = 1024 * 1024;
  if (ws_size < 89 * MB) return;

  char* w = (char*)d_ws;
  hbf* xb = (hbf*)(w + 0 * MB);
  hbf* wqkvt = (hbf*)(w + 8 * MB);
  hbf* wot = (hbf*)(w + 14 * MB);
  hbf* w1t = (hbf*)(w + 16 * MB);
  hbf* w2t = (hbf*)(w + 24 * MB);
  hbf* Qb = (hbf*)(w + 32 * MB);
  hbf* Kb = (hbf*)(w + 40 * MB);
  hbf* Vb = (hbf*)(w + 48 * MB);
  hbf* Vtb = (hbf*)(w + 56 * MB);
  hbf* heads = (hbf*)(w + 64 * MB);
  hbf* r1 = (hbf*)(w + 72 * MB);
  hbf* o1 = (hbf*)(w + 80 * MB);
  hbf* ff1 = (hbf*)(w + 32 * MB);   // over dead Q/K/V/Vt
  float* P0 = (float*)(w + 0 * MB);   // over dead xb/wqkvt/wot (16 MB)
  float* P1 = (float*)(w + 64 * MB);  // over dead heads/r1 (16 MB)
  hbf* b1b = (hbf*)(w + 88 * MB);
  hbf* b2b = b1b + FF_;
  float* red = (float*)(b2b + D_);
  int* flag = (int*)(red + 8);

  hipMemsetAsync(red, 0, 8 * sizeof(float) + sizeof(int), stream);
  detect_dtype<<<1, 256, 0, stream>>>((const unsigned*)x, flag);

  const int M = B_ * T_;  // 4096
  // --- one-launch preconversion ---
  preconv<<<13314, 256, 0, stream>>>(x, Wq, Wk, Wv, Wo, W1, W2, b1, b2, xb,
                                     wqkvt, wot, w1t, w2t, b1b, b2b, flag);
  // --- QKV fused projection: 256x256 double-buffered kernel (192 blocks) ---
  gemm256<0><<<dim3(3 * D_ / 256, M / 256), 512, 0, stream>>>(
      xb, wqkvt, Qb, nullptr, 3 * D_, D_, D_);
  // --- attention: col-softmax stats + fused V scale/transpose, then apply ---
  attn_stats<<<dim3(32, 32), 256, 0, stream>>>(Qb, Kb, Vb, Vtb);
  attn_apply<<<dim3(16, 32), 256, 0, stream>>>(Qb, Kb, Vtb, heads);
  // --- out-proj + residual + fused LN1 stats; TR grid (32 m-tiles first) ---
  gemm_bt<1, 128, 64, 64, 1><<<dim3(32, 16), 256, 0, stream>>>(
      heads, wot, r1, nullptr, nullptr, xb, red, M, D_, D_, D_);
  ln_norm<<<2048, 256, 0, stream>>>(r1, red, o1, flag, 1);
  // --- FFN1: 256x256 double-buffered single-barrier kernel (grid = 1/CU) ---
  gemm256<2><<<dim3(FF_ / 256, M / 256), 512, 0, stream>>>(
      o1, w1t, ff1, b1b, FF_, D_, D_);
  // --- FFN2 split-K=2 -> fp32 partials; TR grid: A(ff1) panels pinned per
  //     XCD (A-stream was 135MB measured; B-stream <= 64MB) ---
  gemm_bt<4, 128, 128, 64, 1><<<dim3(32, 8, 2), 256, 0, stream>>>(
      ff1, w2t, nullptr, P0, P1, nullptr, nullptr, M, D_, FF_ / 2, FF_);
  // --- LN2 (r2 = P0+P1+b2+o1, never materialized; vectorized) ---
  ln2_stats<<<dim3(256, B_), 256, 0, stream>>>(P0, P1, o1, b2b, red + 4);
  ln2_norm<<<2048, 256, 0, stream>>>(P0, P1, o1, b2b, red + 4, d_out, flag);
}

// Round 15
// 428.519 us; speedup vs baseline: 1.1242x; 1.0026x over previous
//
#include <hip/hip_runtime.h>
#include <hip/hip_bf16.h>
#include <cstddef>
#include <cstdint>

typedef __hip_bfloat16 hbf;
typedef __attribute__((ext_vector_type(8))) __bf16 bf16x8;
typedef __attribute__((ext_vector_type(4))) float f32x4;

#define B_ 2
#define T_ 2048
#define D_ 1024
#define H_ 16
#define FF_ 4096
#define EPS_ 1e-5f
// Q pre-scale = log2(e)/sqrt(dk): attention exponentials become native exp2
#define SCALE_ 0.18033688011112f

__device__ __forceinline__ float bf2f(hbf v) { return __bfloat162float(v); }
__device__ __forceinline__ float fexp2(float x) {
  return __builtin_amdgcn_exp2f(x);  // v_exp_f32 (2^x native)
}
__device__ __forceinline__ float flog2(float x) {
  return __builtin_amdgcn_logf(x);  // v_log_f32 (log2 native)
}
__device__ __forceinline__ float ldin(const void* p, size_t i, int isbf) {
  return isbf ? __bfloat162float(((const hbf*)p)[i]) : ((const float*)p)[i];
}
__device__ __forceinline__ void ston(void* p, size_t i, float v, int isbf) {
  if (isbf) ((hbf*)p)[i] = __float2bfloat16(v);
  else ((float*)p)[i] = v;
}
__device__ __forceinline__ f32x4 mfma16(bf16x8 a, bf16x8 b, f32x4 c) {
  return __builtin_amdgcn_mfma_f32_16x16x32_bf16(a, b, c, 0, 0, 0);
}
__device__ __forceinline__ bf16x8 ldfrag(const hbf* p) {
  return *(const bf16x8*)p;
}
// async global->LDS, 16B/lane; LDS base wave-uniform (HW: lane i -> base+i*16)
__device__ __forceinline__ void glds16(const hbf* g, hbf* l) {
  __builtin_amdgcn_global_load_lds(
      (const __attribute__((address_space(1))) void*)g,
      (__attribute__((address_space(3))) void*)l, 16, 0, 0);
}

// ---------------------------------------------------------------------------
// Runtime input-dtype detection (bf16 vs fp32), from bit patterns of x.
// ---------------------------------------------------------------------------
__global__ __launch_bounds__(256) void detect_dtype(const unsigned* x,
                                                    int* flag) {
  __shared__ int cnt[256];
  int c = 0;
  for (int i = threadIdx.x; i < 4096; i += 256) {
    unsigned low = x[i] & 0xFFFFu;
    unsigned e = (low >> 7) & 0xFFu;
    if (e >= 100u && e <= 142u) c++;
  }
  cnt[threadIdx.x] = c;
  __syncthreads();
  for (int off = 128; off > 0; off >>= 1) {
    if ((int)threadIdx.x < off) cnt[threadIdx.x] += cnt[threadIdx.x + off];
    __syncthreads();
  }
  if (threadIdx.x == 0) *flag = (cnt[0] > 2458) ? 1 : 0;
}

// ---------------------------------------------------------------------------
// Mega-preconversion: one launch does all weight transposes + x/bias converts.
// Flat block-id job table:
//  [0,3072)      Wq/Wk/Wv -> wqkvt (head-sliced transpose, R=1024,C=64,z=16)
//  [3072,4096)   Wo -> wot          (1024x1024)
//  [4096,8192)   W1 -> w1t          (1024x4096)
//  [8192,12288)  W2 -> w2t          (4096x1024)
//  [12288,13312) x -> xb            (4M elements, 4096/block, vectorized)
//  13312: b1 -> b1b ; 13313: b2 -> b2b
// ---------------------------------------------------------------------------
__device__ __forceinline__ void tr_tile(const void* __restrict__ src,
                                        hbf* __restrict__ dst, int R, int C,
                                        size_t zoff, int cx, int ry, int f,
                                        float (*tile)[33]) {
  const int tx = threadIdx.x & 31, ty = threadIdx.x >> 5;
  const int c0 = cx * 32, r0 = ry * 32;
#pragma unroll
  for (int p = 0; p < 4; p++) {
    int rr = p * 8 + ty;
    tile[rr][tx] = ldin(src, zoff + (size_t)(r0 + rr) * C + c0 + tx, f);
  }
  __syncthreads();
#pragma unroll
  for (int p = 0; p < 4; p++) {
    int cc = p * 8 + ty;
    dst[zoff + (size_t)(c0 + cc) * R + r0 + tx] = __float2bfloat16(tile[tx][cc]);
  }
}

__global__ __launch_bounds__(256) void preconv(
    const void* __restrict__ x, const void* __restrict__ Wq,
    const void* __restrict__ Wk, const void* __restrict__ Wv,
    const void* __restrict__ Wo, const void* __restrict__ W1,
    const void* __restrict__ W2, const void* __restrict__ b1,
    const void* __restrict__ b2, hbf* __restrict__ xb,
    hbf* __restrict__ wqkvt, hbf* __restrict__ wot, hbf* __restrict__ w1t,
    hbf* __restrict__ w2t, hbf* __restrict__ b1b, hbf* __restrict__ b2b,
    const int* __restrict__ flag) {
  __shared__ float tile[32][33];
  const int f = *flag;
  const int bid = blockIdx.x;
  if (bid < 3072) {
    int which = bid >> 10;  // 0=Wq 1=Wk 2=Wv
    int r = bid & 1023;
    int z = r >> 6, rem = r & 63;
    int ry = rem >> 1, cx = rem & 1;
    const void* src = (which == 0) ? Wq : (which == 1) ? Wk : Wv;
    hbf* dst = wqkvt + (size_t)which * (D_ * D_);
    tr_tile(src, dst, 1024, 64, (size_t)z * 65536, cx, ry, f, tile);
  } else if (bid < 4096) {
    int t = bid - 3072;
    tr_tile(Wo, wot, 1024, 1024, 0, t & 31, t >> 5, f, tile);
  } else if (bid < 8192) {
    int t = bid - 4096;
    tr_tile(W1, w1t, 1024, 4096, 0, t & 127, t >> 7, f, tile);
  } else if (bid < 12288) {
    int t = bid - 8192;
    tr_tile(W2, w2t, 4096, 1024, 0, t & 31, t >> 5, f, tile);
  } else if (bid < 13312) {
    size_t base = (size_t)(bid - 12288) * 4096;
    if (f) {
      // bf16 input: straight 16B copies
      const uint4* src = (const uint4*)((const hbf*)x + base);
      uint4* dst = (uint4*)(xb + base);
      for (int i = threadIdx.x; i < 512; i += 256) dst[i] = src[i];
    } else {
      // fp32 input: float4 x2 -> 8 bf16 packed (uint2x2)
      const float4* src = (const float4*)((const float*)x + base);
      for (int i = threadIdx.x; i < 512; i += 256) {
        float4 a = src[i * 2], b = src[i * 2 + 1];
        union {
          hbf h[8];
          uint4 u;
        } o;
        o.h[0] = __float2bfloat16(a.x);
        o.h[1] = __float2bfloat16(a.y);
        o.h[2] = __float2bfloat16(a.z);
        o.h[3] = __float2bfloat16(a.w);
        o.h[4] = __float2bfloat16(b.x);
        o.h[5] = __float2bfloat16(b.y);
        o.h[6] = __float2bfloat16(b.z);
        o.h[7] = __float2bfloat16(b.w);
        *(uint4*)(xb + base + (size_t)i * 8) = o.u;
      }
    }
  } else if (bid == 13312) {
    for (int i = threadIdx.x; i < FF_; i += 256)
      b1b[i] = __float2bfloat16(ldin(b1, i, f));
  } else {
    for (int i = threadIdx.x; i < D_; i += 256)
      b2b[i] = __float2bfloat16(ldin(b2, i, f));
  }
}

// ---------------------------------------------------------------------------
// MFMA GEMM, double-buffered single-barrier schedule (R15): prologue stages
// K-tile 0; each iteration issues the async glds prefetch of tile t+1 into
// the other buffer BEFORE reading fragments / MFMA of tile t, then ONE
// barrier drains it. Same tiles, same K-order, same epilogues as the old
// 2-barrier gemm_bt -- only the staging schedule changed (the conversion
// that already paid off in FFN1/QKV/attn_stats/attn_apply).
// BMxBN tile, BK=64, 4 waves 2x2. LDS: MODE4 64KB, MODE1 48KB (grids are
// 512 blocks = 2/CU, so no occupancy loss).
// TR grid transpose: bx walks M-tiles (gridDim.x % 8 == 0 -> XCD = bx%8
// pins A panels; verified R11: FFN2 FETCH 135->49MB).
// MODE 1: C = acc + e1[m*N+n]; fused LN stats -> atomicAdd red[batch]
// MODE 4: Cf_z[m*N+n] = acc  (fp32 split-K partial, z = blockIdx.z)
// ---------------------------------------------------------------------------
template <int MODE, int BM, int BN, int TR>
__global__ __launch_bounds__(256) void gemm_bt(
    const hbf* __restrict__ A, const hbf* __restrict__ Bt, hbf* __restrict__ C,
    float* __restrict__ Cf0, float* __restrict__ Cf1,
    const hbf* __restrict__ e1, float* __restrict__ red, int M, int N, int K,
    int LDK) {
  constexpr int WM = BM / 2, WN = BN / 2;
  constexpr int IF = WM / 16, JF = WN / 16;
  __shared__ alignas(16) hbf As[2][BM * 64];
  __shared__ alignas(16) hbf Bs[2][BN * 64];
  const int tid = threadIdx.x;
  const int wave = tid >> 6, lane = tid & 63;
  const int quad = lane >> 4, l16 = lane & 15;
  const int m0 = (TR ? blockIdx.x : blockIdx.y) * BM;
  const int n0 = (TR ? blockIdx.y : blockIdx.x) * BN;
  const int mw = (wave >> 1) * WM, nw = (wave & 1) * WN;
  const int srow = tid >> 3;       // 0..31
  const int scol = (tid & 7) * 8;  // 0..56
  const int kbase = (MODE == 4) ? blockIdx.z * K : 0;
  const f32x4 zero = {0.f, 0.f, 0.f, 0.f};
  f32x4 acc[IF][JF];
#pragma unroll
  for (int i = 0; i < IF; i++)
#pragma unroll
    for (int j = 0; j < JF; j++) acc[i][j] = zero;

  const hbf* ga = &A[(size_t)(m0 + srow) * LDK + kbase + scol];
  const hbf* gb = &Bt[(size_t)(n0 + srow) * LDK + kbase + scol];
  const int lofs = wave * 512;  // wave-uniform base within a 32-row chunk

  // prologue: stage K-tile 0 into buffer 0
#pragma unroll
  for (int c = 0; c < BM / 32; c++)
    glds16(ga + (size_t)(c * 32) * LDK, &As[0][c * 2048 + lofs]);
#pragma unroll
  for (int c = 0; c < BN / 32; c++)
    glds16(gb + (size_t)(c * 32) * LDK, &Bs[0][c * 2048 + lofs]);
  __syncthreads();

  const int NT = K / 64;
  for (int t = 0; t < NT; t++) {
    const int cur = t & 1;
    if (t < NT - 1) {  // async prefetch t+1 into other buffer (drains at bar)
      size_t ko = (size_t)(t + 1) * 64;
#pragma unroll
      for (int c = 0; c < BM / 32; c++)
        glds16(ga + (size_t)(c * 32) * LDK + ko,
               &As[cur ^ 1][c * 2048 + lofs]);
#pragma unroll
      for (int c = 0; c < BN / 32; c++)
        glds16(gb + (size_t)(c * 32) * LDK + ko,
               &Bs[cur ^ 1][c * 2048 + lofs]);
    }
    bf16x8 af[2][IF], bfr[2][JF];
#pragma unroll
    for (int h = 0; h < 2; h++) {
#pragma unroll
      for (int i = 0; i < IF; i++)
        af[h][i] =
            ldfrag(&As[cur][(mw + i * 16 + l16) * 64 + h * 32 + quad * 8]);
#pragma unroll
      for (int j = 0; j < JF; j++)
        bfr[h][j] =
            ldfrag(&Bs[cur][(nw + j * 16 + l16) * 64 + h * 32 + quad * 8]);
    }
#pragma unroll
    for (int h = 0; h < 2; h++)
#pragma unroll
      for (int i = 0; i < IF; i++)
#pragma unroll
        for (int j = 0; j < JF; j++)
          acc[i][j] = mfma16(af[h][i], bfr[h][j], acc[i][j]);
    __syncthreads();  // prefetch complete + buffer reuse safe
  }
  float ssum = 0.f, ssq = 0.f;
#pragma unroll
  for (int i = 0; i < IF; i++)
#pragma unroll
    for (int j = 0; j < JF; j++)
#pragma unroll
      for (int r = 0; r < 4; r++) {
        int m = m0 + mw + i * 16 + quad * 4 + r;
        int n = n0 + nw + j * 16 + l16;
        float v = acc[i][j][r];
        if (MODE == 1) {
          hbf hv = __float2bfloat16(v + bf2f(e1[(size_t)m * N + n]));
          C[(size_t)m * N + n] = hv;
          float fv = bf2f(hv);
          ssum += fv;
          ssq += fv * fv;
        } else if (MODE == 4) {
          float* Cf = blockIdx.z ? Cf1 : Cf0;
          Cf[(size_t)m * N + n] = v;
        }
      }
  if (MODE == 1) {
    // fused LN stats: block tile lies within one batch (BM=128 | 2048)
    float* sc = (float*)&As[0][0];  // dead LDS reuse (post final barrier)
    sc[tid] = ssum;
    sc[256 + tid] = ssq;
    __syncthreads();
    for (int off = 128; off > 0; off >>= 1) {
      if (tid < off) {
        sc[tid] += sc[tid + off];
        sc[256 + tid] += sc[256 + tid + off];
      }
      __syncthreads();
    }
    if (tid == 0) {
      int b = m0 >> 11;
      atomicAdd(&red[b * 2 + 0], sc[0]);
      atomicAdd(&red[b * 2 + 1], sc[256]);
    }
  }
}

// ---------------------------------------------------------------------------
// 256x256-tile double-buffered GEMM (8 waves 2x4, 64 MFMA per wave per
// K-tile against ONE barrier; prefetch of t+1 issued before compute of t;
// 128KB LDS, 1 block/CU). Verified R10/R13: FFN1 and QKV both left top-5
// vs the 128 2-barrier tile. Templated:
//  MODE 2: C = relu(acc + bias[n])                       (FFN1; grid 16x16)
//  MODE 0: QKV scatter to (which,B,H,T,64), Q pre-scaled (grid 12x16)
// ---------------------------------------------------------------------------
template <int MODE>
__global__ __launch_bounds__(512) void gemm256(
    const hbf* __restrict__ A, const hbf* __restrict__ Bt, hbf* __restrict__ C,
    const hbf* __restrict__ bias, int N, int K, int LDK) {
  __shared__ alignas(16) hbf As[2][256 * 64];
  __shared__ alignas(16) hbf Bs[2][256 * 64];
  const int tid = threadIdx.x;
  const int wave = tid >> 6, lane = tid & 63;
  const int quad = lane >> 4, l16 = lane & 15;
  const int wr = wave >> 2, wc = wave & 3;  // 2x4 wave grid
  const int m0 = blockIdx.y * 256, n0 = blockIdx.x * 256;
  const int mw = wr * 128, nw = wc * 64;
  const int srow = tid >> 3;       // 0..63 (rows within a 64-row chunk)
  const int scol = (tid & 7) * 8;  // 0..56
  const hbf* ga = &A[(size_t)(m0 + srow) * LDK + scol];
  const hbf* gb = &Bt[(size_t)(n0 + srow) * LDK + scol];
  const int lbase = wave * 512;  // wave-uniform LDS base within a chunk
  const f32x4 zero = {0.f, 0.f, 0.f, 0.f};
  f32x4 acc[8][4];
#pragma unroll
  for (int i = 0; i < 8; i++)
#pragma unroll
    for (int j = 0; j < 4; j++) acc[i][j] = zero;

  const int NT = K / 64;
  // prologue: stage tile 0 into buffer 0
#pragma unroll
  for (int c = 0; c < 4; c++) {
    glds16(ga + (size_t)(c * 64) * LDK, &As[0][c * 4096 + lbase]);
    glds16(gb + (size_t)(c * 64) * LDK, &Bs[0][c * 4096 + lbase]);
  }
  __syncthreads();

  for (int t = 0; t < NT; t++) {
    const int cur = t & 1;
    if (t < NT - 1) {  // async prefetch t+1 into the other buffer;
                       // drains at the end-of-iteration barrier
      size_t ko = (size_t)(t + 1) * 64;
#pragma unroll
      for (int c = 0; c < 4; c++) {
        glds16(ga + (size_t)(c * 64) * LDK + ko,
               &As[cur ^ 1][c * 4096 + lbase]);
        glds16(gb + (size_t)(c * 64) * LDK + ko,
               &Bs[cur ^ 1][c * 4096 + lbase]);
      }
    }
    // compute tile t from buffer cur: 2 k-halves x (8 m x 4 n) MFMA
#pragma unroll
    for (int h = 0; h < 2; h++) {
      bf16x8 bfr[4];
#pragma unroll
      for (int j = 0; j < 4; j++)
        bfr[j] = ldfrag(&Bs[cur][(nw + j * 16 + l16) * 64 + h * 32 + quad * 8]);
#pragma unroll
      for (int i = 0; i < 8; i++) {
        bf16x8 af =
            ldfrag(&As[cur][(mw + i * 16 + l16) * 64 + h * 32 + quad * 8]);
#pragma unroll
        for (int j = 0; j < 4; j++)
          acc[i][j] = mfma16(af, bfr[j], acc[i][j]);
      }
    }
    __syncthreads();  // drains prefetch vmcnt + protects buffer reuse
  }
  // epilogue
#pragma unroll
  for (int i = 0; i < 8; i++)
#pragma unroll
    for (int j = 0; j < 4; j++)
#pragma unroll
      for (int r = 0; r < 4; r++) {
        int m = m0 + mw + i * 16 + quad * 4 + r;
        int n = n0 + nw + j * 16 + l16;
        float v = acc[i][j][r];
        if (MODE == 2) {
          C[(size_t)m * N + n] =
              __float2bfloat16(fmaxf(v + bf2f(bias[n]), 0.f));
        } else if (MODE == 0) {
          int which = n >> 10, n1 = n & 1023;
          int hd = n1 >> 6, cc = n1 & 63;
          int bb = m >> 11, tt = m & (T_ - 1);
          if (which == 0) v *= SCALE_;  // pre-scale Q by log2e/sqrt(dk)
          C[(size_t)which * ((size_t)B_ * H_ * T_ * 64) +
            (((size_t)(bb * H_ + hd)) * T_ + tt) * 64 + cc] =
              __float2bfloat16(v);
        }
      }
}

// ---------------------------------------------------------------------------
// Attention stats + V-transform (MFMA): S = Q K^T (Q pre-scaled by log2e/8,
// so all exponentials are base-2 -> native v_exp_f32).
//   adj[s] = max_q S[q,s] + log2(sum_q 2^(S[q,s]-max))
// Tail (fused, block owns its 64 s-rows): Vt'[v,s] = V[s,v]*2^(-adj[s]).
// Block: 64 s (4 waves x 16), loops 32 q-tiles of 64. Q staged via
// double-buffered glds + XOR swizzle, one barrier/iter (R14, verified:
// left top-5). K staging one-time padded-72; fused V tail unchanged.
// ---------------------------------------------------------------------------
__global__ __launch_bounds__(256) void attn_stats(const hbf* __restrict__ Q,
                                                  const hbf* __restrict__ K,
                                                  const hbf* __restrict__ V,
                                                  hbf* __restrict__ Vt) {
  __shared__ alignas(16) hbf Ks[64 * 72];
  __shared__ alignas(16) hbf Qs[2][64 * 64];
  __shared__ float sAdj[64];
  const int bh = blockIdx.y;
  const int s0 = blockIdx.x * 64;
  const int tid = threadIdx.x;
  const int wave = tid >> 6, lane = tid & 63;
  const int quad = lane >> 4, l16 = lane & 15;
  const int sw = wave * 16;
  const hbf* Kb = K + (size_t)bh * T_ * 64;
  const hbf* Qb = Q + (size_t)bh * T_ * 64;
  const hbf* Vb = V + (size_t)bh * T_ * 64;
  hbf* Vtb = Vt + (size_t)bh * 64 * T_;
  const int r_ = tid >> 3, c_ = (tid & 7) * 8;
  // swizzled glds staging for Q: LDS slot (row=tid>>3, chunk=tid&7) holds
  // global chunk (tid&7)^(row&7); reads use ^sx (sx = (l16&7)*8 elems)
  const int swz = (tid & 7) ^ (r_ & 7);
  const hbf* gq = Qb + (size_t)r_ * 64 + swz * 8;
  hbf* lQ0 = &Qs[0][wave * 512];
  hbf* lQ1 = &Qs[1][wave * 512];
  const int sx = (l16 & 7) * 8;
  // one-time K staging (padded stride 72, conflict-lite)
#pragma unroll
  for (int c = 0; c < 2; c++) {
    int row = c * 32 + r_;
    *(float4*)(&Ks[row * 72 + c_]) =
        *(const float4*)(&Kb[(size_t)(s0 + row) * 64 + c_]);
  }
  // prologue: stage Q tile 0 into buf 0 (rows 0..31 and 32..63)
  glds16(gq, lQ0);
  glds16(gq + (size_t)32 * 64, lQ0 + 2048);
  __syncthreads();
  bf16x8 kf0 = ldfrag(&Ks[(sw + l16) * 72 + quad * 8]);
  bf16x8 kf1 = ldfrag(&Ks[(sw + l16) * 72 + 32 + quad * 8]);
  float m_thr[4], l_thr[4];
#pragma unroll
  for (int r = 0; r < 4; r++) {
    m_thr[r] = -1e30f;
    l_thr[r] = 0.f;
  }
  const f32x4 zero = {0.f, 0.f, 0.f, 0.f};
  for (int qt = 0; qt < T_ / 64; qt++) {
    const int cur = qt & 1;
    if (qt < T_ / 64 - 1) {  // async prefetch next Q tile (drains at barrier)
      size_t qo = (size_t)(qt + 1) * 4096;
      hbf* lQn = cur ? lQ0 : lQ1;
      glds16(gq + qo, lQn);
      glds16(gq + qo + (size_t)32 * 64, lQn + 2048);
    }
    const hbf* Qc = &Qs[cur][0];
    f32x4 acc[4];
#pragma unroll
    for (int j = 0; j < 4; j++) {
      bf16x8 qf0 = ldfrag(&Qc[(j * 16 + l16) * 64 + ((quad * 8) ^ sx)]);
      bf16x8 qf1 = ldfrag(&Qc[(j * 16 + l16) * 64 + ((32 + quad * 8) ^ sx)]);
      f32x4 a = zero;
      a = mfma16(kf0, qf0, a);
      a = mfma16(kf1, qf1, a);
      acc[j] = a;
    }
#pragma unroll
    for (int r = 0; r < 4; r++) {
      float mt = fmaxf(fmaxf(acc[0][r], acc[1][r]),
                       fmaxf(acc[2][r], acc[3][r]));
      float nm = fmaxf(m_thr[r], mt);
      float s = l_thr[r] * fexp2(m_thr[r] - nm);
#pragma unroll
      for (int j = 0; j < 4; j++) s += fexp2(acc[j][r] - nm);
      l_thr[r] = s;
      m_thr[r] = nm;
    }
    __syncthreads();  // prefetch complete + buffer reuse safe
  }
#pragma unroll
  for (int d = 1; d < 16; d <<= 1) {
#pragma unroll
    for (int r = 0; r < 4; r++) {
      float om = __shfl_xor(m_thr[r], d);
      float ol = __shfl_xor(l_thr[r], d);
      float nm = fmaxf(m_thr[r], om);
      l_thr[r] = l_thr[r] * fexp2(m_thr[r] - nm) + ol * fexp2(om - nm);
      m_thr[r] = nm;
    }
  }
  if (l16 == 0) {
#pragma unroll
    for (int r = 0; r < 4; r++)
      sAdj[sw + quad * 4 + r] = m_thr[r] + flog2(l_thr[r]);
  }
  __syncthreads();
  // fused V scale+transpose for this block's s-range (reuse Ks as tile)
#pragma unroll
  for (int c = 0; c < 2; c++) {
    int e = (c * 256 + tid) * 8;
    int r = e >> 6, col = e & 63;
    union alignas(16) {
      hbf h[8];
      float4 f4;
    } u;
    u.f4 = *(const float4*)(&Vb[(size_t)(s0 + r) * 64 + col]);
    float sc = fexp2(-sAdj[r]);
#pragma unroll
    for (int k2 = 0; k2 < 8; k2++)
      u.h[k2] = __float2bfloat16(bf2f(u.h[k2]) * sc);
    *(float4*)(&Ks[r * 72 + col]) = u.f4;
  }
  __syncthreads();
#pragma unroll
  for (int c = 0; c < 2; c++) {
    int e = (c * 256 + tid) * 8;
    int v = e >> 6, tt = e & 63;
    union alignas(16) {
      hbf h[8];
      float4 f4;
    } u;
#pragma unroll
    for (int k2 = 0; k2 < 8; k2++) u.h[k2] = Ks[(tt + k2) * 72 + v];
    *(float4*)(&Vtb[(size_t)v * T_ + s0 + tt]) = u.f4;
  }
}

// ---------------------------------------------------------------------------
// Attention apply (MFMA): O[q,v] = sum_s 2^(S[q,s]) * V'[s,v]
// (normalizer folded into V'). Cross-iteration pipeline: iteration st
// computes QK^T(st) AND PV(st-1) so PV's MFMAs overlap QK's load/exp chain.
//  * K double-buffered (16KB), V triple-buffered (24KB), P per-wave
//    double-buffered (37KB). 77KB total -> 2 blocks/CU (grid cap).
//  * staging via global_load_lds + XOR swizzle, one barrier per iteration,
//    s_setprio(1) around MFMA clusters.
// Block: 128 q (4 waves x 32), s-tiles of 64, grid (16,32).
// ---------------------------------------------------------------------------
__global__ __launch_bounds__(256) void attn_apply(const hbf* __restrict__ Q,
                                                  const hbf* __restrict__ K,
                                                  const hbf* __restrict__ Vt,
                                                  hbf* __restrict__ heads) {
  __shared__ alignas(16) hbf Ksb[2 * 64 * 64];
  __shared__ alignas(16) hbf Vsb[3 * 64 * 64];
  __shared__ alignas(16) hbf Ps[4 * 2 * 32 * 72];
  const int bh = blockIdx.y;
  const int b = bh >> 4, h = bh & 15;
  const int q0 = blockIdx.x * 128;
  const int tid = threadIdx.x;
  const int wave = tid >> 6, lane = tid & 63;
  const int quad = lane >> 4, l16 = lane & 15;
  const int qw = wave * 32;
  const hbf* Qb = Q + (size_t)bh * T_ * 64;
  const hbf* Kb = K + (size_t)bh * T_ * 64;
  const hbf* Vtb = Vt + (size_t)bh * 64 * T_;
  hbf* Pw = &Ps[wave * (2 * 32 * 72)];
  // staging: lane -> LDS slot (row=tid>>3, chunk=tid&7); source chunk is
  // inverse-swizzled so LDS slot (r,c) holds global chunk c^(r&7).
  const int srow = tid >> 3, sc8 = tid & 7;
  const int swz = sc8 ^ (srow & 7);
  const hbf* gk = Kb + (size_t)srow * 64 + swz * 8;
  const hbf* gv = Vtb + (size_t)srow * T_ + swz * 8;
  hbf* lK = &Ksb[wave * 512];
  hbf* lV = &Vsb[wave * 512];
  const int sx = (l16 & 7) * 8;  // read-side elem swizzle for this lane's rows
  // Q fragments (B-operand): lane supplies Q[col=q(l16)][k=quad*8 in hh*32]
  bf16x8 qf[2][2];
#pragma unroll
  for (int i = 0; i < 2; i++)
#pragma unroll
    for (int hh = 0; hh < 2; hh++)
      qf[i][hh] = ldfrag(&Qb[(size_t)(q0 + qw + i * 16 + l16) * 64 + hh * 32 +
                             quad * 8]);
  const f32x4 zero = {0.f, 0.f, 0.f, 0.f};
  f32x4 accO[2][4];
#pragma unroll
  for (int i = 0; i < 2; i++)
#pragma unroll
    for (int j = 0; j < 4; j++) accO[i][j] = zero;

  // prologue: stage tiles 0 and 1 (K slots 0/1, V slots 0/1)
  glds16(gk, lK);
  glds16(gk + 2048, lK + 2048);
  glds16(gv, lV);
  glds16(gv + (size_t)32 * T_, lV + 2048);
  glds16(gk + 4096, lK + 4096);
  glds16(gk + 4096 + 2048, lK + 4096 + 2048);
  glds16(gv + 64, lV + 4096);
  glds16(gv + (size_t)32 * T_ + 64, lV + 4096 + 2048);
  __syncthreads();

  // prologue compute: QK^T(0) -> P[0] (no PV yet)
  {
    const hbf* Kc = &Ksb[0];
    bf16x8 kf[4][2];
#pragma unroll
    for (int j = 0; j < 4; j++)
#pragma unroll
      for (int hh = 0; hh < 2; hh++)
        kf[j][hh] =
            ldfrag(&Kc[(j * 16 + l16) * 64 + ((hh * 32 + quad * 8) ^ sx)]);
    __builtin_amdgcn_s_setprio(1);
    f32x4 accS[2][4];
#pragma unroll
    for (int i = 0; i < 2; i++)
#pragma unroll
      for (int j = 0; j < 4; j++) {
        f32x4 a = mfma16(kf[j][0], qf[i][0], zero);
        accS[i][j] = mfma16(kf[j][1], qf[i][1], a);
      }
    __builtin_amdgcn_s_setprio(0);
#pragma unroll
    for (int i = 0; i < 2; i++)
#pragma unroll
      for (int j = 0; j < 4; j++) {
        union {
          hbf h4[4];
          uint2 u;
        } pk;
#pragma unroll
        for (int r = 0; r < 4; r++)
          pk.h4[r] = __float2bfloat16(fexp2(accS[i][j][r]));
        *(uint2*)&Pw[(i * 16 + l16) * 72 + j * 16 + quad * 4] = pk.u;
      }
  }
  __syncthreads();  // protect K slot 0 from the st=1 prefetch (tile 2)

  for (int st = 1; st < T_ / 64; st++) {
    const int kcur = st & 1;
    const int pcur = st & 1, pprev = pcur ^ 1;
    const int vprev = (st - 1) % 3;
    if (st < T_ / 64 - 1) {  // async prefetch tile st+1 (drains at barrier)
      const int knxt = (st + 1) & 1, vnxt = (st + 1) % 3;
      size_t ko = (size_t)(st + 1) * 4096;
      glds16(gk + ko, lK + knxt * 4096);
      glds16(gk + ko + 2048, lK + knxt * 4096 + 2048);
      glds16(gv + (st + 1) * 64, lV + vnxt * 4096);
      glds16(gv + (size_t)32 * T_ + (st + 1) * 64, lV + vnxt * 4096 + 2048);
    }
    const hbf* Kc = &Ksb[kcur * 4096];
    const hbf* Vp = &Vsb[vprev * 4096];
    // issue kf loads for QK(st) early (in-order lgkm: complete before pf use)
    bf16x8 kf[4][2];
#pragma unroll
    for (int j = 0; j < 4; j++)
#pragma unroll
      for (int hh = 0; hh < 2; hh++)
        kf[j][hh] =
            ldfrag(&Kc[(j * 16 + l16) * 64 + ((hh * 32 + quad * 8) ^ sx)]);
    // PV(st-1): A = P[prev] rows q, B = V'[prev] rows v
    bf16x8 pf[2][2];
#pragma unroll
    for (int i = 0; i < 2; i++)
#pragma unroll
      for (int hh = 0; hh < 2; hh++)
        pf[i][hh] = ldfrag(
            &Pw[pprev * (32 * 72) + (i * 16 + l16) * 72 + hh * 32 + quad * 8]);
    __builtin_amdgcn_s_setprio(1);
#pragma unroll
    for (int j2 = 0; j2 < 4; j2++) {
      bf16x8 vf0 = ldfrag(&Vp[(j2 * 16 + l16) * 64 + ((quad * 8) ^ sx)]);
      bf16x8 vf1 = ldfrag(&Vp[(j2 * 16 + l16) * 64 + ((32 + quad * 8) ^ sx)]);
#pragma unroll
      for (int i = 0; i < 2; i++) {
        accO[i][j2] = mfma16(pf[i][0], vf0, accO[i][j2]);
        accO[i][j2] = mfma16(pf[i][1], vf1, accO[i][j2]);
      }
    }
    // QK^T(st) swapped: accS[i][j] = D[s][q]
    f32x4 accS[2][4];
#pragma unroll
    for (int i = 0; i < 2; i++)
#pragma unroll
      for (int j = 0; j < 4; j++) {
        f32x4 a = mfma16(kf[j][0], qf[i][0], zero);
        accS[i][j] = mfma16(kf[j][1], qf[i][1], a);
      }
    __builtin_amdgcn_s_setprio(0);
    // exp2 -> bf16 pack -> P[cur] (8 b64 writes, s-consecutive)
#pragma unroll
    for (int i = 0; i < 2; i++)
#pragma unroll
      for (int j = 0; j < 4; j++) {
        union {
          hbf h4[4];
          uint2 u;
        } pk;
#pragma unroll
        for (int r = 0; r < 4; r++)
          pk.h4[r] = __float2bfloat16(fexp2(accS[i][j][r]));
        *(uint2*)&Pw[pcur * (32 * 72) + (i * 16 + l16) * 72 + j * 16 +
                     quad * 4] = pk.u;
      }
    __syncthreads();
  }
  // epilogue: PV(last tile): P[(T/64-1)&1], V[(T/64-1)%3]
  {
    const int pl = (T_ / 64 - 1) & 1;
    const hbf* Vp = &Vsb[((T_ / 64 - 1) % 3) * 4096];
    bf16x8 pf[2][2];
#pragma unroll
    for (int i = 0; i < 2; i++)
#pragma unroll
      for (int hh = 0; hh < 2; hh++)
        pf[i][hh] = ldfrag(
            &Pw[pl * (32 * 72) + (i * 16 + l16) * 72 + hh * 32 + quad * 8]);
    __builtin_amdgcn_s_setprio(1);
#pragma unroll
    for (int j2 = 0; j2 < 4; j2++) {
      bf16x8 vf0 = ldfrag(&Vp[(j2 * 16 + l16) * 64 + ((quad * 8) ^ sx)]);
      bf16x8 vf1 = ldfrag(&Vp[(j2 * 16 + l16) * 64 + ((32 + quad * 8) ^ sx)]);
#pragma unroll
      for (int i = 0; i < 2; i++) {
        accO[i][j2] = mfma16(pf[i][0], vf0, accO[i][j2]);
        accO[i][j2] = mfma16(pf[i][1], vf1, accO[i][j2]);
      }
    }
    __builtin_amdgcn_s_setprio(0);
  }
#pragma unroll
  for (int i = 0; i < 2; i++)
#pragma unroll
    for (int j2 = 0; j2 < 4; j2++)
#pragma unroll
      for (int r = 0; r < 4; r++) {
        int q = q0 + qw + i * 16 + quad * 4 + r;
        int v = j2 * 16 + l16;
        heads[((size_t)(b * T_ + q)) * D_ + h * 64 + v] =
            __float2bfloat16(accO[i][j2][r]);
      }
}

// ---------------------------------------------------------------------------
// LN1 normalize (stats came fused from the out-proj GEMM). Vectorized
// 4x bf16 in/out (G13).
// ---------------------------------------------------------------------------
__global__ __launch_bounds__(256) void ln_norm(const hbf* __restrict__ src,
                                               const float* __restrict__ red,
                                               void* dst,
                                               const int* __restrict__ flag,
                                               int force_bf) {
  const int isbf = force_bf ? 1 : *flag;
  const float invN = 1.f / (float)(T_ * D_);
  const uint2* sv = (const uint2*)src;
  for (size_t i = (size_t)blockIdx.x * 256 + threadIdx.x;
       i < (size_t)B_ * T_ * D_ / 4; i += (size_t)gridDim.x * 256) {
    int b = (int)(i >> 19);  // per-batch 4-elem count = T*D/4 = 2^19
    float mu = red[b * 2 + 0] * invN;
    float var = red[b * 2 + 1] * invN - mu * mu;
    float rstd = rsqrtf(var + EPS_);
    union {
      uint2 u;
      hbf h[4];
    } s;
    s.u = sv[i];
    float out[4];
#pragma unroll
    for (int r = 0; r < 4; r++) out[r] = (bf2f(s.h[r]) - mu) * rstd;
    if (isbf) {
      union {
        hbf h[4];
        uint2 u;
      } pk;
#pragma unroll
      for (int r = 0; r < 4; r++) pk.h[r] = __float2bfloat16(out[r]);
      ((uint2*)dst)[i] = pk.u;
    } else {
      float4 f{out[0], out[1], out[2], out[3]};
      ((float4*)dst)[i] = f;
    }
  }
}

// ---------------------------------------------------------------------------
// LN2 stats over r2 = P0+P1+b2+o1 (r2 never materialized). Vectorized:
// float4 partial loads + uint2 (4x bf16) o1/b2 loads (G13).
// ---------------------------------------------------------------------------
__global__ __launch_bounds__(256) void ln2_stats(const float* __restrict__ P0,
                                                 const float* __restrict__ P1,
                                                 const hbf* __restrict__ o1,
                                                 const hbf* __restrict__ b2b,
                                                 float* __restrict__ red) {
  __shared__ float s1[256], s2[256];
  const int b = blockIdx.y;
  const size_t base = (size_t)b * (T_ * D_ / 4);
  const float4* P0v = (const float4*)P0;
  const float4* P1v = (const float4*)P1;
  const uint2* o1v = (const uint2*)o1;
  const uint2* b2v = (const uint2*)b2b;
  float sum = 0.f, sq = 0.f;
  for (size_t i = (size_t)blockIdx.x * 256 + threadIdx.x;
       i < (size_t)(T_ * D_ / 4); i += (size_t)gridDim.x * 256) {
    float4 p0 = P0v[base + i], p1 = P1v[base + i];
    union {
      uint2 u;
      hbf h[4];
    } o, bb;
    o.u = o1v[base + i];
    bb.u = b2v[i & (D_ / 4 - 1)];
#pragma unroll
    for (int r = 0; r < 4; r++) {
      float v = (&p0.x)[r] + (&p1.x)[r] + bf2f(bb.h[r]) + bf2f(o.h[r]);
      sum += v;
      sq += v * v;
    }
  }
  s1[threadIdx.x] = sum;
  s2[threadIdx.x] = sq;
  __syncthreads();
  for (int off = 128; off > 0; off >>= 1) {
    if ((int)threadIdx.x < off) {
      s1[threadIdx.x] += s1[threadIdx.x + off];
      s2[threadIdx.x] += s2[threadIdx.x + off];
    }
    __syncthreads();
  }
  if (threadIdx.x == 0) {
    atomicAdd(&red[b * 2 + 0], s1[0]);
    atomicAdd(&red[b * 2 + 1], s2[0]);
  }
}

__global__ __launch_bounds__(256) void ln2_norm(
    const float* __restrict__ P0, const float* __restrict__ P1,
    const hbf* __restrict__ o1, const hbf* __restrict__ b2b,
    const float* __restrict__ red, void* dst, const int* __restrict__ flag) {
  const int isbf = *flag;
  const float invN = 1.f / (float)(T_ * D_);
  const float4* P0v = (const float4*)P0;
  const float4* P1v = (const float4*)P1;
  const uint2* o1v = (const uint2*)o1;
  const uint2* b2v = (const uint2*)b2b;
  for (size_t i = (size_t)blockIdx.x * 256 + threadIdx.x;
       i < (size_t)B_ * T_ * D_ / 4; i += (size_t)gridDim.x * 256) {
    int b = (int)(i >> 19);  // per-batch float4 count = T*D/4 = 2^19
    float mu = red[b * 2 + 0] * invN;
    float var = red[b * 2 + 1] * invN - mu * mu;
    float rstd = rsqrtf(var + EPS_);
    float4 p0 = P0v[i], p1 = P1v[i];
    union {
      uint2 u;
      hbf h[4];
    } o, bb;
    o.u = o1v[i];
    bb.u = b2v[i & (D_ / 4 - 1)];
    float out[4];
#pragma unroll
    for (int r = 0; r < 4; r++)
      out[r] =
          ((&p0.x)[r] + (&p1.x)[r] + bf2f(bb.h[r]) + bf2f(o.h[r]) - mu) * rstd;
    if (isbf) {
      union {
        hbf h[4];
        uint2 u;
      } pk;
#pragma unroll
      for (int r = 0; r < 4; r++) pk.h[r] = __float2bfloat16(out[r]);
      ((uint2*)dst)[i] = pk.u;
    } else {
      float4 f{out[0], out[1], out[2], out[3]};
      ((float4*)dst)[i] = f;
    }
  }
}

// ---------------------------------------------------------------------------
// Workspace (MiB offsets), ~88.1 MB total:
//  [0,8) xb | [8,14) Wqkvt | [14,16) Wot | [16,24) W1t | [24,32) W2t
//  [32,40) Q | [40,48) K | [48,56) V | [56,64) Vt | [64,72) heads
//  [72,80) r1 | [80,88) o1 | ff1 aliases [32,64)
//  split-K partials (fp32, 16 MB each): P0 over [0,16), P1 over [64,80)
//  [88,..) b1b 8K | b2b 2K | red 32B | flag 4B
// ---------------------------------------------------------------------------
extern "C" void kernel_launch(void* const* d_in, const int* in_sizes, int n_in,
                              void* d_out, int out_size, void* d_ws,
                              size_t ws_size, hipStream_t stream) {
  const void* x = d_in[0];
  const void* Wq = d_in[1];
  const void* Wk = d_in[2];
  const void* Wv = d_in[3];
  const void* Wo = d_in[4];
  const void* W1 = d_in[5];
  const void* W2 = d_in[7];
  const void* b1 = d_in[6];
  const void* b2 = d_in[8];

  const size_t MB = 1024 * 1024;
  if (ws_size < 89 * MB) return;

  char* w = (char*)d_ws;
  hbf* xb = (hbf*)(w + 0 * MB);
  hbf* wqkvt = (hbf*)(w + 8 * MB);
  hbf* wot = (hbf*)(w + 14 * MB);
  hbf* w1t = (hbf*)(w + 16 * MB);
  hbf* w2t = (hbf*)(w + 24 * MB);
  hbf* Qb = (hbf*)(w + 32 * MB);
  hbf* Kb = (hbf*)(w + 40 * MB);
  hbf* Vb = (hbf*)(w + 48 * MB);
  hbf* Vtb = (hbf*)(w + 56 * MB);
  hbf* heads = (hbf*)(w + 64 * MB);
  hbf* r1 = (hbf*)(w + 72 * MB);
  hbf* o1 = (hbf*)(w + 80 * MB);
  hbf* ff1 = (hbf*)(w + 32 * MB);   // over dead Q/K/V/Vt
  float* P0 = (float*)(w + 0 * MB);   // over dead xb/wqkvt/wot (16 MB)
  float* P1 = (float*)(w + 64 * MB);  // over dead heads/r1 (16 MB)
  hbf* b1b = (hbf*)(w + 88 * MB);
  hbf* b2b = b1b + FF_;
  float* red = (float*)(b2b + D_);
  int* flag = (int*)(red + 8);

  hipMemsetAsync(red, 0, 8 * sizeof(float) + sizeof(int), stream);
  detect_dtype<<<1, 256, 0, stream>>>((const unsigned*)x, flag);

  const int M = B_ * T_;  // 4096
  // --- one-launch preconversion ---
  preconv<<<13314, 256, 0, stream>>>(x, Wq, Wk, Wv, Wo, W1, W2, b1, b2, xb,
                                     wqkvt, wot, w1t, w2t, b1b, b2b, flag);
  // --- QKV fused projection: 256x256 double-buffered kernel (192 blocks) ---
  gemm256<0><<<dim3(3 * D_ / 256, M / 256), 512, 0, stream>>>(
      xb, wqkvt, Qb, nullptr, 3 * D_, D_, D_);
  // --- attention: col-softmax stats + fused V scale/transpose, then apply ---
  attn_stats<<<dim3(32, 32), 256, 0, stream>>>(Qb, Kb, Vb, Vtb);
  attn_apply<<<dim3(16, 32), 256, 0, stream>>>(Qb, Kb, Vtb, heads);
  // --- out-proj + residual + fused LN1 stats; TR grid, double-buffered ---
  gemm_bt<1, 128, 64, 1><<<dim3(32, 16), 256, 0, stream>>>(
      heads, wot, r1, nullptr, nullptr, xb, red, M, D_, D_, D_);
  ln_norm<<<2048, 256, 0, stream>>>(r1, red, o1, flag, 1);
  // --- FFN1: 256x256 double-buffered single-barrier kernel (grid = 1/CU) ---
  gemm256<2><<<dim3(FF_ / 256, M / 256), 512, 0, stream>>>(
      o1, w1t, ff1, b1b, FF_, D_, D_);
  // --- FFN2 split-K=2 -> fp32 partials; TR grid, double-buffered ---
  gemm_bt<4, 128, 128, 1><<<dim3(32, 8, 2), 256, 0, stream>>>(
      ff1, w2t, nullptr, P0, P1, nullptr, nullptr, M, D_, FF_ / 2, FF_);
  // --- LN2 (r2 = P0+P1+b2+o1, never materialized; vectorized) ---
  ln2_stats<<<dim3(256, B_), 256, 0, stream>>>(P0, P1, o1, b2b, red + 4);
  ln2_norm<<<2048, 256, 0, stream>>>(P0, P1, o1, b2b, red + 4, d_out, flag);
}